// Round 1
// baseline (2430.820 us; speedup 1.0000x reference)
//
#include <hip/hip_runtime.h>
#include <math.h>

#define B_  2
#define L_  2000
#define DM_ 256
#define DI_ 512
#define DS_ 16
#define NL_ 4
#define BL_ (B_*L_)     // 4000
#define BLP_ 4096       // rows padded to multiple of 64

__device__ __forceinline__ float siluf(float x) {
    return x / (1.f + __expf(-x));
}

// ---------------- embed: h = x*biw + bib + gene_emb + mod_emb ----------------
__global__ __launch_bounds__(256) void embed_kernel(
    const float* __restrict__ x, const float* __restrict__ biw,
    const float* __restrict__ bib, const float* __restrict__ ge,
    const float* __restrict__ me, float* __restrict__ h)
{
    int bl = blockIdx.x, d = threadIdx.x;
    int l = bl % L_;
    h[(size_t)bl*DM_ + d] = x[bl]*biw[d] + bib[d] + ge[(size_t)l*DM_ + d] + me[d];
}

// ---------------- layernorm over D_MODEL=256, one block per row ----------------
__global__ __launch_bounds__(256) void ln_kernel(
    const float* __restrict__ h, const float* __restrict__ w,
    const float* __restrict__ b, float* __restrict__ out)
{
    __shared__ float sm[4];
    int row = blockIdx.x, tid = threadIdx.x;
    float v = h[(size_t)row*DM_ + tid];
    float s = v;
    #pragma unroll
    for (int o = 32; o > 0; o >>= 1) s += __shfl_down(s, o);
    if ((tid & 63) == 0) sm[tid >> 6] = s;
    __syncthreads();
    float mu = (sm[0]+sm[1]+sm[2]+sm[3]) * (1.f/DM_);
    __syncthreads();
    float d = v - mu;
    float q = d*d;
    #pragma unroll
    for (int o = 32; o > 0; o >>= 1) q += __shfl_down(q, o);
    if ((tid & 63) == 0) sm[tid >> 6] = q;
    __syncthreads();
    float var = (sm[0]+sm[1]+sm[2]+sm[3]) * (1.f/DM_);
    out[(size_t)row*DM_ + tid] = d * rsqrtf(var + 1e-5f) * w[tid] + b[tid];
}

// ---------------- generic fp32 GEMM: C[m,n] (+)= sum_k A[m,k]*W[n,k] ----------------
// 64x64 tile, K in chunks of 64, 256 threads, 4x4 register blocking.
// FUSE_SILU: A_eff[m,k] = A[m,k] * silu(Z[m*ldz + k])   (for out_proj: y * silu(z))
template<bool FUSE_SILU, bool ACCUM>
__global__ __launch_bounds__(256) void gemm64(
    const float* __restrict__ A, const float* __restrict__ Z, int ldz,
    const float* __restrict__ W, float* __restrict__ C, int ldc, int K)
{
    __shared__ float a_s[64][68];
    __shared__ float w_s[64][68];
    const int r0 = blockIdx.x * 64, c0 = blockIdx.y * 64;
    const int tid = threadIdx.x;
    const int tx = tid & 15, ty = tid >> 4;
    const int lrow = tid >> 2, lk0 = (tid & 3) * 16;
    float acc[4][4] = {};
    for (int kc = 0; kc < K; kc += 64) {
        const float* Ap = A + (size_t)(r0 + lrow)*K + kc + lk0;
        float4 av[4];
        #pragma unroll
        for (int q = 0; q < 4; q++) av[q] = *(const float4*)(Ap + 4*q);
        if constexpr (FUSE_SILU) {
            const float* Zp = Z + (size_t)(r0 + lrow)*ldz + kc + lk0;
            #pragma unroll
            for (int q = 0; q < 4; q++) {
                float4 zv = *(const float4*)(Zp + 4*q);
                av[q].x *= siluf(zv.x);
                av[q].y *= siluf(zv.y);
                av[q].z *= siluf(zv.z);
                av[q].w *= siluf(zv.w);
            }
        }
        const float* Wp = W + (size_t)(c0 + lrow)*K + kc + lk0;
        float4 wv[4];
        #pragma unroll
        for (int q = 0; q < 4; q++) wv[q] = *(const float4*)(Wp + 4*q);
        #pragma unroll
        for (int q = 0; q < 4; q++) *(float4*)&a_s[lrow][lk0 + 4*q] = av[q];
        #pragma unroll
        for (int q = 0; q < 4; q++) *(float4*)&w_s[lrow][lk0 + 4*q] = wv[q];
        __syncthreads();
        #pragma unroll
        for (int k4 = 0; k4 < 64; k4 += 4) {
            float4 af[4], wf[4];
            #pragma unroll
            for (int i = 0; i < 4; i++) af[i] = *(const float4*)&a_s[ty + 16*i][k4];
            #pragma unroll
            for (int j = 0; j < 4; j++) wf[j] = *(const float4*)&w_s[tx + 16*j][k4];
            #pragma unroll
            for (int i = 0; i < 4; i++) {
                #pragma unroll
                for (int j = 0; j < 4; j++) {
                    acc[i][j] = fmaf(af[i].x, wf[j].x, acc[i][j]);
                    acc[i][j] = fmaf(af[i].y, wf[j].y, acc[i][j]);
                    acc[i][j] = fmaf(af[i].z, wf[j].z, acc[i][j]);
                    acc[i][j] = fmaf(af[i].w, wf[j].w, acc[i][j]);
                }
            }
        }
        __syncthreads();
    }
    #pragma unroll
    for (int i = 0; i < 4; i++) {
        #pragma unroll
        for (int j = 0; j < 4; j++) {
            size_t idx = (size_t)(r0 + ty + 16*i)*ldc + (c0 + tx + 16*j);
            if constexpr (ACCUM) C[idx] += acc[i][j]; else C[idx] = acc[i][j];
        }
    }
}

// ---------------- depthwise causal conv(4) + silu; writes u (b,l,c) and ut (b,c,l) ----------------
__global__ __launch_bounds__(256) void conv_silu_kernel(
    const float* __restrict__ xz, const float* __restrict__ cw,
    const float* __restrict__ cb, float* __restrict__ u, float* __restrict__ ut)
{
    int bl = blockIdx.x, tid = threadIdx.x;
    int b = bl / L_, l = bl % L_;
    #pragma unroll
    for (int cc = 0; cc < 2; cc++) {
        int c = tid + cc*256;
        float acc = cb[c];
        #pragma unroll
        for (int k = 0; k < 4; k++) {
            int ls = l + k - 3;
            if (ls >= 0) acc = fmaf(xz[(size_t)(b*L_ + ls)*1024 + c], cw[c*4 + k], acc);
        }
        float s = siluf(acc);
        u[(size_t)bl*DI_ + c] = s;
        ut[((size_t)(b*DI_ + c))*L_ + l] = s;
    }
}

// ---------------- fused x_proj (N=48,K=512) + dt_proj (N=512,K=16) + softplus ----------------
// Writes Bm/Cm transposed (b,n,l) and dt transposed (b,d,l).
__global__ __launch_bounds__(256) void xproj_dt_kernel(
    const float* __restrict__ U, const float* __restrict__ XW,
    const float* __restrict__ DTW, const float* __restrict__ DTB,
    float* __restrict__ bmt, float* __restrict__ cmt, float* __restrict__ dtt)
{
    __shared__ float a_s[64][68];
    __shared__ float w_s[48][68];
    __shared__ __align__(16) float dtr_s[64][16];
    const int r0 = blockIdx.x * 64;
    const int tid = threadIdx.x;
    const int tx = tid & 15, ty = tid >> 4;
    const int lrow = tid >> 2, lk0 = (tid & 3) * 16;
    float acc[4][3] = {};
    for (int kc = 0; kc < 512; kc += 64) {
        const float* Ap = U + (size_t)(r0 + lrow)*512 + kc + lk0;
        float4 av[4];
        #pragma unroll
        for (int q = 0; q < 4; q++) av[q] = *(const float4*)(Ap + 4*q);
        #pragma unroll
        for (int q = 0; q < 4; q++) *(float4*)&a_s[lrow][lk0 + 4*q] = av[q];
        if (lrow < 48) {
            const float* Wp = XW + (size_t)lrow*512 + kc + lk0;
            #pragma unroll
            for (int q = 0; q < 4; q++) *(float4*)&w_s[lrow][lk0 + 4*q] = *(const float4*)(Wp + 4*q);
        }
        __syncthreads();
        #pragma unroll
        for (int k4 = 0; k4 < 64; k4 += 4) {
            float4 af[4], wf[3];
            #pragma unroll
            for (int i = 0; i < 4; i++) af[i] = *(const float4*)&a_s[ty + 16*i][k4];
            #pragma unroll
            for (int j = 0; j < 3; j++) wf[j] = *(const float4*)&w_s[tx + 16*j][k4];
            #pragma unroll
            for (int i = 0; i < 4; i++) {
                #pragma unroll
                for (int j = 0; j < 3; j++) {
                    acc[i][j] = fmaf(af[i].x, wf[j].x, acc[i][j]);
                    acc[i][j] = fmaf(af[i].y, wf[j].y, acc[i][j]);
                    acc[i][j] = fmaf(af[i].z, wf[j].z, acc[i][j]);
                    acc[i][j] = fmaf(af[i].w, wf[j].w, acc[i][j]);
                }
            }
        }
        __syncthreads();
    }
    // scatter: dt_r -> LDS, Bm/Cm -> global transposed
    #pragma unroll
    for (int i = 0; i < 4; i++) {
        int rr = ty + 16*i, bl = r0 + rr;
        int b = bl / L_, l = bl % L_;
        dtr_s[rr][tx] = acc[i][0];
        if (bl < BL_) {
            bmt[((size_t)(b*DS_ + tx))*L_ + l] = acc[i][1];
            cmt[((size_t)(b*DS_ + tx))*L_ + l] = acc[i][2];
        }
    }
    __syncthreads();
    // phase 2: dt = softplus(dt_r @ DTW^T + DTB), write transposed (b,d,l)
    #pragma unroll
    for (int c2 = 0; c2 < 2; c2++) {
        int nc = tid + c2*256;
        float wreg[16];
        #pragma unroll
        for (int r = 0; r < 16; r++) wreg[r] = DTW[nc*16 + r];
        float bias = DTB[nc];
        int rmax = BL_ - r0; if (rmax > 64) rmax = 64;
        for (int rr = 0; rr < rmax; rr++) {
            int bl = r0 + rr, b = bl / L_, l = bl % L_;
            float acc2 = bias;
            const float4* dp = (const float4*)&dtr_s[rr][0];
            #pragma unroll
            for (int r4 = 0; r4 < 4; r4++) {
                float4 dv = dp[r4];
                acc2 = fmaf(dv.x, wreg[4*r4+0], acc2);
                acc2 = fmaf(dv.y, wreg[4*r4+1], acc2);
                acc2 = fmaf(dv.z, wreg[4*r4+2], acc2);
                acc2 = fmaf(dv.w, wreg[4*r4+3], acc2);
            }
            float dt = acc2 > 20.f ? acc2 : log1pf(__expf(acc2));
            dtt[((size_t)(b*DI_ + nc))*L_ + l] = dt;
        }
    }
}

// ---------------- selective scan: thread=(d,n), 16-lane shfl reduce over n ----------------
__global__ __launch_bounds__(256) void scan_kernel(
    const float* __restrict__ dtt, const float* __restrict__ ut,
    const float* __restrict__ bmt, const float* __restrict__ cmt,
    const float* __restrict__ Alog, const float* __restrict__ Dv,
    float* __restrict__ ys)
{
    const int blk = blockIdx.x;
    const int b = blk >> 5;                // 32 blocks per batch
    const int d0 = (blk & 31) * DS_;
    const int tid = threadIdx.x;
    const int n = tid & 15, dd = tid >> 4;
    const int d = d0 + dd;
    const float Ac = -__expf(Alog[d*DS_ + n]);
    const float Dd = Dv[d];
    const float* dtp = dtt + (size_t)(b*DI_ + d)*L_;
    const float* up  = ut  + (size_t)(b*DI_ + d)*L_;
    const float* bp  = bmt + (size_t)(b*DS_ + n)*L_;
    const float* cp  = cmt + (size_t)(b*DS_ + n)*L_;
    float* yrow = ys + (size_t)b*L_*DI_ + d;
    float s = 0.f;
    for (int l = 0; l < L_; l += 4) {
        float4 dt4 = *(const float4*)(dtp + l);
        float4 u4  = *(const float4*)(up + l);
        float4 b4  = *(const float4*)(bp + l);
        float4 c4  = *(const float4*)(cp + l);
        float dtv[4] = {dt4.x, dt4.y, dt4.z, dt4.w};
        float uv[4]  = {u4.x, u4.y, u4.z, u4.w};
        float bv[4]  = {b4.x, b4.y, b4.z, b4.w};
        float cv[4]  = {c4.x, c4.y, c4.z, c4.w};
        #pragma unroll
        for (int j = 0; j < 4; j++) {
            float e = __expf(dtv[j] * Ac);
            s = fmaf(e, s, dtv[j]*bv[j]*uv[j]);
            float y = s * cv[j];
            y += __shfl_xor(y, 1);
            y += __shfl_xor(y, 2);
            y += __shfl_xor(y, 4);
            y += __shfl_xor(y, 8);
            if (n == 0) yrow[(size_t)(l + j)*DI_] = fmaf(uv[j], Dd, y);
        }
    }
}

// ---------------- final LN + head dot ----------------
__global__ __launch_bounds__(256) void final_kernel(
    const float* __restrict__ h, const float* __restrict__ fw,
    const float* __restrict__ fb, const float* __restrict__ hw,
    const float* __restrict__ hb, float* __restrict__ out)
{
    __shared__ float sm[4];
    int row = blockIdx.x, tid = threadIdx.x;
    float v = h[(size_t)row*DM_ + tid];
    float s = v;
    #pragma unroll
    for (int o = 32; o > 0; o >>= 1) s += __shfl_down(s, o);
    if ((tid & 63) == 0) sm[tid >> 6] = s;
    __syncthreads();
    float mu = (sm[0]+sm[1]+sm[2]+sm[3]) * (1.f/DM_);
    __syncthreads();
    float dv = v - mu;
    float q = dv*dv;
    #pragma unroll
    for (int o = 32; o > 0; o >>= 1) q += __shfl_down(q, o);
    if ((tid & 63) == 0) sm[tid >> 6] = q;
    __syncthreads();
    float var = (sm[0]+sm[1]+sm[2]+sm[3]) * (1.f/DM_);
    float nv = dv * rsqrtf(var + 1e-5f) * fw[tid] + fb[tid];
    float p = nv * hw[tid];
    __syncthreads();
    #pragma unroll
    for (int o = 32; o > 0; o >>= 1) p += __shfl_down(p, o);
    if ((tid & 63) == 0) sm[tid >> 6] = p;
    __syncthreads();
    if (tid == 0) out[row] = sm[0]+sm[1]+sm[2]+sm[3] + hb[0];
}

extern "C" void kernel_launch(void* const* d_in, const int* in_sizes, int n_in,
                              void* d_out, int out_size, void* d_ws, size_t ws_size,
                              hipStream_t stream)
{
    const float* x    = (const float*)d_in[0];
    const float* biw  = (const float*)d_in[1];
    const float* bib  = (const float*)d_in[2];
    const float* ge   = (const float*)d_in[3];
    const float* me   = (const float*)d_in[4];
    const float* lnw  = (const float*)d_in[5];
    const float* lnb  = (const float*)d_in[6];
    const float* ipw  = (const float*)d_in[7];
    const float* cw   = (const float*)d_in[8];
    const float* cb   = (const float*)d_in[9];
    const float* xpw  = (const float*)d_in[10];
    const float* dtw  = (const float*)d_in[11];
    const float* dtb  = (const float*)d_in[12];
    const float* alog = (const float*)d_in[13];
    const float* Dv   = (const float*)d_in[14];
    const float* opw  = (const float*)d_in[15];
    const float* fw   = (const float*)d_in[16];
    const float* fb   = (const float*)d_in[17];
    const float* hw   = (const float*)d_in[18];
    const float* hb   = (const float*)d_in[19];
    float* out = (float*)d_out;

    // workspace layout (floats); total ~14.71M floats = 58.9 MB
    float* ws  = (float*)d_ws;
    float* h   = ws;
    float* hn  = h   + (size_t)BLP_*DM_;
    float* xz  = hn  + (size_t)BLP_*DM_;
    float* u   = xz  + (size_t)BLP_*1024;
    float* ut  = u   + (size_t)BLP_*DI_;
    float* dtt = ut  + (size_t)B_*DI_*L_;
    float* bmt = dtt + (size_t)B_*DI_*L_;
    float* cmt = bmt + (size_t)B_*DS_*L_;
    float* ysb = cmt + (size_t)B_*DS_*L_;

    embed_kernel<<<BL_, 256, 0, stream>>>(x, biw, bib, ge, me, h);
    for (int i = 0; i < NL_; i++) {
        ln_kernel<<<BL_, 256, 0, stream>>>(h, lnw + i*DM_, lnb + i*DM_, hn);
        gemm64<false,false><<<dim3(BLP_/64, 1024/64), 256, 0, stream>>>(
            hn, nullptr, 0, ipw + (size_t)i*1024*DM_, xz, 1024, DM_);
        conv_silu_kernel<<<BL_, 256, 0, stream>>>(xz, cw + i*DI_*4, cb + i*DI_, u, ut);
        xproj_dt_kernel<<<BLP_/64, 256, 0, stream>>>(
            u, xpw + (size_t)i*48*DI_, dtw + (size_t)i*DI_*16, dtb + i*DI_,
            bmt, cmt, dtt);
        scan_kernel<<<B_*(DI_/DS_), 256, 0, stream>>>(
            dtt, ut, bmt, cmt, alog + (size_t)i*DI_*DS_, Dv + i*DI_, ysb);
        gemm64<true,true><<<dim3(BLP_/64, DM_/64), 256, 0, stream>>>(
            ysb, xz + 512, 1024, opw + (size_t)i*DM_*DI_, h, DM_, DI_);
    }
    final_kernel<<<BL_, 256, 0, stream>>>(h, fw, fb, hw, hb, out);
}

// Round 2
// 1084.118 us; speedup vs baseline: 2.2422x; 2.2422x over previous
//
#include <hip/hip_runtime.h>
#include <math.h>

#define B_  2
#define L_  2000
#define DM_ 256
#define DI_ 512
#define DS_ 16
#define NL_ 4
#define BL_ (B_*L_)     // 4000
#define BLP_ 4096       // rows padded to multiple of 64
#define NC_ 20          // scan chunks
#define CL_ 100         // chunk length (L_ = NC_*CL_, CL_%4==0)

__device__ __forceinline__ float siluf(float x) {
    return x / (1.f + __expf(-x));
}

// ---------------- embed: h = x*biw + bib + gene_emb + mod_emb ----------------
__global__ __launch_bounds__(256) void embed_kernel(
    const float* __restrict__ x, const float* __restrict__ biw,
    const float* __restrict__ bib, const float* __restrict__ ge,
    const float* __restrict__ me, float* __restrict__ h)
{
    int bl = blockIdx.x, d = threadIdx.x;
    int l = bl % L_;
    h[(size_t)bl*DM_ + d] = x[bl]*biw[d] + bib[d] + ge[(size_t)l*DM_ + d] + me[d];
}

// ---------------- layernorm over D_MODEL=256, one block per row ----------------
__global__ __launch_bounds__(256) void ln_kernel(
    const float* __restrict__ h, const float* __restrict__ w,
    const float* __restrict__ b, float* __restrict__ out)
{
    __shared__ float sm[4];
    int row = blockIdx.x, tid = threadIdx.x;
    float v = h[(size_t)row*DM_ + tid];
    float s = v;
    #pragma unroll
    for (int o = 32; o > 0; o >>= 1) s += __shfl_down(s, o);
    if ((tid & 63) == 0) sm[tid >> 6] = s;
    __syncthreads();
    float mu = (sm[0]+sm[1]+sm[2]+sm[3]) * (1.f/DM_);
    __syncthreads();
    float d = v - mu;
    float q = d*d;
    #pragma unroll
    for (int o = 32; o > 0; o >>= 1) q += __shfl_down(q, o);
    if ((tid & 63) == 0) sm[tid >> 6] = q;
    __syncthreads();
    float var = (sm[0]+sm[1]+sm[2]+sm[3]) * (1.f/DM_);
    out[(size_t)row*DM_ + tid] = d * rsqrtf(var + 1e-5f) * w[tid] + b[tid];
}

// ---------------- generic fp32 GEMM: C[m,n] (+)= sum_k A[m,k]*W[n,k] ----------------
// 64x64 tile, K in chunks of 64, 256 threads, 4x4 register blocking.
// FUSE_SILU: A_eff[m,k] = A[m,k] * silu(Z[m*ldz + k])   (for out_proj: y * silu(z))
template<bool FUSE_SILU, bool ACCUM>
__global__ __launch_bounds__(256) void gemm64(
    const float* __restrict__ A, const float* __restrict__ Z, int ldz,
    const float* __restrict__ W, float* __restrict__ C, int ldc, int K)
{
    __shared__ float a_s[64][68];
    __shared__ float w_s[64][68];
    const int r0 = blockIdx.x * 64, c0 = blockIdx.y * 64;
    const int tid = threadIdx.x;
    const int tx = tid & 15, ty = tid >> 4;
    const int lrow = tid >> 2, lk0 = (tid & 3) * 16;
    float acc[4][4] = {};
    for (int kc = 0; kc < K; kc += 64) {
        const float* Ap = A + (size_t)(r0 + lrow)*K + kc + lk0;
        float4 av[4];
        #pragma unroll
        for (int q = 0; q < 4; q++) av[q] = *(const float4*)(Ap + 4*q);
        if constexpr (FUSE_SILU) {
            const float* Zp = Z + (size_t)(r0 + lrow)*ldz + kc + lk0;
            #pragma unroll
            for (int q = 0; q < 4; q++) {
                float4 zv = *(const float4*)(Zp + 4*q);
                av[q].x *= siluf(zv.x);
                av[q].y *= siluf(zv.y);
                av[q].z *= siluf(zv.z);
                av[q].w *= siluf(zv.w);
            }
        }
        const float* Wp = W + (size_t)(c0 + lrow)*K + kc + lk0;
        float4 wv[4];
        #pragma unroll
        for (int q = 0; q < 4; q++) wv[q] = *(const float4*)(Wp + 4*q);
        #pragma unroll
        for (int q = 0; q < 4; q++) *(float4*)&a_s[lrow][lk0 + 4*q] = av[q];
        #pragma unroll
        for (int q = 0; q < 4; q++) *(float4*)&w_s[lrow][lk0 + 4*q] = wv[q];
        __syncthreads();
        #pragma unroll
        for (int k4 = 0; k4 < 64; k4 += 4) {
            float4 af[4], wf[4];
            #pragma unroll
            for (int i = 0; i < 4; i++) af[i] = *(const float4*)&a_s[ty + 16*i][k4];
            #pragma unroll
            for (int j = 0; j < 4; j++) wf[j] = *(const float4*)&w_s[tx + 16*j][k4];
            #pragma unroll
            for (int i = 0; i < 4; i++) {
                #pragma unroll
                for (int j = 0; j < 4; j++) {
                    acc[i][j] = fmaf(af[i].x, wf[j].x, acc[i][j]);
                    acc[i][j] = fmaf(af[i].y, wf[j].y, acc[i][j]);
                    acc[i][j] = fmaf(af[i].z, wf[j].z, acc[i][j]);
                    acc[i][j] = fmaf(af[i].w, wf[j].w, acc[i][j]);
                }
            }
        }
        __syncthreads();
    }
    #pragma unroll
    for (int i = 0; i < 4; i++) {
        #pragma unroll
        for (int j = 0; j < 4; j++) {
            size_t idx = (size_t)(r0 + ty + 16*i)*ldc + (c0 + tx + 16*j);
            if constexpr (ACCUM) C[idx] += acc[i][j]; else C[idx] = acc[i][j];
        }
    }
}

// ---------------- depthwise causal conv(4) + silu; writes u (b,l,c) and ut (b,c,l) ----------------
__global__ __launch_bounds__(256) void conv_silu_kernel(
    const float* __restrict__ xz, const float* __restrict__ cw,
    const float* __restrict__ cb, float* __restrict__ u, float* __restrict__ ut)
{
    int bl = blockIdx.x, tid = threadIdx.x;
    int b = bl / L_, l = bl % L_;
    #pragma unroll
    for (int cc = 0; cc < 2; cc++) {
        int c = tid + cc*256;
        float acc = cb[c];
        #pragma unroll
        for (int k = 0; k < 4; k++) {
            int ls = l + k - 3;
            if (ls >= 0) acc = fmaf(xz[(size_t)(b*L_ + ls)*1024 + c], cw[c*4 + k], acc);
        }
        float s = siluf(acc);
        u[(size_t)bl*DI_ + c] = s;
        ut[((size_t)(b*DI_ + c))*L_ + l] = s;
    }
}

// ---------------- fused x_proj (N=48,K=512) + dt_proj (N=512,K=16) + softplus ----------------
// Writes Bm/Cm transposed (b,n,l) and dt transposed (b,d,l).
__global__ __launch_bounds__(256) void xproj_dt_kernel(
    const float* __restrict__ U, const float* __restrict__ XW,
    const float* __restrict__ DTW, const float* __restrict__ DTB,
    float* __restrict__ bmt, float* __restrict__ cmt, float* __restrict__ dtt)
{
    __shared__ float a_s[64][68];
    __shared__ float w_s[48][68];
    __shared__ __align__(16) float dtr_s[64][16];
    const int r0 = blockIdx.x * 64;
    const int tid = threadIdx.x;
    const int tx = tid & 15, ty = tid >> 4;
    const int lrow = tid >> 2, lk0 = (tid & 3) * 16;
    float acc[4][3] = {};
    for (int kc = 0; kc < 512; kc += 64) {
        const float* Ap = U + (size_t)(r0 + lrow)*512 + kc + lk0;
        float4 av[4];
        #pragma unroll
        for (int q = 0; q < 4; q++) av[q] = *(const float4*)(Ap + 4*q);
        #pragma unroll
        for (int q = 0; q < 4; q++) *(float4*)&a_s[lrow][lk0 + 4*q] = av[q];
        if (lrow < 48) {
            const float* Wp = XW + (size_t)lrow*512 + kc + lk0;
            #pragma unroll
            for (int q = 0; q < 4; q++) *(float4*)&w_s[lrow][lk0 + 4*q] = *(const float4*)(Wp + 4*q);
        }
        __syncthreads();
        #pragma unroll
        for (int k4 = 0; k4 < 64; k4 += 4) {
            float4 af[4], wf[3];
            #pragma unroll
            for (int i = 0; i < 4; i++) af[i] = *(const float4*)&a_s[ty + 16*i][k4];
            #pragma unroll
            for (int j = 0; j < 3; j++) wf[j] = *(const float4*)&w_s[tx + 16*j][k4];
            #pragma unroll
            for (int i = 0; i < 4; i++) {
                #pragma unroll
                for (int j = 0; j < 3; j++) {
                    acc[i][j] = fmaf(af[i].x, wf[j].x, acc[i][j]);
                    acc[i][j] = fmaf(af[i].y, wf[j].y, acc[i][j]);
                    acc[i][j] = fmaf(af[i].z, wf[j].z, acc[i][j]);
                    acc[i][j] = fmaf(af[i].w, wf[j].w, acc[i][j]);
                }
            }
        }
        __syncthreads();
    }
    // scatter: dt_r -> LDS, Bm/Cm -> global transposed
    #pragma unroll
    for (int i = 0; i < 4; i++) {
        int rr = ty + 16*i, bl = r0 + rr;
        int b = bl / L_, l = bl % L_;
        dtr_s[rr][tx] = acc[i][0];
        if (bl < BL_) {
            bmt[((size_t)(b*DS_ + tx))*L_ + l] = acc[i][1];
            cmt[((size_t)(b*DS_ + tx))*L_ + l] = acc[i][2];
        }
    }
    __syncthreads();
    // phase 2: dt = softplus(dt_r @ DTW^T + DTB), write transposed (b,d,l)
    #pragma unroll
    for (int c2 = 0; c2 < 2; c2++) {
        int nc = tid + c2*256;
        float wreg[16];
        #pragma unroll
        for (int r = 0; r < 16; r++) wreg[r] = DTW[nc*16 + r];
        float bias = DTB[nc];
        int rmax = BL_ - r0; if (rmax > 64) rmax = 64;
        for (int rr = 0; rr < rmax; rr++) {
            int bl = r0 + rr, b = bl / L_, l = bl % L_;
            float acc2 = bias;
            const float4* dp = (const float4*)&dtr_s[rr][0];
            #pragma unroll
            for (int r4 = 0; r4 < 4; r4++) {
                float4 dv = dp[r4];
                acc2 = fmaf(dv.x, wreg[4*r4+0], acc2);
                acc2 = fmaf(dv.y, wreg[4*r4+1], acc2);
                acc2 = fmaf(dv.z, wreg[4*r4+2], acc2);
                acc2 = fmaf(dv.w, wreg[4*r4+3], acc2);
            }
            float dt = acc2 > 20.f ? acc2 : log1pf(__expf(acc2));
            dtt[((size_t)(b*DI_ + nc))*L_ + l] = dt;
        }
    }
}

// ---------------- chunked selective scan ----------------
// grid(NC_, 32, B_), block 256 = 16 d x 16 n. Phase 1: chunk-local end state
// (zero init) + chunk gain prod(e). No C load, no shuffles.
__global__ __launch_bounds__(256) void scan_phase1(
    const float* __restrict__ dtt, const float* __restrict__ ut,
    const float* __restrict__ bmt, const float* __restrict__ Alog,
    float* __restrict__ send, float* __restrict__ aprod)
{
    const int c = blockIdx.x, g = blockIdx.y, b = blockIdx.z;
    const int tid = threadIdx.x;
    const int n = tid & 15, dd = tid >> 4;
    const int d = g*16 + dd;
    const float Ac = -__expf(Alog[d*DS_ + n]);
    const int l0 = c * CL_;
    const float* dtp = dtt + (size_t)(b*DI_ + d)*L_ + l0;
    const float* up  = ut  + (size_t)(b*DI_ + d)*L_ + l0;
    const float* bp  = bmt + (size_t)(b*DS_ + n)*L_ + l0;
    float s = 0.f, ap = 1.f;
    for (int l = 0; l < CL_; l += 4) {
        float4 dt4 = *(const float4*)(dtp + l);
        float4 u4  = *(const float4*)(up + l);
        float4 b4  = *(const float4*)(bp + l);
        float dtv[4] = {dt4.x, dt4.y, dt4.z, dt4.w};
        float uv[4]  = {u4.x, u4.y, u4.z, u4.w};
        float bv[4]  = {b4.x, b4.y, b4.z, b4.w};
        #pragma unroll
        for (int j = 0; j < 4; j++) {
            float e = __expf(dtv[j] * Ac);
            s = fmaf(e, s, dtv[j]*bv[j]*uv[j]);
            ap *= e;
        }
    }
    size_t idx = ((size_t)(b*DI_ + d)*DS_ + n)*NC_ + c;
    send[idx]  = s;
    aprod[idx] = ap;
}

// Phase 2: sequential carry over chunks; in-place converts send -> s_in per chunk.
__global__ __launch_bounds__(256) void scan_phase2(
    float* __restrict__ send, const float* __restrict__ aprod)
{
    int t = blockIdx.x*256 + threadIdx.x;   // B_*DI_*DS_ = 16384 threads
    size_t base = (size_t)t * NC_;
    float s = 0.f;
    #pragma unroll
    for (int c = 0; c < NC_; c++) {
        float tmp = send[base + c];
        send[base + c] = s;                 // state entering chunk c
        s = fmaf(aprod[base + c], s, tmp);
    }
}

// Phase 3: re-run chunk with correct incoming state, produce y (+ u*D).
__global__ __launch_bounds__(256) void scan_phase3(
    const float* __restrict__ dtt, const float* __restrict__ ut,
    const float* __restrict__ bmt, const float* __restrict__ cmt,
    const float* __restrict__ Alog, const float* __restrict__ Dv,
    const float* __restrict__ sin_, float* __restrict__ ys)
{
    const int c = blockIdx.x, g = blockIdx.y, b = blockIdx.z;
    const int tid = threadIdx.x;
    const int n = tid & 15, dd = tid >> 4;
    const int d = g*16 + dd;
    const float Ac = -__expf(Alog[d*DS_ + n]);
    const float Dd = Dv[d];
    const int l0 = c * CL_;
    const float* dtp = dtt + (size_t)(b*DI_ + d)*L_ + l0;
    const float* up  = ut  + (size_t)(b*DI_ + d)*L_ + l0;
    const float* bp  = bmt + (size_t)(b*DS_ + n)*L_ + l0;
    const float* cp  = cmt + (size_t)(b*DS_ + n)*L_ + l0;
    float* yrow = ys + (size_t)b*L_*DI_ + (size_t)l0*DI_ + d;
    float s = sin_[((size_t)(b*DI_ + d)*DS_ + n)*NC_ + c];
    for (int l = 0; l < CL_; l += 4) {
        float4 dt4 = *(const float4*)(dtp + l);
        float4 u4  = *(const float4*)(up + l);
        float4 b4  = *(const float4*)(bp + l);
        float4 c4  = *(const float4*)(cp + l);
        float dtv[4] = {dt4.x, dt4.y, dt4.z, dt4.w};
        float uv[4]  = {u4.x, u4.y, u4.z, u4.w};
        float bv[4]  = {b4.x, b4.y, b4.z, b4.w};
        float cv[4]  = {c4.x, c4.y, c4.z, c4.w};
        #pragma unroll
        for (int j = 0; j < 4; j++) {
            float e = __expf(dtv[j] * Ac);
            s = fmaf(e, s, dtv[j]*bv[j]*uv[j]);
            float y = s * cv[j];
            y += __shfl_xor(y, 1);
            y += __shfl_xor(y, 2);
            y += __shfl_xor(y, 4);
            y += __shfl_xor(y, 8);
            if (n == 0) yrow[(size_t)(l + j)*DI_] = fmaf(uv[j], Dd, y);
        }
    }
}

// ---------------- final LN + head dot ----------------
__global__ __launch_bounds__(256) void final_kernel(
    const float* __restrict__ h, const float* __restrict__ fw,
    const float* __restrict__ fb, const float* __restrict__ hw,
    const float* __restrict__ hb, float* __restrict__ out)
{
    __shared__ float sm[4];
    int row = blockIdx.x, tid = threadIdx.x;
    float v = h[(size_t)row*DM_ + tid];
    float s = v;
    #pragma unroll
    for (int o = 32; o > 0; o >>= 1) s += __shfl_down(s, o);
    if ((tid & 63) == 0) sm[tid >> 6] = s;
    __syncthreads();
    float mu = (sm[0]+sm[1]+sm[2]+sm[3]) * (1.f/DM_);
    __syncthreads();
    float dv = v - mu;
    float q = dv*dv;
    #pragma unroll
    for (int o = 32; o > 0; o >>= 1) q += __shfl_down(q, o);
    if ((tid & 63) == 0) sm[tid >> 6] = q;
    __syncthreads();
    float var = (sm[0]+sm[1]+sm[2]+sm[3]) * (1.f/DM_);
    float nv = dv * rsqrtf(var + 1e-5f) * fw[tid] + fb[tid];
    float p = nv * hw[tid];
    __syncthreads();
    #pragma unroll
    for (int o = 32; o > 0; o >>= 1) p += __shfl_down(p, o);
    if ((tid & 63) == 0) sm[tid >> 6] = p;
    __syncthreads();
    if (tid == 0) out[row] = sm[0]+sm[1]+sm[2]+sm[3] + hb[0];
}

extern "C" void kernel_launch(void* const* d_in, const int* in_sizes, int n_in,
                              void* d_out, int out_size, void* d_ws, size_t ws_size,
                              hipStream_t stream)
{
    const float* x    = (const float*)d_in[0];
    const float* biw  = (const float*)d_in[1];
    const float* bib  = (const float*)d_in[2];
    const float* ge   = (const float*)d_in[3];
    const float* me   = (const float*)d_in[4];
    const float* lnw  = (const float*)d_in[5];
    const float* lnb  = (const float*)d_in[6];
    const float* ipw  = (const float*)d_in[7];
    const float* cw   = (const float*)d_in[8];
    const float* cb   = (const float*)d_in[9];
    const float* xpw  = (const float*)d_in[10];
    const float* dtw  = (const float*)d_in[11];
    const float* dtb  = (const float*)d_in[12];
    const float* alog = (const float*)d_in[13];
    const float* Dv   = (const float*)d_in[14];
    const float* opw  = (const float*)d_in[15];
    const float* fw   = (const float*)d_in[16];
    const float* fb   = (const float*)d_in[17];
    const float* hw   = (const float*)d_in[18];
    const float* hb   = (const float*)d_in[19];
    float* out = (float*)d_out;

    // workspace layout (floats); total ~14.71M floats = 58.9 MB
    float* ws  = (float*)d_ws;
    float* h   = ws;
    float* hn  = h   + (size_t)BLP_*DM_;
    float* xz  = hn  + (size_t)BLP_*DM_;
    float* u   = xz  + (size_t)BLP_*1024;
    float* ut  = u   + (size_t)BLP_*DI_;
    float* dtt = ut  + (size_t)B_*DI_*L_;
    float* bmt = dtt + (size_t)B_*DI_*L_;
    float* cmt = bmt + (size_t)B_*DS_*L_;
    float* ysb = cmt + (size_t)B_*DS_*L_;
    // scan carry buffers alias hn (dead between in_proj gemm and next ln):
    // need 2 * B*DI*DS*NC = 655,360 floats <= BLP_*DM_ = 1,048,576.  OK.
    float* send  = hn;
    float* aprod = hn + (size_t)B_*DI_*DS_*NC_;

    embed_kernel<<<BL_, 256, 0, stream>>>(x, biw, bib, ge, me, h);
    for (int i = 0; i < NL_; i++) {
        ln_kernel<<<BL_, 256, 0, stream>>>(h, lnw + i*DM_, lnb + i*DM_, hn);
        gemm64<false,false><<<dim3(BLP_/64, 1024/64), 256, 0, stream>>>(
            hn, nullptr, 0, ipw + (size_t)i*1024*DM_, xz, 1024, DM_);
        conv_silu_kernel<<<BL_, 256, 0, stream>>>(xz, cw + i*DI_*4, cb + i*DI_, u, ut);
        xproj_dt_kernel<<<BLP_/64, 256, 0, stream>>>(
            u, xpw + (size_t)i*48*DI_, dtw + (size_t)i*DI_*16, dtb + i*DI_,
            bmt, cmt, dtt);
        scan_phase1<<<dim3(NC_, DI_/16, B_), 256, 0, stream>>>(
            dtt, ut, bmt, alog + (size_t)i*DI_*DS_, send, aprod);
        scan_phase2<<<B_*DI_*DS_/256, 256, 0, stream>>>(send, aprod);
        scan_phase3<<<dim3(NC_, DI_/16, B_), 256, 0, stream>>>(
            dtt, ut, bmt, cmt, alog + (size_t)i*DI_*DS_, Dv + i*DI_,
            send, ysb);
        gemm64<true,true><<<dim3(BLP_/64, DM_/64), 256, 0, stream>>>(
            ysb, xz + 512, 1024, opw + (size_t)i*DM_*DI_, h, DM_, DI_);
    }
    final_kernel<<<BL_, 256, 0, stream>>>(h, fw, fb, hw, hb, out);
}

// Round 3
// 933.848 us; speedup vs baseline: 2.6030x; 1.1609x over previous
//
#include <hip/hip_runtime.h>
#include <math.h>

#define B_  2
#define L_  2000
#define DM_ 256
#define DI_ 512
#define DS_ 16
#define NL_ 4
#define BL_ (B_*L_)     // 4000
#define BLP_ 4096       // rows padded to multiple of 64
#define NC_ 20          // scan chunks
#define CL_ 100         // chunk length (L_ = NC_*CL_, CL_%4==0)

__device__ __forceinline__ float siluf(float x) {
    return x / (1.f + __expf(-x));
}

// ---------------- embed: h = x*biw + bib + gene_emb + mod_emb ----------------
__global__ __launch_bounds__(256) void embed_kernel(
    const float* __restrict__ x, const float* __restrict__ biw,
    const float* __restrict__ bib, const float* __restrict__ ge,
    const float* __restrict__ me, float* __restrict__ h)
{
    int bl = blockIdx.x, d = threadIdx.x;
    int l = bl % L_;
    h[(size_t)bl*DM_ + d] = x[bl]*biw[d] + bib[d] + ge[(size_t)l*DM_ + d] + me[d];
}

// ---------------- layernorm over D_MODEL=256, one block per row ----------------
__global__ __launch_bounds__(256) void ln_kernel(
    const float* __restrict__ h, const float* __restrict__ w,
    const float* __restrict__ b, float* __restrict__ out)
{
    __shared__ float sm[4];
    int row = blockIdx.x, tid = threadIdx.x;
    float v = h[(size_t)row*DM_ + tid];
    float s = v;
    #pragma unroll
    for (int o = 32; o > 0; o >>= 1) s += __shfl_down(s, o);
    if ((tid & 63) == 0) sm[tid >> 6] = s;
    __syncthreads();
    float mu = (sm[0]+sm[1]+sm[2]+sm[3]) * (1.f/DM_);
    __syncthreads();
    float d = v - mu;
    float q = d*d;
    #pragma unroll
    for (int o = 32; o > 0; o >>= 1) q += __shfl_down(q, o);
    if ((tid & 63) == 0) sm[tid >> 6] = q;
    __syncthreads();
    float var = (sm[0]+sm[1]+sm[2]+sm[3]) * (1.f/DM_);
    out[(size_t)row*DM_ + tid] = d * rsqrtf(var + 1e-5f) * w[tid] + b[tid];
}

// ---------------- generic fp32 GEMM: C[m,n] (+)= sum_k A[m,k]*W[n,k] ----------------
// 64x64 tile, K in chunks of 64, 256 threads, 4x4 register blocking.
// FUSE_SILU: A_eff[m,k] = A[m,k] * silu(Z[m*ldz + k])   (for out_proj: y * silu(z))
template<bool FUSE_SILU, bool ACCUM>
__global__ __launch_bounds__(256) void gemm64(
    const float* __restrict__ A, const float* __restrict__ Z, int ldz,
    const float* __restrict__ W, float* __restrict__ C, int ldc, int K)
{
    __shared__ float a_s[64][68];
    __shared__ float w_s[64][68];
    const int r0 = blockIdx.x * 64, c0 = blockIdx.y * 64;
    const int tid = threadIdx.x;
    const int tx = tid & 15, ty = tid >> 4;
    const int lrow = tid >> 2, lk0 = (tid & 3) * 16;
    float acc[4][4] = {};
    for (int kc = 0; kc < K; kc += 64) {
        const float* Ap = A + (size_t)(r0 + lrow)*K + kc + lk0;
        float4 av[4];
        #pragma unroll
        for (int q = 0; q < 4; q++) av[q] = *(const float4*)(Ap + 4*q);
        if constexpr (FUSE_SILU) {
            const float* Zp = Z + (size_t)(r0 + lrow)*ldz + kc + lk0;
            #pragma unroll
            for (int q = 0; q < 4; q++) {
                float4 zv = *(const float4*)(Zp + 4*q);
                av[q].x *= siluf(zv.x);
                av[q].y *= siluf(zv.y);
                av[q].z *= siluf(zv.z);
                av[q].w *= siluf(zv.w);
            }
        }
        const float* Wp = W + (size_t)(c0 + lrow)*K + kc + lk0;
        float4 wv[4];
        #pragma unroll
        for (int q = 0; q < 4; q++) wv[q] = *(const float4*)(Wp + 4*q);
        #pragma unroll
        for (int q = 0; q < 4; q++) *(float4*)&a_s[lrow][lk0 + 4*q] = av[q];
        #pragma unroll
        for (int q = 0; q < 4; q++) *(float4*)&w_s[lrow][lk0 + 4*q] = wv[q];
        __syncthreads();
        #pragma unroll
        for (int k4 = 0; k4 < 64; k4 += 4) {
            float4 af[4], wf[4];
            #pragma unroll
            for (int i = 0; i < 4; i++) af[i] = *(const float4*)&a_s[ty + 16*i][k4];
            #pragma unroll
            for (int j = 0; j < 4; j++) wf[j] = *(const float4*)&w_s[tx + 16*j][k4];
            #pragma unroll
            for (int i = 0; i < 4; i++) {
                #pragma unroll
                for (int j = 0; j < 4; j++) {
                    acc[i][j] = fmaf(af[i].x, wf[j].x, acc[i][j]);
                    acc[i][j] = fmaf(af[i].y, wf[j].y, acc[i][j]);
                    acc[i][j] = fmaf(af[i].z, wf[j].z, acc[i][j]);
                    acc[i][j] = fmaf(af[i].w, wf[j].w, acc[i][j]);
                }
            }
        }
        __syncthreads();
    }
    #pragma unroll
    for (int i = 0; i < 4; i++) {
        #pragma unroll
        for (int j = 0; j < 4; j++) {
            size_t idx = (size_t)(r0 + ty + 16*i)*ldc + (c0 + tx + 16*j);
            if constexpr (ACCUM) C[idx] += acc[i][j]; else C[idx] = acc[i][j];
        }
    }
}

// ---------------- depthwise causal conv(4) + silu; writes u (b,l,c) and ut (b,c,l) ----------------
__global__ __launch_bounds__(256) void conv_silu_kernel(
    const float* __restrict__ xz, const float* __restrict__ cw,
    const float* __restrict__ cb, float* __restrict__ u, float* __restrict__ ut)
{
    int bl = blockIdx.x, tid = threadIdx.x;
    int b = bl / L_, l = bl % L_;
    #pragma unroll
    for (int cc = 0; cc < 2; cc++) {
        int c = tid + cc*256;
        float acc = cb[c];
        #pragma unroll
        for (int k = 0; k < 4; k++) {
            int ls = l + k - 3;
            if (ls >= 0) acc = fmaf(xz[(size_t)(b*L_ + ls)*1024 + c], cw[c*4 + k], acc);
        }
        float s = siluf(acc);
        u[(size_t)bl*DI_ + c] = s;
        ut[((size_t)(b*DI_ + c))*L_ + l] = s;
    }
}

// ---------------- fused x_proj (N=48,K=512) + dt_proj (N=512,K=16) + softplus ----------------
// 16-row M-tile, 256 blocks. K staged in chunks of 128 (A and W both in LDS).
// Thread (r = tid>>4, cg = tid&15) computes cols 3cg..3cg+2 of row r.
// Writes Bm/Cm transposed (b,n,l); dt via fused dt_proj phase, transposed (b,d,l).
__global__ __launch_bounds__(256) void xproj_dt_kernel(
    const float* __restrict__ U, const float* __restrict__ XW,
    const float* __restrict__ DTW, const float* __restrict__ DTB,
    float* __restrict__ bmt, float* __restrict__ cmt, float* __restrict__ dtt)
{
    __shared__ float a_s[16][132];   // stride 132: rows 4 banks apart
    __shared__ float w_s[48][132];
    __shared__ float dtr_s[16][16];
    const int r0 = blockIdx.x * 16;
    const int tid = threadIdx.x;
    const int r = tid >> 4, cg = tid & 15;
    float acc[3] = {};
    for (int kc = 0; kc < 512; kc += 128) {
        // stage A: 16x128 = 512 float4, 2 per thread
        #pragma unroll
        for (int q = 0; q < 2; q++) {
            int f = tid + 256*q;
            int row = f >> 5, c4 = (f & 31) * 4;
            *(float4*)&a_s[row][c4] = *(const float4*)(U + (size_t)(r0 + row)*512 + kc + c4);
        }
        // stage W: 48x128 = 1536 float4, 6 per thread
        #pragma unroll
        for (int q = 0; q < 6; q++) {
            int f = tid + 256*q;
            int row = f >> 5, c4 = (f & 31) * 4;
            *(float4*)&w_s[row][c4] = *(const float4*)(XW + (size_t)row*512 + kc + c4);
        }
        __syncthreads();
        #pragma unroll
        for (int kq = 0; kq < 32; kq++) {
            float4 av = *(const float4*)&a_s[r][4*kq];
            #pragma unroll
            for (int j = 0; j < 3; j++) {
                float4 wv = *(const float4*)&w_s[3*cg + j][4*kq];
                acc[j] = fmaf(av.x, wv.x, acc[j]);
                acc[j] = fmaf(av.y, wv.y, acc[j]);
                acc[j] = fmaf(av.z, wv.z, acc[j]);
                acc[j] = fmaf(av.w, wv.w, acc[j]);
            }
        }
        __syncthreads();
    }
    // scatter: dt_r cols -> LDS; Bm/Cm cols -> global transposed
    {
        int bl = r0 + r;
        int b = bl / L_, l = bl % L_;
        bool valid = bl < BL_;
        #pragma unroll
        for (int j = 0; j < 3; j++) {
            int c = 3*cg + j;
            if (c < 16) dtr_s[r][c] = acc[j];
            else if (valid) {
                if (c < 32) bmt[((size_t)(b*DS_ + (c-16)))*L_ + l] = acc[j];
                else        cmt[((size_t)(b*DS_ + (c-32)))*L_ + l] = acc[j];
            }
        }
    }
    __syncthreads();
    // fused dt_proj: dt = softplus(dt_r @ DTW^T + DTB); 2 cols/thread x 16 rows
    #pragma unroll
    for (int q = 0; q < 2; q++) {
        int c = tid + q*256;
        float wreg[16];
        const float4* wp = (const float4*)(DTW + (size_t)c*16);
        #pragma unroll
        for (int k4 = 0; k4 < 4; k4++) {
            float4 wv = wp[k4];
            wreg[4*k4+0] = wv.x; wreg[4*k4+1] = wv.y;
            wreg[4*k4+2] = wv.z; wreg[4*k4+3] = wv.w;
        }
        float bias = DTB[c];
        #pragma unroll 4
        for (int rr = 0; rr < 16; rr++) {
            int bl2 = r0 + rr;
            if (bl2 >= BL_) break;
            int b2 = bl2 / L_, l2 = bl2 % L_;
            float acc2 = bias;
            #pragma unroll
            for (int k = 0; k < 16; k++) acc2 = fmaf(dtr_s[rr][k], wreg[k], acc2);
            float dt = acc2 > 20.f ? acc2 : log1pf(__expf(acc2));
            dtt[((size_t)(b2*DI_ + c))*L_ + l2] = dt;
        }
    }
}

// ---------------- chunked selective scan ----------------
// grid(NC_, 32, B_), block 256 = 16 d x 16 n. Phase 1: chunk-local end state
// (zero init) + chunk gain prod(e). No C load, no shuffles.
__global__ __launch_bounds__(256) void scan_phase1(
    const float* __restrict__ dtt, const float* __restrict__ ut,
    const float* __restrict__ bmt, const float* __restrict__ Alog,
    float* __restrict__ send, float* __restrict__ aprod)
{
    const int c = blockIdx.x, g = blockIdx.y, b = blockIdx.z;
    const int tid = threadIdx.x;
    const int n = tid & 15, dd = tid >> 4;
    const int d = g*16 + dd;
    const float Ac = -__expf(Alog[d*DS_ + n]);
    const int l0 = c * CL_;
    const float* dtp = dtt + (size_t)(b*DI_ + d)*L_ + l0;
    const float* up  = ut  + (size_t)(b*DI_ + d)*L_ + l0;
    const float* bp  = bmt + (size_t)(b*DS_ + n)*L_ + l0;
    float s = 0.f, ap = 1.f;
    for (int l = 0; l < CL_; l += 4) {
        float4 dt4 = *(const float4*)(dtp + l);
        float4 u4  = *(const float4*)(up + l);
        float4 b4  = *(const float4*)(bp + l);
        float dtv[4] = {dt4.x, dt4.y, dt4.z, dt4.w};
        float uv[4]  = {u4.x, u4.y, u4.z, u4.w};
        float bv[4]  = {b4.x, b4.y, b4.z, b4.w};
        #pragma unroll
        for (int j = 0; j < 4; j++) {
            float e = __expf(dtv[j] * Ac);
            s = fmaf(e, s, dtv[j]*bv[j]*uv[j]);
            ap *= e;
        }
    }
    size_t idx = ((size_t)(b*DI_ + d)*DS_ + n)*NC_ + c;
    send[idx]  = s;
    aprod[idx] = ap;
}

// Phase 2: sequential carry over chunks; in-place converts send -> s_in per chunk.
__global__ __launch_bounds__(256) void scan_phase2(
    float* __restrict__ send, const float* __restrict__ aprod)
{
    int t = blockIdx.x*256 + threadIdx.x;   // B_*DI_*DS_ = 16384 threads
    size_t base = (size_t)t * NC_;
    float s = 0.f;
    #pragma unroll
    for (int c = 0; c < NC_; c++) {
        float tmp = send[base + c];
        send[base + c] = s;                 // state entering chunk c
        s = fmaf(aprod[base + c], s, tmp);
    }
}

// Phase 3: re-run chunk with correct incoming state, produce y (+ u*D).
__global__ __launch_bounds__(256) void scan_phase3(
    const float* __restrict__ dtt, const float* __restrict__ ut,
    const float* __restrict__ bmt, const float* __restrict__ cmt,
    const float* __restrict__ Alog, const float* __restrict__ Dv,
    const float* __restrict__ sin_, float* __restrict__ ys)
{
    const int c = blockIdx.x, g = blockIdx.y, b = blockIdx.z;
    const int tid = threadIdx.x;
    const int n = tid & 15, dd = tid >> 4;
    const int d = g*16 + dd;
    const float Ac = -__expf(Alog[d*DS_ + n]);
    const float Dd = Dv[d];
    const int l0 = c * CL_;
    const float* dtp = dtt + (size_t)(b*DI_ + d)*L_ + l0;
    const float* up  = ut  + (size_t)(b*DI_ + d)*L_ + l0;
    const float* bp  = bmt + (size_t)(b*DS_ + n)*L_ + l0;
    const float* cp  = cmt + (size_t)(b*DS_ + n)*L_ + l0;
    float* yrow = ys + (size_t)b*L_*DI_ + (size_t)l0*DI_ + d;
    float s = sin_[((size_t)(b*DI_ + d)*DS_ + n)*NC_ + c];
    for (int l = 0; l < CL_; l += 4) {
        float4 dt4 = *(const float4*)(dtp + l);
        float4 u4  = *(const float4*)(up + l);
        float4 b4  = *(const float4*)(bp + l);
        float4 c4  = *(const float4*)(cp + l);
        float dtv[4] = {dt4.x, dt4.y, dt4.z, dt4.w};
        float uv[4]  = {u4.x, u4.y, u4.z, u4.w};
        float bv[4]  = {b4.x, b4.y, b4.z, b4.w};
        float cv[4]  = {c4.x, c4.y, c4.z, c4.w};
        #pragma unroll
        for (int j = 0; j < 4; j++) {
            float e = __expf(dtv[j] * Ac);
            s = fmaf(e, s, dtv[j]*bv[j]*uv[j]);
            float y = s * cv[j];
            y += __shfl_xor(y, 1);
            y += __shfl_xor(y, 2);
            y += __shfl_xor(y, 4);
            y += __shfl_xor(y, 8);
            if (n == 0) yrow[(size_t)(l + j)*DI_] = fmaf(uv[j], Dd, y);
        }
    }
}

// ---------------- final LN + head dot ----------------
__global__ __launch_bounds__(256) void final_kernel(
    const float* __restrict__ h, const float* __restrict__ fw,
    const float* __restrict__ fb, const float* __restrict__ hw,
    const float* __restrict__ hb, float* __restrict__ out)
{
    __shared__ float sm[4];
    int row = blockIdx.x, tid = threadIdx.x;
    float v = h[(size_t)row*DM_ + tid];
    float s = v;
    #pragma unroll
    for (int o = 32; o > 0; o >>= 1) s += __shfl_down(s, o);
    if ((tid & 63) == 0) sm[tid >> 6] = s;
    __syncthreads();
    float mu = (sm[0]+sm[1]+sm[2]+sm[3]) * (1.f/DM_);
    __syncthreads();
    float dv = v - mu;
    float q = dv*dv;
    #pragma unroll
    for (int o = 32; o > 0; o >>= 1) q += __shfl_down(q, o);
    if ((tid & 63) == 0) sm[tid >> 6] = q;
    __syncthreads();
    float var = (sm[0]+sm[1]+sm[2]+sm[3]) * (1.f/DM_);
    float nv = dv * rsqrtf(var + 1e-5f) * fw[tid] + fb[tid];
    float p = nv * hw[tid];
    __syncthreads();
    #pragma unroll
    for (int o = 32; o > 0; o >>= 1) p += __shfl_down(p, o);
    if ((tid & 63) == 0) sm[tid >> 6] = p;
    __syncthreads();
    if (tid == 0) out[row] = sm[0]+sm[1]+sm[2]+sm[3] + hb[0];
}

extern "C" void kernel_launch(void* const* d_in, const int* in_sizes, int n_in,
                              void* d_out, int out_size, void* d_ws, size_t ws_size,
                              hipStream_t stream)
{
    const float* x    = (const float*)d_in[0];
    const float* biw  = (const float*)d_in[1];
    const float* bib  = (const float*)d_in[2];
    const float* ge   = (const float*)d_in[3];
    const float* me   = (const float*)d_in[4];
    const float* lnw  = (const float*)d_in[5];
    const float* lnb  = (const float*)d_in[6];
    const float* ipw  = (const float*)d_in[7];
    const float* cw   = (const float*)d_in[8];
    const float* cb   = (const float*)d_in[9];
    const float* xpw  = (const float*)d_in[10];
    const float* dtw  = (const float*)d_in[11];
    const float* dtb  = (const float*)d_in[12];
    const float* alog = (const float*)d_in[13];
    const float* Dv   = (const float*)d_in[14];
    const float* opw  = (const float*)d_in[15];
    const float* fw   = (const float*)d_in[16];
    const float* fb   = (const float*)d_in[17];
    const float* hw   = (const float*)d_in[18];
    const float* hb   = (const float*)d_in[19];
    float* out = (float*)d_out;

    // workspace layout (floats); total ~14.71M floats = 58.9 MB
    float* ws  = (float*)d_ws;
    float* h   = ws;
    float* hn  = h   + (size_t)BLP_*DM_;
    float* xz  = hn  + (size_t)BLP_*DM_;
    float* u   = xz  + (size_t)BLP_*1024;
    float* ut  = u   + (size_t)BLP_*DI_;
    float* dtt = ut  + (size_t)B_*DI_*L_;
    float* bmt = dtt + (size_t)B_*DI_*L_;
    float* cmt = bmt + (size_t)B_*DS_*L_;
    float* ysb = cmt + (size_t)B_*DS_*L_;
    // scan carry buffers alias hn (dead between in_proj gemm and next ln):
    // need 2 * B*DI*DS*NC = 655,360 floats <= BLP_*DM_ = 1,048,576.  OK.
    float* send  = hn;
    float* aprod = hn + (size_t)B_*DI_*DS_*NC_;

    embed_kernel<<<BL_, 256, 0, stream>>>(x, biw, bib, ge, me, h);
    for (int i = 0; i < NL_; i++) {
        ln_kernel<<<BL_, 256, 0, stream>>>(h, lnw + i*DM_, lnb + i*DM_, hn);
        gemm64<false,false><<<dim3(BLP_/64, 1024/64), 256, 0, stream>>>(
            hn, nullptr, 0, ipw + (size_t)i*1024*DM_, xz, 1024, DM_);
        conv_silu_kernel<<<BL_, 256, 0, stream>>>(xz, cw + i*DI_*4, cb + i*DI_, u, ut);
        xproj_dt_kernel<<<BLP_/16, 256, 0, stream>>>(
            u, xpw + (size_t)i*48*DI_, dtw + (size_t)i*DI_*16, dtb + i*DI_,
            bmt, cmt, dtt);
        scan_phase1<<<dim3(NC_, DI_/16, B_), 256, 0, stream>>>(
            dtt, ut, bmt, alog + (size_t)i*DI_*DS_, send, aprod);
        scan_phase2<<<B_*DI_*DS_/256, 256, 0, stream>>>(send, aprod);
        scan_phase3<<<dim3(NC_, DI_/16, B_), 256, 0, stream>>>(
            dtt, ut, bmt, cmt, alog + (size_t)i*DI_*DS_, Dv + i*DI_,
            send, ysb);
        gemm64<true,true><<<dim3(BLP_/64, DM_/64), 256, 0, stream>>>(
            ysb, xz + 512, 1024, opw + (size_t)i*DM_*DI_, h, DM_, DI_);
    }
    final_kernel<<<BL_, 256, 0, stream>>>(h, fw, fb, hw, hb, out);
}

// Round 4
// 895.235 us; speedup vs baseline: 2.7153x; 1.0431x over previous
//
#include <hip/hip_runtime.h>
#include <math.h>

#define B_  2
#define L_  2000
#define DM_ 256
#define DI_ 512
#define DS_ 16
#define NL_ 4
#define BL_ (B_*L_)     // 4000
#define BLP_ 4096       // rows padded to multiple of 64
#define NC_ 20          // scan chunks
#define CL_ 100         // chunk length (L_ = NC_*CL_, CL_%4==0)

typedef unsigned short ushort_t;
typedef __attribute__((ext_vector_type(8))) short bf16x8;
typedef __attribute__((ext_vector_type(4))) float f32x4;

__device__ __forceinline__ float siluf(float x) {
    return x / (1.f + __expf(-x));
}

__device__ __forceinline__ ushort_t f2bf(float x) {
    unsigned int u = __float_as_uint(x);
    unsigned int r = (u + 0x7FFFu + ((u >> 16) & 1u)) >> 16;
    return (ushort_t)r;
}

// ---------------- fp32 -> bf16 weight conversion (4 el/thread) ----------------
__global__ __launch_bounds__(256) void f2bf_kernel(
    const float* __restrict__ src, ushort_t* __restrict__ dst, int n4)
{
    int i = (blockIdx.x*256 + threadIdx.x);
    if (i < n4) {
        float4 v = *(const float4*)(src + 4*i);
        ushort_t o[4] = {f2bf(v.x), f2bf(v.y), f2bf(v.z), f2bf(v.w)};
        *(ushort2*)(dst + 4*i)     = *(ushort2*)&o[0];
        *(ushort2*)(dst + 4*i + 2) = *(ushort2*)&o[2];
    }
}

// ---------------- embed: h = x*biw + bib + gene_emb + mod_emb ----------------
__global__ __launch_bounds__(256) void embed_kernel(
    const float* __restrict__ x, const float* __restrict__ biw,
    const float* __restrict__ bib, const float* __restrict__ ge,
    const float* __restrict__ me, float* __restrict__ h)
{
    int bl = blockIdx.x, d = threadIdx.x;
    int l = bl % L_;
    h[(size_t)bl*DM_ + d] = x[bl]*biw[d] + bib[d] + ge[(size_t)l*DM_ + d] + me[d];
}

// ---------------- layernorm over D_MODEL=256 -> bf16 output ----------------
__global__ __launch_bounds__(256) void ln_kernel(
    const float* __restrict__ h, const float* __restrict__ w,
    const float* __restrict__ b, ushort_t* __restrict__ out)
{
    __shared__ float sm[4];
    int row = blockIdx.x, tid = threadIdx.x;
    float v = h[(size_t)row*DM_ + tid];
    float s = v;
    #pragma unroll
    for (int o = 32; o > 0; o >>= 1) s += __shfl_down(s, o);
    if ((tid & 63) == 0) sm[tid >> 6] = s;
    __syncthreads();
    float mu = (sm[0]+sm[1]+sm[2]+sm[3]) * (1.f/DM_);
    __syncthreads();
    float d = v - mu;
    float q = d*d;
    #pragma unroll
    for (int o = 32; o > 0; o >>= 1) q += __shfl_down(q, o);
    if ((tid & 63) == 0) sm[tid >> 6] = q;
    __syncthreads();
    float var = (sm[0]+sm[1]+sm[2]+sm[3]) * (1.f/DM_);
    out[(size_t)row*DM_ + tid] = f2bf(d * rsqrtf(var + 1e-5f) * w[tid] + b[tid]);
}

// ---------------- bf16 MFMA GEMM: C[m,n] (+)= sum_k A[m,k]*W[n,k] ----------------
// A: [M][K] bf16, W: [N][K] bf16, C: fp32. 128x128 tile, BK=64, 4 waves,
// each wave a 64x64 sub-tile via 4x4 grid of 16x16x32 MFMA.
template<bool ACCUM>
__global__ __launch_bounds__(256) void gemm_mfma(
    const ushort_t* __restrict__ A, const ushort_t* __restrict__ W,
    float* __restrict__ C, int ldc, int K)
{
    __shared__ ushort_t a_s[128*64];
    __shared__ ushort_t b_s[128*64];
    const int r0 = blockIdx.x*128, c0 = blockIdx.y*128;
    const int tid = threadIdx.x;
    const int lane = tid & 63, w = tid >> 6;
    const int wm = (w & 1)*64, wn = (w >> 1)*64;
    const int qd = lane >> 4, l16 = lane & 15;
    f32x4 acc[4][4] = {};
    for (int kc = 0; kc < K; kc += 64) {
        #pragma unroll
        for (int q = 0; q < 4; q++) {
            int ch = tid + 256*q;              // 0..1023
            int row = ch >> 3, col8 = (ch & 7)*8;
            *(bf16x8*)&a_s[row*64 + col8] =
                *(const bf16x8*)(A + (size_t)(r0 + row)*K + kc + col8);
            *(bf16x8*)&b_s[row*64 + col8] =
                *(const bf16x8*)(W + (size_t)(c0 + row)*K + kc + col8);
        }
        __syncthreads();
        #pragma unroll
        for (int ks = 0; ks < 2; ks++) {
            bf16x8 af[4], bf[4];
            #pragma unroll
            for (int i = 0; i < 4; i++)
                af[i] = *(const bf16x8*)&a_s[(wm + i*16 + l16)*64 + ks*32 + qd*8];
            #pragma unroll
            for (int j = 0; j < 4; j++)
                bf[j] = *(const bf16x8*)&b_s[(wn + j*16 + l16)*64 + ks*32 + qd*8];
            #pragma unroll
            for (int i = 0; i < 4; i++) {
                #pragma unroll
                for (int j = 0; j < 4; j++)
                    acc[i][j] = __builtin_amdgcn_mfma_f32_16x16x32_bf16(
                        af[i], bf[j], acc[i][j], 0, 0, 0);
            }
        }
        __syncthreads();
    }
    // C/D layout: col = lane&15, row = (lane>>4)*4 + reg   [m89/m91 verified]
    #pragma unroll
    for (int i = 0; i < 4; i++) {
        #pragma unroll
        for (int j = 0; j < 4; j++) {
            #pragma unroll
            for (int r = 0; r < 4; r++) {
                int row = r0 + wm + i*16 + qd*4 + r;
                int col = c0 + wn + j*16 + l16;
                size_t idx = (size_t)row*ldc + col;
                if constexpr (ACCUM) C[idx] += acc[i][j][r];
                else                 C[idx]  = acc[i][j][r];
            }
        }
    }
}

// ---------------- depthwise causal conv(4) + silu; writes u (b,l,c) and ut (b,c,l) ----------------
__global__ __launch_bounds__(256) void conv_silu_kernel(
    const float* __restrict__ xz, const float* __restrict__ cw,
    const float* __restrict__ cb, float* __restrict__ u, float* __restrict__ ut)
{
    int bl = blockIdx.x, tid = threadIdx.x;
    int b = bl / L_, l = bl % L_;
    #pragma unroll
    for (int cc = 0; cc < 2; cc++) {
        int c = tid + cc*256;
        float acc = cb[c];
        #pragma unroll
        for (int k = 0; k < 4; k++) {
            int ls = l + k - 3;
            if (ls >= 0) acc = fmaf(xz[(size_t)(b*L_ + ls)*1024 + c], cw[c*4 + k], acc);
        }
        float s = siluf(acc);
        u[(size_t)bl*DI_ + c] = s;
        ut[((size_t)(b*DI_ + c))*L_ + l] = s;
    }
}

// ---------------- fused x_proj (N=48,K=512) + dt_proj (N=512,K=16) + softplus ----------------
__global__ __launch_bounds__(256) void xproj_dt_kernel(
    const float* __restrict__ U, const float* __restrict__ XW,
    const float* __restrict__ DTW, const float* __restrict__ DTB,
    float* __restrict__ bmt, float* __restrict__ cmt, float* __restrict__ dtt)
{
    __shared__ float a_s[16][132];
    __shared__ float w_s[48][132];
    __shared__ float dtr_s[16][16];
    const int r0 = blockIdx.x * 16;
    const int tid = threadIdx.x;
    const int r = tid >> 4, cg = tid & 15;
    float acc[3] = {};
    for (int kc = 0; kc < 512; kc += 128) {
        #pragma unroll
        for (int q = 0; q < 2; q++) {
            int f = tid + 256*q;
            int row = f >> 5, c4 = (f & 31) * 4;
            *(float4*)&a_s[row][c4] = *(const float4*)(U + (size_t)(r0 + row)*512 + kc + c4);
        }
        #pragma unroll
        for (int q = 0; q < 6; q++) {
            int f = tid + 256*q;
            int row = f >> 5, c4 = (f & 31) * 4;
            *(float4*)&w_s[row][c4] = *(const float4*)(XW + (size_t)row*512 + kc + c4);
        }
        __syncthreads();
        #pragma unroll
        for (int kq = 0; kq < 32; kq++) {
            float4 av = *(const float4*)&a_s[r][4*kq];
            #pragma unroll
            for (int j = 0; j < 3; j++) {
                float4 wv = *(const float4*)&w_s[3*cg + j][4*kq];
                acc[j] = fmaf(av.x, wv.x, acc[j]);
                acc[j] = fmaf(av.y, wv.y, acc[j]);
                acc[j] = fmaf(av.z, wv.z, acc[j]);
                acc[j] = fmaf(av.w, wv.w, acc[j]);
            }
        }
        __syncthreads();
    }
    {
        int bl = r0 + r;
        int b = bl / L_, l = bl % L_;
        bool valid = bl < BL_;
        #pragma unroll
        for (int j = 0; j < 3; j++) {
            int c = 3*cg + j;
            if (c < 16) dtr_s[r][c] = acc[j];
            else if (valid) {
                if (c < 32) bmt[((size_t)(b*DS_ + (c-16)))*L_ + l] = acc[j];
                else        cmt[((size_t)(b*DS_ + (c-32)))*L_ + l] = acc[j];
            }
        }
    }
    __syncthreads();
    #pragma unroll
    for (int q = 0; q < 2; q++) {
        int c = tid + q*256;
        float wreg[16];
        const float4* wp = (const float4*)(DTW + (size_t)c*16);
        #pragma unroll
        for (int k4 = 0; k4 < 4; k4++) {
            float4 wv = wp[k4];
            wreg[4*k4+0] = wv.x; wreg[4*k4+1] = wv.y;
            wreg[4*k4+2] = wv.z; wreg[4*k4+3] = wv.w;
        }
        float bias = DTB[c];
        #pragma unroll 4
        for (int rr = 0; rr < 16; rr++) {
            int bl2 = r0 + rr;
            if (bl2 >= BL_) break;
            int b2 = bl2 / L_, l2 = bl2 % L_;
            float acc2 = bias;
            #pragma unroll
            for (int k = 0; k < 16; k++) acc2 = fmaf(dtr_s[rr][k], wreg[k], acc2);
            float dt = acc2 > 20.f ? acc2 : log1pf(__expf(acc2));
            dtt[((size_t)(b2*DI_ + c))*L_ + l2] = dt;
        }
    }
}

// ---------------- chunked selective scan ----------------
__global__ __launch_bounds__(256) void scan_phase1(
    const float* __restrict__ dtt, const float* __restrict__ ut,
    const float* __restrict__ bmt, const float* __restrict__ Alog,
    float* __restrict__ send, float* __restrict__ aprod)
{
    const int c = blockIdx.x, g = blockIdx.y, b = blockIdx.z;
    const int tid = threadIdx.x;
    const int n = tid & 15, dd = tid >> 4;
    const int d = g*16 + dd;
    const float Ac = -__expf(Alog[d*DS_ + n]);
    const int l0 = c * CL_;
    const float* dtp = dtt + (size_t)(b*DI_ + d)*L_ + l0;
    const float* up  = ut  + (size_t)(b*DI_ + d)*L_ + l0;
    const float* bp  = bmt + (size_t)(b*DS_ + n)*L_ + l0;
    float s = 0.f, ap = 1.f;
    for (int l = 0; l < CL_; l += 4) {
        float4 dt4 = *(const float4*)(dtp + l);
        float4 u4  = *(const float4*)(up + l);
        float4 b4  = *(const float4*)(bp + l);
        float dtv[4] = {dt4.x, dt4.y, dt4.z, dt4.w};
        float uv[4]  = {u4.x, u4.y, u4.z, u4.w};
        float bv[4]  = {b4.x, b4.y, b4.z, b4.w};
        #pragma unroll
        for (int j = 0; j < 4; j++) {
            float e = __expf(dtv[j] * Ac);
            s = fmaf(e, s, dtv[j]*bv[j]*uv[j]);
            ap *= e;
        }
    }
    size_t idx = ((size_t)(b*DI_ + d)*DS_ + n)*NC_ + c;
    send[idx]  = s;
    aprod[idx] = ap;
}

__global__ __launch_bounds__(256) void scan_phase2(
    float* __restrict__ send, const float* __restrict__ aprod)
{
    int t = blockIdx.x*256 + threadIdx.x;   // B_*DI_*DS_ = 16384 threads
    size_t base = (size_t)t * NC_;
    float s = 0.f;
    #pragma unroll
    for (int c = 0; c < NC_; c++) {
        float tmp = send[base + c];
        send[base + c] = s;
        s = fmaf(aprod[base + c], s, tmp);
    }
}

// Phase 3: re-run chunk with incoming state; fuse (y + u*D) * silu(z) -> bf16.
__global__ __launch_bounds__(256) void scan_phase3(
    const float* __restrict__ dtt, const float* __restrict__ ut,
    const float* __restrict__ bmt, const float* __restrict__ cmt,
    const float* __restrict__ Alog, const float* __restrict__ Dv,
    const float* __restrict__ sin_, const float* __restrict__ xz,
    ushort_t* __restrict__ ysb)
{
    const int c = blockIdx.x, g = blockIdx.y, b = blockIdx.z;
    const int tid = threadIdx.x;
    const int n = tid & 15, dd = tid >> 4;
    const int d = g*16 + dd;
    const float Ac = -__expf(Alog[d*DS_ + n]);
    const float Dd = Dv[d];
    const int l0 = c * CL_;
    const float* dtp = dtt + (size_t)(b*DI_ + d)*L_ + l0;
    const float* up  = ut  + (size_t)(b*DI_ + d)*L_ + l0;
    const float* bp  = bmt + (size_t)(b*DS_ + n)*L_ + l0;
    const float* cp  = cmt + (size_t)(b*DS_ + n)*L_ + l0;
    ushort_t* yrow = ysb + (size_t)(b*L_ + l0)*DI_ + d;
    const float* zrow = xz + (size_t)(b*L_ + l0)*1024 + 512 + d;
    float s = sin_[((size_t)(b*DI_ + d)*DS_ + n)*NC_ + c];
    for (int l = 0; l < CL_; l += 4) {
        float4 dt4 = *(const float4*)(dtp + l);
        float4 u4  = *(const float4*)(up + l);
        float4 b4  = *(const float4*)(bp + l);
        float4 c4  = *(const float4*)(cp + l);
        float dtv[4] = {dt4.x, dt4.y, dt4.z, dt4.w};
        float uv[4]  = {u4.x, u4.y, u4.z, u4.w};
        float bv[4]  = {b4.x, b4.y, b4.z, b4.w};
        float cv[4]  = {c4.x, c4.y, c4.z, c4.w};
        #pragma unroll
        for (int j = 0; j < 4; j++) {
            float e = __expf(dtv[j] * Ac);
            s = fmaf(e, s, dtv[j]*bv[j]*uv[j]);
            float y = s * cv[j];
            y += __shfl_xor(y, 1);
            y += __shfl_xor(y, 2);
            y += __shfl_xor(y, 4);
            y += __shfl_xor(y, 8);
            if (n == 0) {
                float zv = zrow[(size_t)(l + j)*1024];
                yrow[(size_t)(l + j)*DI_] = f2bf(fmaf(uv[j], Dd, y) * siluf(zv));
            }
        }
    }
}

// ---------------- final LN + head dot ----------------
__global__ __launch_bounds__(256) void final_kernel(
    const float* __restrict__ h, const float* __restrict__ fw,
    const float* __restrict__ fb, const float* __restrict__ hw,
    const float* __restrict__ hb, float* __restrict__ out)
{
    __shared__ float sm[4];
    int row = blockIdx.x, tid = threadIdx.x;
    float v = h[(size_t)row*DM_ + tid];
    float s = v;
    #pragma unroll
    for (int o = 32; o > 0; o >>= 1) s += __shfl_down(s, o);
    if ((tid & 63) == 0) sm[tid >> 6] = s;
    __syncthreads();
    float mu = (sm[0]+sm[1]+sm[2]+sm[3]) * (1.f/DM_);
    __syncthreads();
    float dv = v - mu;
    float q = dv*dv;
    #pragma unroll
    for (int o = 32; o > 0; o >>= 1) q += __shfl_down(q, o);
    if ((tid & 63) == 0) sm[tid >> 6] = q;
    __syncthreads();
    float var = (sm[0]+sm[1]+sm[2]+sm[3]) * (1.f/DM_);
    float nv = dv * rsqrtf(var + 1e-5f) * fw[tid] + fb[tid];
    float p = nv * hw[tid];
    __syncthreads();
    #pragma unroll
    for (int o = 32; o > 0; o >>= 1) p += __shfl_down(p, o);
    if ((tid & 63) == 0) sm[tid >> 6] = p;
    __syncthreads();
    if (tid == 0) out[row] = sm[0]+sm[1]+sm[2]+sm[3] + hb[0];
}

extern "C" void kernel_launch(void* const* d_in, const int* in_sizes, int n_in,
                              void* d_out, int out_size, void* d_ws, size_t ws_size,
                              hipStream_t stream)
{
    const float* x    = (const float*)d_in[0];
    const float* biw  = (const float*)d_in[1];
    const float* bib  = (const float*)d_in[2];
    const float* ge   = (const float*)d_in[3];
    const float* me   = (const float*)d_in[4];
    const float* lnw  = (const float*)d_in[5];
    const float* lnb  = (const float*)d_in[6];
    const float* ipw  = (const float*)d_in[7];
    const float* cw   = (const float*)d_in[8];
    const float* cb   = (const float*)d_in[9];
    const float* xpw  = (const float*)d_in[10];
    const float* dtw  = (const float*)d_in[11];
    const float* dtb  = (const float*)d_in[12];
    const float* alog = (const float*)d_in[13];
    const float* Dv   = (const float*)d_in[14];
    const float* opw  = (const float*)d_in[15];
    const float* fw   = (const float*)d_in[16];
    const float* fb   = (const float*)d_in[17];
    const float* hw   = (const float*)d_in[18];
    const float* hb   = (const float*)d_in[19];
    float* out = (float*)d_out;

    // workspace layout (floats unless noted); total ~14.05M f = 56.2 MB
    float* ws  = (float*)d_ws;
    float* h    = ws;                                    // 1,048,576
    float* scr  = h + (size_t)BLP_*DM_;                  // 655,360 (hnb | send+aprod)
    float* xz   = scr + 655360;                          // 4,194,304
    float* u    = xz + (size_t)BLP_*1024;                // 2,097,152
    float* ut   = u + (size_t)BLP_*DI_;                  // 2,048,000
    float* dtt  = ut + (size_t)B_*DI_*L_;                // 2,048,000
    float* bmt  = dtt + (size_t)B_*DI_*L_;               // 64,000
    float* cmt  = bmt + (size_t)B_*DS_*L_;               // 64,000
    ushort_t* ysbb = (ushort_t*)(cmt + (size_t)B_*DS_*L_); // BLP_*DI_ ushorts
    ushort_t* ipwb = ysbb + (size_t)BLP_*DI_;            // 4*1024*256 ushorts
    ushort_t* opwb = ipwb + (size_t)NL_*1024*DM_;        // 4*256*512 ushorts
    // scr aliases: hnb live [ln -> in_proj gemm], send/aprod live [p1 -> p3]
    ushort_t* hnb  = (ushort_t*)scr;                     // BLP_*DM_ ushorts
    float* send  = scr;
    float* aprod = scr + (size_t)B_*DI_*DS_*NC_;         // 327,680 each

    // convert weights to bf16 (every launch; ~1.6M elements)
    f2bf_kernel<<<(NL_*1024*DM_/4 + 255)/256, 256, 0, stream>>>(ipw, ipwb, NL_*1024*DM_/4);
    f2bf_kernel<<<(NL_*DM_*DI_/4 + 255)/256, 256, 0, stream>>>(opw, opwb, NL_*DM_*DI_/4);

    embed_kernel<<<BL_, 256, 0, stream>>>(x, biw, bib, ge, me, h);
    for (int i = 0; i < NL_; i++) {
        ln_kernel<<<BL_, 256, 0, stream>>>(h, lnw + i*DM_, lnb + i*DM_, hnb);
        gemm_mfma<false><<<dim3(BLP_/128, 1024/128), 256, 0, stream>>>(
            hnb, ipwb + (size_t)i*1024*DM_, xz, 1024, DM_);
        conv_silu_kernel<<<BL_, 256, 0, stream>>>(xz, cw + i*DI_*4, cb + i*DI_, u, ut);
        xproj_dt_kernel<<<BLP_/16, 256, 0, stream>>>(
            u, xpw + (size_t)i*48*DI_, dtw + (size_t)i*DI_*16, dtb + i*DI_,
            bmt, cmt, dtt);
        scan_phase1<<<dim3(NC_, DI_/16, B_), 256, 0, stream>>>(
            dtt, ut, bmt, alog + (size_t)i*DI_*DS_, send, aprod);
        scan_phase2<<<B_*DI_*DS_/256, 256, 0, stream>>>(send, aprod);
        scan_phase3<<<dim3(NC_, DI_/16, B_), 256, 0, stream>>>(
            dtt, ut, bmt, cmt, alog + (size_t)i*DI_*DS_, Dv + i*DI_,
            send, xz, ysbb);
        gemm_mfma<true><<<dim3(BLP_/128, DM_/128), 256, 0, stream>>>(
            ysbb, opwb + (size_t)i*DM_*DI_, h, DM_, DI_);
    }
    final_kernel<<<BL_, 256, 0, stream>>>(h, fw, fb, hw, hb, out);
}

// Round 5
// 805.053 us; speedup vs baseline: 3.0195x; 1.1120x over previous
//
#include <hip/hip_runtime.h>
#include <math.h>

#define B_  2
#define L_  2000
#define DM_ 256
#define DI_ 512
#define DS_ 16
#define NL_ 4
#define BL_ (B_*L_)     // 4000
#define BLP_ 4096       // rows padded to multiple of 64
#define NC_ 50          // scan chunks
#define CL_ 40          // chunk length (L_ = NC_*CL_, CL_%4==0)

typedef unsigned short ushort_t;
typedef __attribute__((ext_vector_type(8))) short bf16x8;
typedef __attribute__((ext_vector_type(4))) float f32x4;

__device__ __forceinline__ float siluf(float x) {
    return x / (1.f + __expf(-x));
}

__device__ __forceinline__ ushort_t f2bf(float x) {
    unsigned int u = __float_as_uint(x);
    unsigned int r = (u + 0x7FFFu + ((u >> 16) & 1u)) >> 16;
    return (ushort_t)r;
}

// ---------------- fp32 -> bf16 weight conversion (4 el/thread) ----------------
__global__ __launch_bounds__(256) void f2bf_kernel(
    const float* __restrict__ src, ushort_t* __restrict__ dst, int n4)
{
    int i = (blockIdx.x*256 + threadIdx.x);
    if (i < n4) {
        float4 v = *(const float4*)(src + 4*i);
        ushort_t o[4] = {f2bf(v.x), f2bf(v.y), f2bf(v.z), f2bf(v.w)};
        *(ushort2*)(dst + 4*i)     = *(ushort2*)&o[0];
        *(ushort2*)(dst + 4*i + 2) = *(ushort2*)&o[2];
    }
}

// ---------------- embed: h = x*biw + bib + gene_emb + mod_emb ----------------
__global__ __launch_bounds__(256) void embed_kernel(
    const float* __restrict__ x, const float* __restrict__ biw,
    const float* __restrict__ bib, const float* __restrict__ ge,
    const float* __restrict__ me, float* __restrict__ h)
{
    int bl = blockIdx.x, d = threadIdx.x;
    int l = bl % L_;
    h[(size_t)bl*DM_ + d] = x[bl]*biw[d] + bib[d] + ge[(size_t)l*DM_ + d] + me[d];
}

// ---------------- layernorm over D_MODEL=256 -> bf16 output ----------------
__global__ __launch_bounds__(256) void ln_kernel(
    const float* __restrict__ h, const float* __restrict__ w,
    const float* __restrict__ b, ushort_t* __restrict__ out)
{
    __shared__ float sm[4];
    int row = blockIdx.x, tid = threadIdx.x;
    float v = h[(size_t)row*DM_ + tid];
    float s = v;
    #pragma unroll
    for (int o = 32; o > 0; o >>= 1) s += __shfl_down(s, o);
    if ((tid & 63) == 0) sm[tid >> 6] = s;
    __syncthreads();
    float mu = (sm[0]+sm[1]+sm[2]+sm[3]) * (1.f/DM_);
    __syncthreads();
    float d = v - mu;
    float q = d*d;
    #pragma unroll
    for (int o = 32; o > 0; o >>= 1) q += __shfl_down(q, o);
    if ((tid & 63) == 0) sm[tid >> 6] = q;
    __syncthreads();
    float var = (sm[0]+sm[1]+sm[2]+sm[3]) * (1.f/DM_);
    out[(size_t)row*DM_ + tid] = f2bf(d * rsqrtf(var + 1e-5f) * w[tid] + b[tid]);
}

// ---------------- bf16 MFMA GEMM: C[m,n] (+)= sum_k A[m,k]*W[n,k] ----------------
template<bool ACCUM>
__global__ __launch_bounds__(256) void gemm_mfma(
    const ushort_t* __restrict__ A, const ushort_t* __restrict__ W,
    float* __restrict__ C, int ldc, int K)
{
    __shared__ ushort_t a_s[128*64];
    __shared__ ushort_t b_s[128*64];
    const int r0 = blockIdx.x*128, c0 = blockIdx.y*128;
    const int tid = threadIdx.x;
    const int lane = tid & 63, w = tid >> 6;
    const int wm = (w & 1)*64, wn = (w >> 1)*64;
    const int qd = lane >> 4, l16 = lane & 15;
    f32x4 acc[4][4] = {};
    for (int kc = 0; kc < K; kc += 64) {
        #pragma unroll
        for (int q = 0; q < 4; q++) {
            int ch = tid + 256*q;              // 0..1023
            int row = ch >> 3, col8 = (ch & 7)*8;
            *(bf16x8*)&a_s[row*64 + col8] =
                *(const bf16x8*)(A + (size_t)(r0 + row)*K + kc + col8);
            *(bf16x8*)&b_s[row*64 + col8] =
                *(const bf16x8*)(W + (size_t)(c0 + row)*K + kc + col8);
        }
        __syncthreads();
        #pragma unroll
        for (int ks = 0; ks < 2; ks++) {
            bf16x8 af[4], bf[4];
            #pragma unroll
            for (int i = 0; i < 4; i++)
                af[i] = *(const bf16x8*)&a_s[(wm + i*16 + l16)*64 + ks*32 + qd*8];
            #pragma unroll
            for (int j = 0; j < 4; j++)
                bf[j] = *(const bf16x8*)&b_s[(wn + j*16 + l16)*64 + ks*32 + qd*8];
            #pragma unroll
            for (int i = 0; i < 4; i++) {
                #pragma unroll
                for (int j = 0; j < 4; j++)
                    acc[i][j] = __builtin_amdgcn_mfma_f32_16x16x32_bf16(
                        af[i], bf[j], acc[i][j], 0, 0, 0);
            }
        }
        __syncthreads();
    }
    // C/D layout: col = lane&15, row = (lane>>4)*4 + reg
    #pragma unroll
    for (int i = 0; i < 4; i++) {
        #pragma unroll
        for (int j = 0; j < 4; j++) {
            #pragma unroll
            for (int r = 0; r < 4; r++) {
                int row = r0 + wm + i*16 + qd*4 + r;
                int col = c0 + wn + j*16 + l16;
                size_t idx = (size_t)row*ldc + col;
                if constexpr (ACCUM) C[idx] += acc[i][j][r];
                else                 C[idx]  = acc[i][j][r];
            }
        }
    }
}

// ---------------- depthwise causal conv(4) + silu; writes u (b,l,c) and ut (b,c,l) ----------------
__global__ __launch_bounds__(256) void conv_silu_kernel(
    const float* __restrict__ xz, const float* __restrict__ cw,
    const float* __restrict__ cb, float* __restrict__ u, float* __restrict__ ut)
{
    int bl = blockIdx.x, tid = threadIdx.x;
    int b = bl / L_, l = bl % L_;
    #pragma unroll
    for (int cc = 0; cc < 2; cc++) {
        int c = tid + cc*256;
        float acc = cb[c];
        #pragma unroll
        for (int k = 0; k < 4; k++) {
            int ls = l + k - 3;
            if (ls >= 0) acc = fmaf(xz[(size_t)(b*L_ + ls)*1024 + c], cw[c*4 + k], acc);
        }
        float s = siluf(acc);
        u[(size_t)bl*DI_ + c] = s;
        ut[((size_t)(b*DI_ + c))*L_ + l] = s;
    }
}

// ---------------- fused x_proj (N=48,K=512) + dt_proj (N=512,K=16) + softplus ----------------
__global__ __launch_bounds__(256) void xproj_dt_kernel(
    const float* __restrict__ U, const float* __restrict__ XW,
    const float* __restrict__ DTW, const float* __restrict__ DTB,
    float* __restrict__ bmt, float* __restrict__ cmt, float* __restrict__ dtt)
{
    __shared__ float a_s[16][132];
    __shared__ float w_s[48][132];
    __shared__ float dtr_s[16][16];
    const int r0 = blockIdx.x * 16;
    const int tid = threadIdx.x;
    const int r = tid >> 4, cg = tid & 15;
    float acc[3] = {};
    for (int kc = 0; kc < 512; kc += 128) {
        #pragma unroll
        for (int q = 0; q < 2; q++) {
            int f = tid + 256*q;
            int row = f >> 5, c4 = (f & 31) * 4;
            *(float4*)&a_s[row][c4] = *(const float4*)(U + (size_t)(r0 + row)*512 + kc + c4);
        }
        #pragma unroll
        for (int q = 0; q < 6; q++) {
            int f = tid + 256*q;
            int row = f >> 5, c4 = (f & 31) * 4;
            *(float4*)&w_s[row][c4] = *(const float4*)(XW + (size_t)row*512 + kc + c4);
        }
        __syncthreads();
        #pragma unroll
        for (int kq = 0; kq < 32; kq++) {
            float4 av = *(const float4*)&a_s[r][4*kq];
            #pragma unroll
            for (int j = 0; j < 3; j++) {
                float4 wv = *(const float4*)&w_s[3*cg + j][4*kq];
                acc[j] = fmaf(av.x, wv.x, acc[j]);
                acc[j] = fmaf(av.y, wv.y, acc[j]);
                acc[j] = fmaf(av.z, wv.z, acc[j]);
                acc[j] = fmaf(av.w, wv.w, acc[j]);
            }
        }
        __syncthreads();
    }
    {
        int bl = r0 + r;
        int b = bl / L_, l = bl % L_;
        bool valid = bl < BL_;
        #pragma unroll
        for (int j = 0; j < 3; j++) {
            int c = 3*cg + j;
            if (c < 16) dtr_s[r][c] = acc[j];
            else if (valid) {
                if (c < 32) bmt[((size_t)(b*DS_ + (c-16)))*L_ + l] = acc[j];
                else        cmt[((size_t)(b*DS_ + (c-32)))*L_ + l] = acc[j];
            }
        }
    }
    __syncthreads();
    #pragma unroll
    for (int q = 0; q < 2; q++) {
        int c = tid + q*256;
        float wreg[16];
        const float4* wp = (const float4*)(DTW + (size_t)c*16);
        #pragma unroll
        for (int k4 = 0; k4 < 4; k4++) {
            float4 wv = wp[k4];
            wreg[4*k4+0] = wv.x; wreg[4*k4+1] = wv.y;
            wreg[4*k4+2] = wv.z; wreg[4*k4+3] = wv.w;
        }
        float bias = DTB[c];
        #pragma unroll 4
        for (int rr = 0; rr < 16; rr++) {
            int bl2 = r0 + rr;
            if (bl2 >= BL_) break;
            int b2 = bl2 / L_, l2 = bl2 % L_;
            float acc2 = bias;
            #pragma unroll
            for (int k = 0; k < 16; k++) acc2 = fmaf(dtr_s[rr][k], wreg[k], acc2);
            float dt = acc2 > 20.f ? acc2 : log1pf(__expf(acc2));
            dtt[((size_t)(b2*DI_ + c))*L_ + l2] = dt;
        }
    }
}

// ---------------- chunked selective scan ----------------
// grid(NC_, 32, B_), block 256 = 16 d x 16 n.
__global__ __launch_bounds__(256) void scan_phase1(
    const float* __restrict__ dtt, const float* __restrict__ ut,
    const float* __restrict__ bmt, const float* __restrict__ Alog,
    float* __restrict__ send, float* __restrict__ aprod)
{
    const int c = blockIdx.x, g = blockIdx.y, b = blockIdx.z;
    const int tid = threadIdx.x;
    const int n = tid & 15, dd = tid >> 4;
    const int d = g*16 + dd;
    const float Ac = -__expf(Alog[d*DS_ + n]);
    const int l0 = c * CL_;
    const float* dtp = dtt + (size_t)(b*DI_ + d)*L_ + l0;
    const float* up  = ut  + (size_t)(b*DI_ + d)*L_ + l0;
    const float* bp  = bmt + (size_t)(b*DS_ + n)*L_ + l0;
    float s = 0.f, ap = 1.f;
    for (int l = 0; l < CL_; l += 4) {
        float4 dt4 = *(const float4*)(dtp + l);
        float4 u4  = *(const float4*)(up + l);
        float4 b4  = *(const float4*)(bp + l);
        float dtv[4] = {dt4.x, dt4.y, dt4.z, dt4.w};
        float uv[4]  = {u4.x, u4.y, u4.z, u4.w};
        float bv[4]  = {b4.x, b4.y, b4.z, b4.w};
        #pragma unroll
        for (int j = 0; j < 4; j++) {
            float e = __expf(dtv[j] * Ac);
            s = fmaf(e, s, dtv[j]*bv[j]*uv[j]);
            ap *= e;
        }
    }
    size_t idx = ((size_t)(b*DI_ + d)*DS_ + n)*NC_ + c;
    send[idx]  = s;
    aprod[idx] = ap;
}

__global__ __launch_bounds__(256) void scan_phase2(
    float* __restrict__ send, const float* __restrict__ aprod)
{
    int t = blockIdx.x*256 + threadIdx.x;   // B_*DI_*DS_ = 16384 threads
    size_t base = (size_t)t * NC_;
    float s = 0.f;
    for (int c = 0; c < NC_; c++) {
        float tmp = send[base + c];
        send[base + c] = s;
        s = fmaf(aprod[base + c], s, tmp);
    }
}

// Phase 3: re-run chunk with incoming state; y+u*D -> LDS tile; cooperative
// coalesced epilogue applies silu(z) and stores bf16.
__global__ __launch_bounds__(256) void scan_phase3(
    const float* __restrict__ dtt, const float* __restrict__ ut,
    const float* __restrict__ bmt, const float* __restrict__ cmt,
    const float* __restrict__ Alog, const float* __restrict__ Dv,
    const float* __restrict__ sin_, const float* __restrict__ xz,
    ushort_t* __restrict__ ysb)
{
    __shared__ float ytile[16][CL_ + 1];
    const int c = blockIdx.x, g = blockIdx.y, b = blockIdx.z;
    const int tid = threadIdx.x;
    const int n = tid & 15, dd = tid >> 4;
    const int d = g*16 + dd;
    const float Ac = -__expf(Alog[d*DS_ + n]);
    const float Dd = Dv[d];
    const int l0 = c * CL_;
    const float* dtp = dtt + (size_t)(b*DI_ + d)*L_ + l0;
    const float* up  = ut  + (size_t)(b*DI_ + d)*L_ + l0;
    const float* bp  = bmt + (size_t)(b*DS_ + n)*L_ + l0;
    const float* cp  = cmt + (size_t)(b*DS_ + n)*L_ + l0;
    float s = sin_[((size_t)(b*DI_ + d)*DS_ + n)*NC_ + c];
    for (int l = 0; l < CL_; l += 4) {
        float4 dt4 = *(const float4*)(dtp + l);
        float4 u4  = *(const float4*)(up + l);
        float4 b4  = *(const float4*)(bp + l);
        float4 c4  = *(const float4*)(cp + l);
        float dtv[4] = {dt4.x, dt4.y, dt4.z, dt4.w};
        float uv[4]  = {u4.x, u4.y, u4.z, u4.w};
        float bv[4]  = {b4.x, b4.y, b4.z, b4.w};
        float cv[4]  = {c4.x, c4.y, c4.z, c4.w};
        #pragma unroll
        for (int j = 0; j < 4; j++) {
            float e = __expf(dtv[j] * Ac);
            s = fmaf(e, s, dtv[j]*bv[j]*uv[j]);
            float y = s * cv[j];
            y += __shfl_xor(y, 1);
            y += __shfl_xor(y, 2);
            y += __shfl_xor(y, 4);
            y += __shfl_xor(y, 8);
            if (n == 0) ytile[dd][l + j] = fmaf(uv[j], Dd, y);
        }
    }
    __syncthreads();
    // epilogue: thread -> (2 consecutive d, 1 l); 32 l-rows per pass
    const int ed = (tid & 7) * 2;          // 0,2,..,14
    const int eli = tid >> 3;              // 0..31
    #pragma unroll
    for (int p = 0; p < (CL_ + 31)/32; p++) {
        int ll = eli + p*32;
        if (ll < CL_) {
            int gl = l0 + ll;
            const float* zp = xz + (size_t)(b*L_ + gl)*1024 + 512 + g*16 + ed;
            float2 zv = *(const float2*)zp;
            ushort_t o[2] = {f2bf(ytile[ed][ll]   * siluf(zv.x)),
                             f2bf(ytile[ed+1][ll] * siluf(zv.y))};
            *(ushort2*)(ysb + (size_t)(b*L_ + gl)*DI_ + g*16 + ed) = *(ushort2*)&o[0];
        }
    }
}

// ---------------- final LN + head dot ----------------
__global__ __launch_bounds__(256) void final_kernel(
    const float* __restrict__ h, const float* __restrict__ fw,
    const float* __restrict__ fb, const float* __restrict__ hw,
    const float* __restrict__ hb, float* __restrict__ out)
{
    __shared__ float sm[4];
    int row = blockIdx.x, tid = threadIdx.x;
    float v = h[(size_t)row*DM_ + tid];
    float s = v;
    #pragma unroll
    for (int o = 32; o > 0; o >>= 1) s += __shfl_down(s, o);
    if ((tid & 63) == 0) sm[tid >> 6] = s;
    __syncthreads();
    float mu = (sm[0]+sm[1]+sm[2]+sm[3]) * (1.f/DM_);
    __syncthreads();
    float dv = v - mu;
    float q = dv*dv;
    #pragma unroll
    for (int o = 32; o > 0; o >>= 1) q += __shfl_down(q, o);
    if ((tid & 63) == 0) sm[tid >> 6] = q;
    __syncthreads();
    float var = (sm[0]+sm[1]+sm[2]+sm[3]) * (1.f/DM_);
    float nv = dv * rsqrtf(var + 1e-5f) * fw[tid] + fb[tid];
    float p = nv * hw[tid];
    __syncthreads();
    #pragma unroll
    for (int o = 32; o > 0; o >>= 1) p += __shfl_down(p, o);
    if ((tid & 63) == 0) sm[tid >> 6] = p;
    __syncthreads();
    if (tid == 0) out[row] = sm[0]+sm[1]+sm[2]+sm[3] + hb[0];
}

extern "C" void kernel_launch(void* const* d_in, const int* in_sizes, int n_in,
                              void* d_out, int out_size, void* d_ws, size_t ws_size,
                              hipStream_t stream)
{
    const float* x    = (const float*)d_in[0];
    const float* biw  = (const float*)d_in[1];
    const float* bib  = (const float*)d_in[2];
    const float* ge   = (const float*)d_in[3];
    const float* me   = (const float*)d_in[4];
    const float* lnw  = (const float*)d_in[5];
    const float* lnb  = (const float*)d_in[6];
    const float* ipw  = (const float*)d_in[7];
    const float* cw   = (const float*)d_in[8];
    const float* cb   = (const float*)d_in[9];
    const float* xpw  = (const float*)d_in[10];
    const float* dtw  = (const float*)d_in[11];
    const float* dtb  = (const float*)d_in[12];
    const float* alog = (const float*)d_in[13];
    const float* Dv   = (const float*)d_in[14];
    const float* opw  = (const float*)d_in[15];
    const float* fw   = (const float*)d_in[16];
    const float* fb   = (const float*)d_in[17];
    const float* hw   = (const float*)d_in[18];
    const float* hb   = (const float*)d_in[19];
    float* out = (float*)d_out;

    // workspace layout (floats unless noted); total ~14.05M f = 56.2 MB
    float* ws  = (float*)d_ws;
    float* h    = ws;                                    // 1,048,576
    float* scr  = h + (size_t)BLP_*DM_;                  // 655,360 (hnb region)
    float* xz   = scr + 655360;                          // 4,194,304
    float* u    = xz + (size_t)BLP_*1024;                // 2,097,152
    float* ut   = u + (size_t)BLP_*DI_;                  // 2,048,000
    float* dtt  = ut + (size_t)B_*DI_*L_;                // 2,048,000
    float* bmt  = dtt + (size_t)B_*DI_*L_;               // 64,000
    float* cmt  = bmt + (size_t)B_*DS_*L_;               // 64,000
    ushort_t* ysbb = (ushort_t*)(cmt + (size_t)B_*DS_*L_); // BLP_*DI_ ushorts
    ushort_t* ipwb = ysbb + (size_t)BLP_*DI_;            // 4*1024*256 ushorts
    ushort_t* opwb = ipwb + (size_t)NL_*1024*DM_;        // 4*256*512 ushorts
    ushort_t* hnb  = (ushort_t*)scr;                     // BLP_*DM_ ushorts
    // send/aprod alias the u buffer: u is only read by xproj_dt, and
    // p1/p2/p3 run strictly between xproj_dt and the next conv_silu write.
    // need 2 * B_*DI_*DS_*NC_ = 1,638,400 floats <= BLP_*DI_ = 2,097,152. OK.
    float* send  = u;
    float* aprod = u + (size_t)B_*DI_*DS_*NC_;

    // convert weights to bf16 (every launch; ~1.6M elements)
    f2bf_kernel<<<(NL_*1024*DM_/4 + 255)/256, 256, 0, stream>>>(ipw, ipwb, NL_*1024*DM_/4);
    f2bf_kernel<<<(NL_*DM_*DI_/4 + 255)/256, 256, 0, stream>>>(opw, opwb, NL_*DM_*DI_/4);

    embed_kernel<<<BL_, 256, 0, stream>>>(x, biw, bib, ge, me, h);
    for (int i = 0; i < NL_; i++) {
        ln_kernel<<<BL_, 256, 0, stream>>>(h, lnw + i*DM_, lnb + i*DM_, hnb);
        gemm_mfma<false><<<dim3(BLP_/128, 1024/128), 256, 0, stream>>>(
            hnb, ipwb + (size_t)i*1024*DM_, xz, 1024, DM_);
        conv_silu_kernel<<<BL_, 256, 0, stream>>>(xz, cw + i*DI_*4, cb + i*DI_, u, ut);
        xproj_dt_kernel<<<BLP_/16, 256, 0, stream>>>(
            u, xpw + (size_t)i*48*DI_, dtw + (size_t)i*DI_*16, dtb + i*DI_,
            bmt, cmt, dtt);
        scan_phase1<<<dim3(NC_, DI_/16, B_), 256, 0, stream>>>(
            dtt, ut, bmt, alog + (size_t)i*DI_*DS_, send, aprod);
        scan_phase2<<<B_*DI_*DS_/256, 256, 0, stream>>>(send, aprod);
        scan_phase3<<<dim3(NC_, DI_/16, B_), 256, 0, stream>>>(
            dtt, ut, bmt, cmt, alog + (size_t)i*DI_*DS_, Dv + i*DI_,
            send, xz, ysbb);
        gemm_mfma<true><<<dim3(BLP_/128, DM_/128), 256, 0, stream>>>(
            ysbb, opwb + (size_t)i*DM_*DI_, h, DM_, DI_);
    }
    final_kernel<<<BL_, 256, 0, stream>>>(h, fw, fb, hw, hb, out);
}

// Round 6
// 650.658 us; speedup vs baseline: 3.7359x; 1.2373x over previous
//
#include <hip/hip_runtime.h>
#include <math.h>

#define B_  2
#define L_  2000
#define DM_ 256
#define DI_ 512
#define DS_ 16
#define NL_ 4
#define BL_ (B_*L_)     // 4000
#define BLP_ 4096       // rows padded to multiple of 64
#define NC_ 50          // scan chunks
#define CL_ 40          // chunk length (L_ = NC_*CL_, CL_%4==0)

typedef unsigned short ushort_t;
typedef __attribute__((ext_vector_type(8))) short bf16x8;
typedef __attribute__((ext_vector_type(4))) float f32x4;

__device__ __forceinline__ float siluf(float x) {
    return x / (1.f + __expf(-x));
}

__device__ __forceinline__ ushort_t f2bf(float x) {
    unsigned int u = __float_as_uint(x);
    unsigned int r = (u + 0x7FFFu + ((u >> 16) & 1u)) >> 16;
    return (ushort_t)r;
}

__device__ __forceinline__ float bf2f(ushort_t v) {
    return __uint_as_float(((unsigned int)v) << 16);
}

// ---------------- fp32 -> bf16 conversion (4 el/thread) ----------------
__global__ __launch_bounds__(256) void f2bf_kernel(
    const float* __restrict__ src, ushort_t* __restrict__ dst, int n4)
{
    int i = (blockIdx.x*256 + threadIdx.x);
    if (i < n4) {
        float4 v = *(const float4*)(src + 4*i);
        ushort_t o[4] = {f2bf(v.x), f2bf(v.y), f2bf(v.z), f2bf(v.w)};
        *(ushort2*)(dst + 4*i)     = *(ushort2*)&o[0];
        *(ushort2*)(dst + 4*i + 2) = *(ushort2*)&o[2];
    }
}

// ---------------- embed: h = x*biw + bib + gene_emb + mod_emb ----------------
__global__ __launch_bounds__(256) void embed_kernel(
    const float* __restrict__ x, const float* __restrict__ biw,
    const float* __restrict__ bib, const float* __restrict__ ge,
    const float* __restrict__ me, float* __restrict__ h)
{
    int bl = blockIdx.x, d = threadIdx.x;
    int l = bl % L_;
    h[(size_t)bl*DM_ + d] = x[bl]*biw[d] + bib[d] + ge[(size_t)l*DM_ + d] + me[d];
}

// ---------------- layernorm over D_MODEL=256 -> bf16 output ----------------
__global__ __launch_bounds__(256) void ln_kernel(
    const float* __restrict__ h, const float* __restrict__ w,
    const float* __restrict__ b, ushort_t* __restrict__ out)
{
    __shared__ float sm[4];
    int row = blockIdx.x, tid = threadIdx.x;
    float v = h[(size_t)row*DM_ + tid];
    float s = v;
    #pragma unroll
    for (int o = 32; o > 0; o >>= 1) s += __shfl_down(s, o);
    if ((tid & 63) == 0) sm[tid >> 6] = s;
    __syncthreads();
    float mu = (sm[0]+sm[1]+sm[2]+sm[3]) * (1.f/DM_);
    __syncthreads();
    float d = v - mu;
    float q = d*d;
    #pragma unroll
    for (int o = 32; o > 0; o >>= 1) q += __shfl_down(q, o);
    if ((tid & 63) == 0) sm[tid >> 6] = q;
    __syncthreads();
    float var = (sm[0]+sm[1]+sm[2]+sm[3]) * (1.f/DM_);
    out[(size_t)row*DM_ + tid] = f2bf(d * rsqrtf(var + 1e-5f) * w[tid] + b[tid]);
}

// ---------------- bf16 MFMA GEMM: C[m,n] (+)= sum_k A[m,k]*W[n,k] ----------------
template<bool ACCUM>
__global__ __launch_bounds__(256) void gemm_mfma(
    const ushort_t* __restrict__ A, const ushort_t* __restrict__ W,
    float* __restrict__ C, int ldc, int K)
{
    __shared__ ushort_t a_s[128*64];
    __shared__ ushort_t b_s[128*64];
    const int r0 = blockIdx.x*128, c0 = blockIdx.y*128;
    const int tid = threadIdx.x;
    const int lane = tid & 63, w = tid >> 6;
    const int wm = (w & 1)*64, wn = (w >> 1)*64;
    const int qd = lane >> 4, l16 = lane & 15;
    f32x4 acc[4][4] = {};
    for (int kc = 0; kc < K; kc += 64) {
        #pragma unroll
        for (int q = 0; q < 4; q++) {
            int ch = tid + 256*q;              // 0..1023
            int row = ch >> 3, col8 = (ch & 7)*8;
            *(bf16x8*)&a_s[row*64 + col8] =
                *(const bf16x8*)(A + (size_t)(r0 + row)*K + kc + col8);
            *(bf16x8*)&b_s[row*64 + col8] =
                *(const bf16x8*)(W + (size_t)(c0 + row)*K + kc + col8);
        }
        __syncthreads();
        #pragma unroll
        for (int ks = 0; ks < 2; ks++) {
            bf16x8 af[4], bf[4];
            #pragma unroll
            for (int i = 0; i < 4; i++)
                af[i] = *(const bf16x8*)&a_s[(wm + i*16 + l16)*64 + ks*32 + qd*8];
            #pragma unroll
            for (int j = 0; j < 4; j++)
                bf[j] = *(const bf16x8*)&b_s[(wn + j*16 + l16)*64 + ks*32 + qd*8];
            #pragma unroll
            for (int i = 0; i < 4; i++) {
                #pragma unroll
                for (int j = 0; j < 4; j++)
                    acc[i][j] = __builtin_amdgcn_mfma_f32_16x16x32_bf16(
                        af[i], bf[j], acc[i][j], 0, 0, 0);
            }
        }
        __syncthreads();
    }
    // C/D layout: col = lane&15, row = (lane>>4)*4 + reg
    #pragma unroll
    for (int i = 0; i < 4; i++) {
        #pragma unroll
        for (int j = 0; j < 4; j++) {
            #pragma unroll
            for (int r = 0; r < 4; r++) {
                int row = r0 + wm + i*16 + qd*4 + r;
                int col = c0 + wn + j*16 + l16;
                size_t idx = (size_t)row*ldc + col;
                if constexpr (ACCUM) C[idx] += acc[i][j][r];
                else                 C[idx]  = acc[i][j][r];
            }
        }
    }
}

// ---------------- conv(4) + silu, tiled; writes u_bf (b,l,c) + ut_bf (b,c,l), both bf16 ----
// grid(32 l-chunks of 64, 8 c-groups of 64, B_), block 256.
__global__ __launch_bounds__(256) void conv_silu_kernel(
    const float* __restrict__ xz, const float* __restrict__ cw,
    const float* __restrict__ cb, ushort_t* __restrict__ u_bf,
    ushort_t* __restrict__ ut_bf)
{
    __shared__ float xs[67][68];
    __shared__ ushort_t us[64][72];
    const int l0 = blockIdx.x * 64, c0 = blockIdx.y * 64, b = blockIdx.z;
    const int tid = threadIdx.x;
    // stage xz tile rows l0-3 .. l0+63
    for (int f = tid; f < 67*16; f += 256) {
        int row = f >> 4, c4 = (f & 15) * 4;
        int l = l0 - 3 + row;
        float4 v = {0.f, 0.f, 0.f, 0.f};
        if (l >= 0 && l < L_)
            v = *(const float4*)(xz + (size_t)(b*L_ + l)*1024 + c0 + c4);
        *(float4*)&xs[row][c4] = v;
    }
    __syncthreads();
    // conv: thread -> fixed c, 16 consecutive l
    const int c_loc = tid & 63, lq = tid >> 6;
    const int c = c0 + c_loc;
    float4 wv = *(const float4*)(cw + c*4);
    float bias = cb[c];
    float x0 = xs[lq*16 + 0][c_loc];
    float x1 = xs[lq*16 + 1][c_loc];
    float x2 = xs[lq*16 + 2][c_loc];
    ushort_t ush[16];
    #pragma unroll
    for (int j = 0; j < 16; j++) {
        float x3 = xs[lq*16 + 3 + j][c_loc];
        float v = fmaf(x0, wv.x, fmaf(x1, wv.y, fmaf(x2, wv.z, fmaf(x3, wv.w, bias))));
        ush[j] = f2bf(siluf(v));
        us[lq*16 + j][c_loc] = ush[j];
        x0 = x1; x1 = x2; x2 = x3;
    }
    // ut_bf: 16 bf16 = 32 B contiguous per c
    int lg0 = l0 + lq*16;
    if (lg0 < L_) {
        unsigned int r[8];
        #pragma unroll
        for (int j = 0; j < 8; j++)
            r[j] = (unsigned int)ush[2*j] | ((unsigned int)ush[2*j+1] << 16);
        ushort_t* dst = ut_bf + (size_t)(b*DI_ + c)*L_ + lg0;
        *(uint4*)dst       = *(uint4*)&r[0];
        *(uint4*)(dst + 8) = *(uint4*)&r[4];
    }
    __syncthreads();
    // u_bf rows (l,c) via LDS transpose, 16B stores
    for (int f = tid; f < 64*8; f += 256) {
        int row = f >> 3, g8 = (f & 7)*8;
        if (l0 + row < L_)
            *(uint4*)(u_bf + (size_t)(b*L_ + l0 + row)*512 + c0 + g8) =
                *(const uint4*)&us[row][g8];
    }
}

// ---------------- x_proj via MFMA + fused dt_proj ----------------
// grid(125, B_): block = 16 l-rows. A: u_bf 16x512 bf16, B: XWb 48x512 bf16.
// 4 waves split K (128 each), LDS-reduce, epilogue scatters Bm/Cm (coalesced
// 64B segs) + dt_proj (fp32) with transposed dtt writes (4x float4 per d).
__global__ __launch_bounds__(256) void xproj_dt_kernel(
    const ushort_t* __restrict__ U, const ushort_t* __restrict__ XWb,
    const float* __restrict__ DTW, const float* __restrict__ DTB,
    float* __restrict__ bmt, float* __restrict__ cmt, float* __restrict__ dtt)
{
    __shared__ ushort_t a_s[16*520];
    __shared__ ushort_t w_s[48*520];
    __shared__ float ps[4*16*48];
    __shared__ float dtr_s[16][16];
    const int l0 = blockIdx.x * 16, b = blockIdx.y;
    const int tid = threadIdx.x;
    const int lane = tid & 63, w = tid >> 6;
    const int qd = lane >> 4, l16 = lane & 15;
    // stage A (16x512): 1024 16B-chunks
    #pragma unroll
    for (int q = 0; q < 4; q++) {
        int f = tid + 256*q;
        int row = f >> 6, col8 = (f & 63)*8;
        *(bf16x8*)&a_s[row*520 + col8] =
            *(const bf16x8*)(U + (size_t)(b*L_ + l0 + row)*512 + col8);
    }
    // stage W (48x512): 3072 16B-chunks
    #pragma unroll
    for (int q = 0; q < 12; q++) {
        int f = tid + 256*q;
        int row = f >> 6, col8 = (f & 63)*8;
        *(bf16x8*)&w_s[row*520 + col8] =
            *(const bf16x8*)(XWb + (size_t)row*512 + col8);
    }
    __syncthreads();
    // MFMA: wave w covers K in [128w, 128w+128)
    f32x4 acc[3] = {};
    #pragma unroll
    for (int step = 0; step < 4; step++) {
        int k = w*128 + step*32 + qd*8;
        bf16x8 af = *(const bf16x8*)&a_s[l16*520 + k];
        #pragma unroll
        for (int j = 0; j < 3; j++) {
            bf16x8 bf = *(const bf16x8*)&w_s[(j*16 + l16)*520 + k];
            acc[j] = __builtin_amdgcn_mfma_f32_16x16x32_bf16(af, bf, acc[j], 0, 0, 0);
        }
    }
    // partials -> LDS
    #pragma unroll
    for (int j = 0; j < 3; j++) {
        #pragma unroll
        for (int r = 0; r < 4; r++)
            ps[(w*16 + qd*4 + r)*48 + j*16 + l16] = acc[j][r];
    }
    __syncthreads();
    // reduce 4 partials into ps[0..767]
    #pragma unroll
    for (int e = tid; e < 768; e += 256)
        ps[e] = ps[e] + ps[768 + e] + ps[1536 + e] + ps[2304 + e];
    __syncthreads();
    // scatter: e = q*256+tid, col = e>>4 (0..47), row = e&15
    #pragma unroll
    for (int q = 0; q < 3; q++) {
        int e = q*256 + tid;
        int col = e >> 4, row = e & 15;
        float val = ps[row*48 + col];
        if (col < 16)       dtr_s[row][col] = val;
        else if (col < 32)  bmt[(size_t)(b*DS_ + col-16)*L_ + l0 + row] = val;
        else                cmt[(size_t)(b*DS_ + col-32)*L_ + l0 + row] = val;
    }
    __syncthreads();
    // dt_proj: thread -> d = tid, tid+256; 16 rows each; softplus; float4 stores
    #pragma unroll
    for (int q = 0; q < 2; q++) {
        int d = tid + q*256;
        float wreg[16];
        const float4* wp = (const float4*)(DTW + (size_t)d*16);
        #pragma unroll
        for (int k4 = 0; k4 < 4; k4++) {
            float4 v = wp[k4];
            wreg[4*k4+0] = v.x; wreg[4*k4+1] = v.y;
            wreg[4*k4+2] = v.z; wreg[4*k4+3] = v.w;
        }
        float bias = DTB[d];
        float dtv[16];
        #pragma unroll
        for (int r = 0; r < 16; r++) {
            float a = bias;
            #pragma unroll
            for (int k = 0; k < 16; k++) a = fmaf(dtr_s[r][k], wreg[k], a);
            dtv[r] = a > 20.f ? a : log1pf(__expf(a));
        }
        float* dp = dtt + (size_t)(b*DI_ + d)*L_ + l0;
        #pragma unroll
        for (int r4 = 0; r4 < 4; r4++)
            *(float4*)(dp + 4*r4) = make_float4(dtv[4*r4], dtv[4*r4+1],
                                                dtv[4*r4+2], dtv[4*r4+3]);
    }
}

// ---------------- chunked selective scan ----------------
// grid(NC_, 32, B_), block 256 = 16 d x 16 n.
__global__ __launch_bounds__(256) void scan_phase1(
    const float* __restrict__ dtt, const ushort_t* __restrict__ ut,
    const float* __restrict__ bmt, const float* __restrict__ Alog,
    float* __restrict__ send, float* __restrict__ aprod)
{
    const int c = blockIdx.x, g = blockIdx.y, b = blockIdx.z;
    const int tid = threadIdx.x;
    const int n = tid & 15, dd = tid >> 4;
    const int d = g*16 + dd;
    const float Ac = -__expf(Alog[d*DS_ + n]);
    const int l0 = c * CL_;
    const float*    dtp = dtt + (size_t)(b*DI_ + d)*L_ + l0;
    const ushort_t* up  = ut  + (size_t)(b*DI_ + d)*L_ + l0;
    const float*    bp  = bmt + (size_t)(b*DS_ + n)*L_ + l0;
    float s = 0.f, ap = 1.f;
    for (int l = 0; l < CL_; l += 4) {
        float4 dt4 = *(const float4*)(dtp + l);
        ushort4 u4 = *(const ushort4*)(up + l);
        float4 b4  = *(const float4*)(bp + l);
        float dtv[4] = {dt4.x, dt4.y, dt4.z, dt4.w};
        float uv[4]  = {bf2f(u4.x), bf2f(u4.y), bf2f(u4.z), bf2f(u4.w)};
        float bv[4]  = {b4.x, b4.y, b4.z, b4.w};
        #pragma unroll
        for (int j = 0; j < 4; j++) {
            float e = __expf(dtv[j] * Ac);
            s = fmaf(e, s, dtv[j]*bv[j]*uv[j]);
            ap *= e;
        }
    }
    size_t idx = ((size_t)(b*DI_ + d)*DS_ + n)*NC_ + c;
    send[idx]  = s;
    aprod[idx] = ap;
}

__global__ __launch_bounds__(256) void scan_phase2(
    float* __restrict__ send, const float* __restrict__ aprod)
{
    int t = blockIdx.x*256 + threadIdx.x;   // B_*DI_*DS_ = 16384 threads
    size_t base = (size_t)t * NC_;
    float s = 0.f;
    for (int c = 0; c < NC_; c++) {
        float tmp = send[base + c];
        send[base + c] = s;
        s = fmaf(aprod[base + c], s, tmp);
    }
}

// Phase 3: re-run chunk with incoming state; y+u*D -> LDS tile; cooperative
// coalesced epilogue applies silu(z) and stores bf16.
__global__ __launch_bounds__(256) void scan_phase3(
    const float* __restrict__ dtt, const ushort_t* __restrict__ ut,
    const float* __restrict__ bmt, const float* __restrict__ cmt,
    const float* __restrict__ Alog, const float* __restrict__ Dv,
    const float* __restrict__ sin_, const float* __restrict__ xz,
    ushort_t* __restrict__ ysb)
{
    __shared__ float ytile[16][CL_ + 1];
    const int c = blockIdx.x, g = blockIdx.y, b = blockIdx.z;
    const int tid = threadIdx.x;
    const int n = tid & 15, dd = tid >> 4;
    const int d = g*16 + dd;
    const float Ac = -__expf(Alog[d*DS_ + n]);
    const float Dd = Dv[d];
    const int l0 = c * CL_;
    const float*    dtp = dtt + (size_t)(b*DI_ + d)*L_ + l0;
    const ushort_t* up  = ut  + (size_t)(b*DI_ + d)*L_ + l0;
    const float*    bp  = bmt + (size_t)(b*DS_ + n)*L_ + l0;
    const float*    cp  = cmt + (size_t)(b*DS_ + n)*L_ + l0;
    float s = sin_[((size_t)(b*DI_ + d)*DS_ + n)*NC_ + c];
    for (int l = 0; l < CL_; l += 4) {
        float4 dt4 = *(const float4*)(dtp + l);
        ushort4 u4 = *(const ushort4*)(up + l);
        float4 b4  = *(const float4*)(bp + l);
        float4 c4  = *(const float4*)(cp + l);
        float dtv[4] = {dt4.x, dt4.y, dt4.z, dt4.w};
        float uv[4]  = {bf2f(u4.x), bf2f(u4.y), bf2f(u4.z), bf2f(u4.w)};
        float bv[4]  = {b4.x, b4.y, b4.z, b4.w};
        float cv[4]  = {c4.x, c4.y, c4.z, c4.w};
        #pragma unroll
        for (int j = 0; j < 4; j++) {
            float e = __expf(dtv[j] * Ac);
            s = fmaf(e, s, dtv[j]*bv[j]*uv[j]);
            float y = s * cv[j];
            y += __shfl_xor(y, 1);
            y += __shfl_xor(y, 2);
            y += __shfl_xor(y, 4);
            y += __shfl_xor(y, 8);
            if (n == 0) ytile[dd][l + j] = fmaf(uv[j], Dd, y);
        }
    }
    __syncthreads();
    // epilogue: thread -> (2 consecutive d, 1 l); 32 l-rows per pass
    const int ed = (tid & 7) * 2;          // 0,2,..,14
    const int eli = tid >> 3;              // 0..31
    #pragma unroll
    for (int p = 0; p < (CL_ + 31)/32; p++) {
        int ll = eli + p*32;
        if (ll < CL_) {
            int gl = l0 + ll;
            const float* zp = xz + (size_t)(b*L_ + gl)*1024 + 512 + g*16 + ed;
            float2 zv = *(const float2*)zp;
            ushort_t o[2] = {f2bf(ytile[ed][ll]   * siluf(zv.x)),
                             f2bf(ytile[ed+1][ll] * siluf(zv.y))};
            *(ushort2*)(ysb + (size_t)(b*L_ + gl)*DI_ + g*16 + ed) = *(ushort2*)&o[0];
        }
    }
}

// ---------------- final LN + head dot ----------------
__global__ __launch_bounds__(256) void final_kernel(
    const float* __restrict__ h, const float* __restrict__ fw,
    const float* __restrict__ fb, const float* __restrict__ hw,
    const float* __restrict__ hb, float* __restrict__ out)
{
    __shared__ float sm[4];
    int row = blockIdx.x, tid = threadIdx.x;
    float v = h[(size_t)row*DM_ + tid];
    float s = v;
    #pragma unroll
    for (int o = 32; o > 0; o >>= 1) s += __shfl_down(s, o);
    if ((tid & 63) == 0) sm[tid >> 6] = s;
    __syncthreads();
    float mu = (sm[0]+sm[1]+sm[2]+sm[3]) * (1.f/DM_);
    __syncthreads();
    float dv = v - mu;
    float q = dv*dv;
    #pragma unroll
    for (int o = 32; o > 0; o >>= 1) q += __shfl_down(q, o);
    if ((tid & 63) == 0) sm[tid >> 6] = q;
    __syncthreads();
    float var = (sm[0]+sm[1]+sm[2]+sm[3]) * (1.f/DM_);
    float nv = dv * rsqrtf(var + 1e-5f) * fw[tid] + fb[tid];
    float p = nv * hw[tid];
    __syncthreads();
    #pragma unroll
    for (int o = 32; o > 0; o >>= 1) p += __shfl_down(p, o);
    if ((tid & 63) == 0) sm[tid >> 6] = p;
    __syncthreads();
    if (tid == 0) out[row] = sm[0]+sm[1]+sm[2]+sm[3] + hb[0];
}

extern "C" void kernel_launch(void* const* d_in, const int* in_sizes, int n_in,
                              void* d_out, int out_size, void* d_ws, size_t ws_size,
                              hipStream_t stream)
{
    const float* x    = (const float*)d_in[0];
    const float* biw  = (const float*)d_in[1];
    const float* bib  = (const float*)d_in[2];
    const float* ge   = (const float*)d_in[3];
    const float* me   = (const float*)d_in[4];
    const float* lnw  = (const float*)d_in[5];
    const float* lnb  = (const float*)d_in[6];
    const float* ipw  = (const float*)d_in[7];
    const float* cw   = (const float*)d_in[8];
    const float* cb   = (const float*)d_in[9];
    const float* xpw  = (const float*)d_in[10];
    const float* dtw  = (const float*)d_in[11];
    const float* dtb  = (const float*)d_in[12];
    const float* alog = (const float*)d_in[13];
    const float* Dv   = (const float*)d_in[14];
    const float* opw  = (const float*)d_in[15];
    const float* fw   = (const float*)d_in[16];
    const float* fb   = (const float*)d_in[17];
    const float* hw   = (const float*)d_in[18];
    const float* hb   = (const float*)d_in[19];
    float* out = (float*)d_out;

    // workspace layout (float units; all offsets 16B-aligned); ~13.7M f = 55 MB
    float* ws  = (float*)d_ws;
    float* h     = ws;                                   // 1,048,576 f
    float* scr   = h + (size_t)BLP_*DM_;                 // 655,360 f (hnb)
    float* xz    = scr + 655360;                         // 4,194,304 f
    float* dtt   = xz + (size_t)BLP_*1024;               // 2,048,000 f
    float* bmt   = dtt + (size_t)B_*DI_*L_;              // 64,000 f
    float* cmt   = bmt + (size_t)B_*DS_*L_;              // 64,000 f
    float* send  = cmt + (size_t)B_*DS_*L_;              // 819,200 f
    float* aprod = send + (size_t)B_*DI_*DS_*NC_;        // 819,200 f
    ushort_t* u_bf  = (ushort_t*)(aprod + (size_t)B_*DI_*DS_*NC_); // BLP_*DI_ us
    ushort_t* ut_bf = u_bf + (size_t)BLP_*DI_;           // B_*DI_*L_ us
    ushort_t* ysbb  = ut_bf + (size_t)B_*DI_*L_;         // BLP_*DI_ us
    ushort_t* ipwb  = ysbb + (size_t)BLP_*DI_;           // NL_*1024*DM_ us
    ushort_t* opwb  = ipwb + (size_t)NL_*1024*DM_;       // NL_*DM_*DI_ us
    ushort_t* xpwb  = opwb + (size_t)NL_*DM_*DI_;        // NL_*48*512 us
    ushort_t* hnb   = (ushort_t*)scr;                    // BLP_*DM_ us

    // convert weights to bf16 (every launch; ~1.7M elements)
    f2bf_kernel<<<(NL_*1024*DM_/4 + 255)/256, 256, 0, stream>>>(ipw, ipwb, NL_*1024*DM_/4);
    f2bf_kernel<<<(NL_*DM_*DI_/4 + 255)/256, 256, 0, stream>>>(opw, opwb, NL_*DM_*DI_/4);
    f2bf_kernel<<<(NL_*48*512/4 + 255)/256, 256, 0, stream>>>(xpw, xpwb, NL_*48*512/4);

    embed_kernel<<<BL_, 256, 0, stream>>>(x, biw, bib, ge, me, h);
    for (int i = 0; i < NL_; i++) {
        ln_kernel<<<BL_, 256, 0, stream>>>(h, lnw + i*DM_, lnb + i*DM_, hnb);
        gemm_mfma<false><<<dim3(BLP_/128, 1024/128), 256, 0, stream>>>(
            hnb, ipwb + (size_t)i*1024*DM_, xz, 1024, DM_);
        conv_silu_kernel<<<dim3(32, 8, B_), 256, 0, stream>>>(
            xz, cw + i*DI_*4, cb + i*DI_, u_bf, ut_bf);
        xproj_dt_kernel<<<dim3(125, B_), 256, 0, stream>>>(
            u_bf, xpwb + (size_t)i*48*512, dtw + (size_t)i*DI_*16, dtb + i*DI_,
            bmt, cmt, dtt);
        scan_phase1<<<dim3(NC_, DI_/16, B_), 256, 0, stream>>>(
            dtt, ut_bf, bmt, alog + (size_t)i*DI_*DS_, send, aprod);
        scan_phase2<<<B_*DI_*DS_/256, 256, 0, stream>>>(send, aprod);
        scan_phase3<<<dim3(NC_, DI_/16, B_), 256, 0, stream>>>(
            dtt, ut_bf, bmt, cmt, alog + (size_t)i*DI_*DS_, Dv + i*DI_,
            send, xz, ysbb);
        gemm_mfma<true><<<dim3(BLP_/128, DM_/128), 256, 0, stream>>>(
            ysbb, opwb + (size_t)i*DM_*DI_, h, DM_, DI_);
    }
    final_kernel<<<BL_, 256, 0, stream>>>(h, fw, fb, hw, hb, out);
}

// Round 7
// 591.723 us; speedup vs baseline: 4.1080x; 1.0996x over previous
//
#include <hip/hip_runtime.h>
#include <math.h>

#define B_  2
#define L_  2000
#define DM_ 256
#define DI_ 512
#define DS_ 16
#define NL_ 4
#define BL_ (B_*L_)     // 4000
#define BLP_ 4096       // rows padded to multiple of 64
#define NC_ 25          // scan chunks
#define CL_ 80          // chunk length (L_ = NC_*CL_; 80 f = 320 B = 5 HBM lines)

typedef unsigned short ushort_t;
typedef __attribute__((ext_vector_type(8))) short bf16x8;
typedef __attribute__((ext_vector_type(4))) float f32x4;

__device__ __forceinline__ float siluf(float x) {
    return x / (1.f + __expf(-x));
}

__device__ __forceinline__ ushort_t f2bf(float x) {
    unsigned int u = __float_as_uint(x);
    unsigned int r = (u + 0x7FFFu + ((u >> 16) & 1u)) >> 16;
    return (ushort_t)r;
}

__device__ __forceinline__ float bf2f(ushort_t v) {
    return __uint_as_float(((unsigned int)v) << 16);
}

// ---------------- fp32 -> bf16 conversion (4 el/thread) ----------------
__global__ __launch_bounds__(256) void f2bf_kernel(
    const float* __restrict__ src, ushort_t* __restrict__ dst, int n4)
{
    int i = (blockIdx.x*256 + threadIdx.x);
    if (i < n4) {
        float4 v = *(const float4*)(src + 4*i);
        ushort_t o[4] = {f2bf(v.x), f2bf(v.y), f2bf(v.z), f2bf(v.w)};
        *(ushort2*)(dst + 4*i)     = *(ushort2*)&o[0];
        *(ushort2*)(dst + 4*i + 2) = *(ushort2*)&o[2];
    }
}

// ---------------- embed: h = x*biw + bib + gene_emb + mod_emb ----------------
__global__ __launch_bounds__(256) void embed_kernel(
    const float* __restrict__ x, const float* __restrict__ biw,
    const float* __restrict__ bib, const float* __restrict__ ge,
    const float* __restrict__ me, float* __restrict__ h)
{
    int bl = blockIdx.x, d = threadIdx.x;
    int l = bl % L_;
    h[(size_t)bl*DM_ + d] = x[bl]*biw[d] + bib[d] + ge[(size_t)l*DM_ + d] + me[d];
}

// ---------------- layernorm over D_MODEL=256 -> bf16 output ----------------
__global__ __launch_bounds__(256) void ln_kernel(
    const float* __restrict__ h, const float* __restrict__ w,
    const float* __restrict__ b, ushort_t* __restrict__ out)
{
    __shared__ float sm[4];
    int row = blockIdx.x, tid = threadIdx.x;
    float v = h[(size_t)row*DM_ + tid];
    float s = v;
    #pragma unroll
    for (int o = 32; o > 0; o >>= 1) s += __shfl_down(s, o);
    if ((tid & 63) == 0) sm[tid >> 6] = s;
    __syncthreads();
    float mu = (sm[0]+sm[1]+sm[2]+sm[3]) * (1.f/DM_);
    __syncthreads();
    float d = v - mu;
    float q = d*d;
    #pragma unroll
    for (int o = 32; o > 0; o >>= 1) q += __shfl_down(q, o);
    if ((tid & 63) == 0) sm[tid >> 6] = q;
    __syncthreads();
    float var = (sm[0]+sm[1]+sm[2]+sm[3]) * (1.f/DM_);
    out[(size_t)row*DM_ + tid] = f2bf(d * rsqrtf(var + 1e-5f) * w[tid] + b[tid]);
}

// ---------------- bf16 MFMA GEMM: C[m,n] (+)= sum_k A[m,k]*W[n,k] ----------------
template<bool ACCUM>
__global__ __launch_bounds__(256) void gemm_mfma(
    const ushort_t* __restrict__ A, const ushort_t* __restrict__ W,
    float* __restrict__ C, int ldc, int K)
{
    __shared__ ushort_t a_s[128*64];
    __shared__ ushort_t b_s[128*64];
    const int r0 = blockIdx.x*128, c0 = blockIdx.y*128;
    const int tid = threadIdx.x;
    const int lane = tid & 63, w = tid >> 6;
    const int wm = (w & 1)*64, wn = (w >> 1)*64;
    const int qd = lane >> 4, l16 = lane & 15;
    f32x4 acc[4][4] = {};
    for (int kc = 0; kc < K; kc += 64) {
        #pragma unroll
        for (int q = 0; q < 4; q++) {
            int ch = tid + 256*q;              // 0..1023
            int row = ch >> 3, col8 = (ch & 7)*8;
            *(bf16x8*)&a_s[row*64 + col8] =
                *(const bf16x8*)(A + (size_t)(r0 + row)*K + kc + col8);
            *(bf16x8*)&b_s[row*64 + col8] =
                *(const bf16x8*)(W + (size_t)(c0 + row)*K + kc + col8);
        }
        __syncthreads();
        #pragma unroll
        for (int ks = 0; ks < 2; ks++) {
            bf16x8 af[4], bf[4];
            #pragma unroll
            for (int i = 0; i < 4; i++)
                af[i] = *(const bf16x8*)&a_s[(wm + i*16 + l16)*64 + ks*32 + qd*8];
            #pragma unroll
            for (int j = 0; j < 4; j++)
                bf[j] = *(const bf16x8*)&b_s[(wn + j*16 + l16)*64 + ks*32 + qd*8];
            #pragma unroll
            for (int i = 0; i < 4; i++) {
                #pragma unroll
                for (int j = 0; j < 4; j++)
                    acc[i][j] = __builtin_amdgcn_mfma_f32_16x16x32_bf16(
                        af[i], bf[j], acc[i][j], 0, 0, 0);
            }
        }
        __syncthreads();
    }
    // C/D layout: col = lane&15, row = (lane>>4)*4 + reg
    #pragma unroll
    for (int i = 0; i < 4; i++) {
        #pragma unroll
        for (int j = 0; j < 4; j++) {
            #pragma unroll
            for (int r = 0; r < 4; r++) {
                int row = r0 + wm + i*16 + qd*4 + r;
                int col = c0 + wn + j*16 + l16;
                size_t idx = (size_t)row*ldc + col;
                if constexpr (ACCUM) C[idx] += acc[i][j][r];
                else                 C[idx]  = acc[i][j][r];
            }
        }
    }
}

// ---------------- conv(4) + silu, tiled; writes u_bf (b,l,c) + ut_bf (b,c,l), both bf16 ----
__global__ __launch_bounds__(256) void conv_silu_kernel(
    const float* __restrict__ xz, const float* __restrict__ cw,
    const float* __restrict__ cb, ushort_t* __restrict__ u_bf,
    ushort_t* __restrict__ ut_bf)
{
    __shared__ float xs[67][68];
    __shared__ ushort_t us[64][72];
    const int l0 = blockIdx.x * 64, c0 = blockIdx.y * 64, b = blockIdx.z;
    const int tid = threadIdx.x;
    // stage xz tile rows l0-3 .. l0+63
    for (int f = tid; f < 67*16; f += 256) {
        int row = f >> 4, c4 = (f & 15) * 4;
        int l = l0 - 3 + row;
        float4 v = {0.f, 0.f, 0.f, 0.f};
        if (l >= 0 && l < L_)
            v = *(const float4*)(xz + (size_t)(b*L_ + l)*1024 + c0 + c4);
        *(float4*)&xs[row][c4] = v;
    }
    __syncthreads();
    // conv: thread -> fixed c, 16 consecutive l
    const int c_loc = tid & 63, lq = tid >> 6;
    const int c = c0 + c_loc;
    float4 wv = *(const float4*)(cw + c*4);
    float bias = cb[c];
    float x0 = xs[lq*16 + 0][c_loc];
    float x1 = xs[lq*16 + 1][c_loc];
    float x2 = xs[lq*16 + 2][c_loc];
    ushort_t ush[16];
    #pragma unroll
    for (int j = 0; j < 16; j++) {
        float x3 = xs[lq*16 + 3 + j][c_loc];
        float v = fmaf(x0, wv.x, fmaf(x1, wv.y, fmaf(x2, wv.z, fmaf(x3, wv.w, bias))));
        ush[j] = f2bf(siluf(v));
        us[lq*16 + j][c_loc] = ush[j];
        x0 = x1; x1 = x2; x2 = x3;
    }
    // ut_bf: 16 bf16 = 32 B contiguous per c
    int lg0 = l0 + lq*16;
    if (lg0 < L_) {
        unsigned int r[8];
        #pragma unroll
        for (int j = 0; j < 8; j++)
            r[j] = (unsigned int)ush[2*j] | ((unsigned int)ush[2*j+1] << 16);
        ushort_t* dst = ut_bf + (size_t)(b*DI_ + c)*L_ + lg0;
        *(uint4*)dst       = *(uint4*)&r[0];
        *(uint4*)(dst + 8) = *(uint4*)&r[4];
    }
    __syncthreads();
    // u_bf rows (l,c) via LDS transpose, 16B stores
    for (int f = tid; f < 64*8; f += 256) {
        int row = f >> 3, g8 = (f & 7)*8;
        if (l0 + row < L_)
            *(uint4*)(u_bf + (size_t)(b*L_ + l0 + row)*512 + c0 + g8) =
                *(const uint4*)&us[row][g8];
    }
}

// ---------------- x_proj via MFMA + fused dt_proj ----------------
__global__ __launch_bounds__(256) void xproj_dt_kernel(
    const ushort_t* __restrict__ U, const ushort_t* __restrict__ XWb,
    const float* __restrict__ DTW, const float* __restrict__ DTB,
    float* __restrict__ bmt, float* __restrict__ cmt, float* __restrict__ dtt)
{
    __shared__ ushort_t a_s[16*520];
    __shared__ ushort_t w_s[48*520];
    __shared__ float ps[4*16*48];
    __shared__ float dtr_s[16][16];
    const int l0 = blockIdx.x * 16, b = blockIdx.y;
    const int tid = threadIdx.x;
    const int lane = tid & 63, w = tid >> 6;
    const int qd = lane >> 4, l16 = lane & 15;
    // stage A (16x512): 1024 16B-chunks
    #pragma unroll
    for (int q = 0; q < 4; q++) {
        int f = tid + 256*q;
        int row = f >> 6, col8 = (f & 63)*8;
        *(bf16x8*)&a_s[row*520 + col8] =
            *(const bf16x8*)(U + (size_t)(b*L_ + l0 + row)*512 + col8);
    }
    // stage W (48x512): 3072 16B-chunks
    #pragma unroll
    for (int q = 0; q < 12; q++) {
        int f = tid + 256*q;
        int row = f >> 6, col8 = (f & 63)*8;
        *(bf16x8*)&w_s[row*520 + col8] =
            *(const bf16x8*)(XWb + (size_t)row*512 + col8);
    }
    __syncthreads();
    // MFMA: wave w covers K in [128w, 128w+128)
    f32x4 acc[3] = {};
    #pragma unroll
    for (int step = 0; step < 4; step++) {
        int k = w*128 + step*32 + qd*8;
        bf16x8 af = *(const bf16x8*)&a_s[l16*520 + k];
        #pragma unroll
        for (int j = 0; j < 3; j++) {
            bf16x8 bf = *(const bf16x8*)&w_s[(j*16 + l16)*520 + k];
            acc[j] = __builtin_amdgcn_mfma_f32_16x16x32_bf16(af, bf, acc[j], 0, 0, 0);
        }
    }
    // partials -> LDS
    #pragma unroll
    for (int j = 0; j < 3; j++) {
        #pragma unroll
        for (int r = 0; r < 4; r++)
            ps[(w*16 + qd*4 + r)*48 + j*16 + l16] = acc[j][r];
    }
    __syncthreads();
    // reduce 4 partials into ps[0..767]
    #pragma unroll
    for (int e = tid; e < 768; e += 256)
        ps[e] = ps[e] + ps[768 + e] + ps[1536 + e] + ps[2304 + e];
    __syncthreads();
    // scatter: e = q*256+tid, col = e>>4 (0..47), row = e&15
    #pragma unroll
    for (int q = 0; q < 3; q++) {
        int e = q*256 + tid;
        int col = e >> 4, row = e & 15;
        float val = ps[row*48 + col];
        if (col < 16)       dtr_s[row][col] = val;
        else if (col < 32)  bmt[(size_t)(b*DS_ + col-16)*L_ + l0 + row] = val;
        else                cmt[(size_t)(b*DS_ + col-32)*L_ + l0 + row] = val;
    }
    __syncthreads();
    // dt_proj: thread -> d = tid, tid+256; 16 rows each; softplus; float4 stores
    #pragma unroll
    for (int q = 0; q < 2; q++) {
        int d = tid + q*256;
        float wreg[16];
        const float4* wp = (const float4*)(DTW + (size_t)d*16);
        #pragma unroll
        for (int k4 = 0; k4 < 4; k4++) {
            float4 v = wp[k4];
            wreg[4*k4+0] = v.x; wreg[4*k4+1] = v.y;
            wreg[4*k4+2] = v.z; wreg[4*k4+3] = v.w;
        }
        float bias = DTB[d];
        float dtv[16];
        #pragma unroll
        for (int r = 0; r < 16; r++) {
            float a = bias;
            #pragma unroll
            for (int k = 0; k < 16; k++) a = fmaf(dtr_s[r][k], wreg[k], a);
            dtv[r] = a > 20.f ? a : log1pf(__expf(a));
        }
        float* dp = dtt + (size_t)(b*DI_ + d)*L_ + l0;
        #pragma unroll
        for (int r4 = 0; r4 < 4; r4++)
            *(float4*)(dp + 4*r4) = make_float4(dtv[4*r4], dtv[4*r4+1],
                                                dtv[4*r4+2], dtv[4*r4+3]);
    }
}

// ---------------- chunked selective scan, LDS-staged ----------------
// grid(NC_, 32, B_), block 256 = 16 d x 16 n. All chunk operands staged to
// LDS with coalesced full-row loads (80 f = 5 exact 64B lines). Row pad 84:
// bank phase 20 -> only free 2-way (n, n+8) aliasing.
// send/aprod layout: [c][b][d][n] -> each block stores one contiguous 1KB.
__global__ __launch_bounds__(256) void scan_phase1(
    const float* __restrict__ dtt, const ushort_t* __restrict__ ut,
    const float* __restrict__ bmt, const float* __restrict__ Alog,
    float* __restrict__ send, float* __restrict__ aprod)
{
    __shared__ float dt_s[16][84];
    __shared__ float b_s[16][84];
    __shared__ ushort_t u_s[16][88];
    const int c = blockIdx.x, g = blockIdx.y, b = blockIdx.z;
    const int tid = threadIdx.x;
    const int n = tid & 15, dd = tid >> 4;
    const int d = g*16 + dd;
    const int l0 = c * CL_;
    for (int f = tid; f < 320; f += 256) {
        int row = f / 20, col = (f % 20) * 4;
        *(float4*)&dt_s[row][col] =
            *(const float4*)(dtt + (size_t)(b*DI_ + g*16 + row)*L_ + l0 + col);
        *(float4*)&b_s[row][col] =
            *(const float4*)(bmt + (size_t)(b*DS_ + row)*L_ + l0 + col);
    }
    for (int f = tid; f < 160; f += 256) {
        int row = f / 10, col = (f % 10) * 8;
        *(uint4*)&u_s[row][col] =
            *(const uint4*)(ut + (size_t)(b*DI_ + g*16 + row)*L_ + l0 + col);
    }
    const float Ac = -__expf(Alog[d*DS_ + n]);
    __syncthreads();
    float s = 0.f, ap = 1.f;
    for (int l = 0; l < CL_; l += 4) {
        float4 dt4 = *(const float4*)&dt_s[dd][l];
        float4 b4  = *(const float4*)&b_s[n][l];
        ushort4 u4 = *(const ushort4*)&u_s[dd][l];
        float dtv[4] = {dt4.x, dt4.y, dt4.z, dt4.w};
        float uv[4]  = {bf2f(u4.x), bf2f(u4.y), bf2f(u4.z), bf2f(u4.w)};
        float bv[4]  = {b4.x, b4.y, b4.z, b4.w};
        #pragma unroll
        for (int j = 0; j < 4; j++) {
            float e = __expf(dtv[j] * Ac);
            s = fmaf(e, s, dtv[j]*bv[j]*uv[j]);
            ap *= e;
        }
    }
    size_t idx = (((size_t)c*B_ + b)*DI_ + d)*DS_ + n;   // block-contiguous
    send[idx]  = s;
    aprod[idx] = ap;
}

__global__ __launch_bounds__(256) void scan_phase2(
    float* __restrict__ send, const float* __restrict__ aprod)
{
    int t = blockIdx.x*256 + threadIdx.x;   // B_*DI_*DS_ = 16384 threads
    float s = 0.f;
    for (int c = 0; c < NC_; c++) {
        size_t idx = (size_t)c*(B_*DI_*DS_) + t;         // coalesced per c
        float tmp = send[idx];
        send[idx] = s;
        s = fmaf(aprod[idx], s, tmp);
    }
}

// Phase 3: LDS-staged chunk re-run with incoming state; y+u*D -> LDS tile;
// cooperative coalesced epilogue applies silu(z), stores bf16.
__global__ __launch_bounds__(256) void scan_phase3(
    const float* __restrict__ dtt, const ushort_t* __restrict__ ut,
    const float* __restrict__ bmt, const float* __restrict__ cmt,
    const float* __restrict__ Alog, const float* __restrict__ Dv,
    const float* __restrict__ sin_, const float* __restrict__ xz,
    ushort_t* __restrict__ ysb)
{
    __shared__ float dt_s[16][84];
    __shared__ float b_s[16][84];
    __shared__ float c_s[16][84];
    __shared__ float ytile[16][84];
    __shared__ ushort_t u_s[16][88];
    const int c = blockIdx.x, g = blockIdx.y, b = blockIdx.z;
    const int tid = threadIdx.x;
    const int n = tid & 15, dd = tid >> 4;
    const int d = g*16 + dd;
    const int l0 = c * CL_;
    for (int f = tid; f < 320; f += 256) {
        int row = f / 20, col = (f % 20) * 4;
        *(float4*)&dt_s[row][col] =
            *(const float4*)(dtt + (size_t)(b*DI_ + g*16 + row)*L_ + l0 + col);
        *(float4*)&b_s[row][col] =
            *(const float4*)(bmt + (size_t)(b*DS_ + row)*L_ + l0 + col);
        *(float4*)&c_s[row][col] =
            *(const float4*)(cmt + (size_t)(b*DS_ + row)*L_ + l0 + col);
    }
    for (int f = tid; f < 160; f += 256) {
        int row = f / 10, col = (f % 10) * 8;
        *(uint4*)&u_s[row][col] =
            *(const uint4*)(ut + (size_t)(b*DI_ + g*16 + row)*L_ + l0 + col);
    }
    const float Ac = -__expf(Alog[d*DS_ + n]);
    const float Dd = Dv[d];
    float s = sin_[(((size_t)c*B_ + b)*DI_ + d)*DS_ + n];
    __syncthreads();
    for (int l = 0; l < CL_; l += 4) {
        float4 dt4 = *(const float4*)&dt_s[dd][l];
        float4 b4  = *(const float4*)&b_s[n][l];
        float4 c4  = *(const float4*)&c_s[n][l];
        ushort4 u4 = *(const ushort4*)&u_s[dd][l];
        float dtv[4] = {dt4.x, dt4.y, dt4.z, dt4.w};
        float uv[4]  = {bf2f(u4.x), bf2f(u4.y), bf2f(u4.z), bf2f(u4.w)};
        float bv[4]  = {b4.x, b4.y, b4.z, b4.w};
        float cv[4]  = {c4.x, c4.y, c4.z, c4.w};
        #pragma unroll
        for (int j = 0; j < 4; j++) {
            float e = __expf(dtv[j] * Ac);
            s = fmaf(e, s, dtv[j]*bv[j]*uv[j]);
            float y = s * cv[j];
            y += __shfl_xor(y, 1);
            y += __shfl_xor(y, 2);
            y += __shfl_xor(y, 4);
            y += __shfl_xor(y, 8);
            if (n == 0) ytile[dd][l + j] = fmaf(uv[j], Dd, y);
        }
    }
    __syncthreads();
    // epilogue: thread -> (2 consecutive d, 1 l); 32 l-rows per pass
    const int ed = (tid & 7) * 2;          // 0,2,..,14
    const int eli = tid >> 3;              // 0..31
    #pragma unroll
    for (int p = 0; p < (CL_ + 31)/32; p++) {
        int ll = eli + p*32;
        if (ll < CL_) {
            int gl = l0 + ll;
            const float* zp = xz + (size_t)(b*L_ + gl)*1024 + 512 + g*16 + ed;
            float2 zv = *(const float2*)zp;
            ushort_t o[2] = {f2bf(ytile[ed][ll]   * siluf(zv.x)),
                             f2bf(ytile[ed+1][ll] * siluf(zv.y))};
            *(ushort2*)(ysb + (size_t)(b*L_ + gl)*DI_ + g*16 + ed) = *(ushort2*)&o[0];
        }
    }
}

// ---------------- final LN + head dot ----------------
__global__ __launch_bounds__(256) void final_kernel(
    const float* __restrict__ h, const float* __restrict__ fw,
    const float* __restrict__ fb, const float* __restrict__ hw,
    const float* __restrict__ hb, float* __restrict__ out)
{
    __shared__ float sm[4];
    int row = blockIdx.x, tid = threadIdx.x;
    float v = h[(size_t)row*DM_ + tid];
    float s = v;
    #pragma unroll
    for (int o = 32; o > 0; o >>= 1) s += __shfl_down(s, o);
    if ((tid & 63) == 0) sm[tid >> 6] = s;
    __syncthreads();
    float mu = (sm[0]+sm[1]+sm[2]+sm[3]) * (1.f/DM_);
    __syncthreads();
    float dv = v - mu;
    float q = dv*dv;
    #pragma unroll
    for (int o = 32; o > 0; o >>= 1) q += __shfl_down(q, o);
    if ((tid & 63) == 0) sm[tid >> 6] = q;
    __syncthreads();
    float var = (sm[0]+sm[1]+sm[2]+sm[3]) * (1.f/DM_);
    float nv = dv * rsqrtf(var + 1e-5f) * fw[tid] + fb[tid];
    float p = nv * hw[tid];
    __syncthreads();
    #pragma unroll
    for (int o = 32; o > 0; o >>= 1) p += __shfl_down(p, o);
    if ((tid & 63) == 0) sm[tid >> 6] = p;
    __syncthreads();
    if (tid == 0) out[row] = sm[0]+sm[1]+sm[2]+sm[3] + hb[0];
}

extern "C" void kernel_launch(void* const* d_in, const int* in_sizes, int n_in,
                              void* d_out, int out_size, void* d_ws, size_t ws_size,
                              hipStream_t stream)
{
    const float* x    = (const float*)d_in[0];
    const float* biw  = (const float*)d_in[1];
    const float* bib  = (const float*)d_in[2];
    const float* ge   = (const float*)d_in[3];
    const float* me   = (const float*)d_in[4];
    const float* lnw  = (const float*)d_in[5];
    const float* lnb  = (const float*)d_in[6];
    const float* ipw  = (const float*)d_in[7];
    const float* cw   = (const float*)d_in[8];
    const float* cb   = (const float*)d_in[9];
    const float* xpw  = (const float*)d_in[10];
    const float* dtw  = (const float*)d_in[11];
    const float* dtb  = (const float*)d_in[12];
    const float* alog = (const float*)d_in[13];
    const float* Dv   = (const float*)d_in[14];
    const float* opw  = (const float*)d_in[15];
    const float* fw   = (const float*)d_in[16];
    const float* fb   = (const float*)d_in[17];
    const float* hw   = (const float*)d_in[18];
    const float* hb   = (const float*)d_in[19];
    float* out = (float*)d_out;

    // workspace layout (float units; all offsets 16B-aligned)
    float* ws  = (float*)d_ws;
    float* h     = ws;                                   // 1,048,576 f
    float* scr   = h + (size_t)BLP_*DM_;                 // 655,360 f (hnb)
    float* xz    = scr + 655360;                         // 4,194,304 f
    float* dtt   = xz + (size_t)BLP_*1024;               // 2,048,000 f
    float* bmt   = dtt + (size_t)B_*DI_*L_;              // 64,000 f
    float* cmt   = bmt + (size_t)B_*DS_*L_;              // 64,000 f
    float* send  = cmt + (size_t)B_*DS_*L_;              // 409,600 f
    float* aprod = send + (size_t)B_*DI_*DS_*NC_;        // 409,600 f
    ushort_t* u_bf  = (ushort_t*)(aprod + (size_t)B_*DI_*DS_*NC_); // BLP_*DI_ us
    ushort_t* ut_bf = u_bf + (size_t)BLP_*DI_;           // B_*DI_*L_ us
    ushort_t* ysbb  = ut_bf + (size_t)B_*DI_*L_;         // BLP_*DI_ us
    ushort_t* ipwb  = ysbb + (size_t)BLP_*DI_;           // NL_*1024*DM_ us
    ushort_t* opwb  = ipwb + (size_t)NL_*1024*DM_;       // NL_*DM_*DI_ us
    ushort_t* xpwb  = opwb + (size_t)NL_*DM_*DI_;        // NL_*48*512 us
    ushort_t* hnb   = (ushort_t*)scr;                    // BLP_*DM_ us

    // convert weights to bf16 (every launch; ~1.7M elements)
    f2bf_kernel<<<(NL_*1024*DM_/4 + 255)/256, 256, 0, stream>>>(ipw, ipwb, NL_*1024*DM_/4);
    f2bf_kernel<<<(NL_*DM_*DI_/4 + 255)/256, 256, 0, stream>>>(opw, opwb, NL_*DM_*DI_/4);
    f2bf_kernel<<<(NL_*48*512/4 + 255)/256, 256, 0, stream>>>(xpw, xpwb, NL_*48*512/4);

    embed_kernel<<<BL_, 256, 0, stream>>>(x, biw, bib, ge, me, h);
    for (int i = 0; i < NL_; i++) {
        ln_kernel<<<BL_, 256, 0, stream>>>(h, lnw + i*DM_, lnb + i*DM_, hnb);
        gemm_mfma<false><<<dim3(BLP_/128, 1024/128), 256, 0, stream>>>(
            hnb, ipwb + (size_t)i*1024*DM_, xz, 1024, DM_);
        conv_silu_kernel<<<dim3(32, 8, B_), 256, 0, stream>>>(
            xz, cw + i*DI_*4, cb + i*DI_, u_bf, ut_bf);
        xproj_dt_kernel<<<dim3(125, B_), 256, 0, stream>>>(
            u_bf, xpwb + (size_t)i*48*512, dtw + (size_t)i*DI_*16, dtb + i*DI_,
            bmt, cmt, dtt);
        scan_phase1<<<dim3(NC_, DI_/16, B_), 256, 0, stream>>>(
            dtt, ut_bf, bmt, alog + (size_t)i*DI_*DS_, send, aprod);
        scan_phase2<<<B_*DI_*DS_/256, 256, 0, stream>>>(send, aprod);
        scan_phase3<<<dim3(NC_, DI_/16, B_), 256, 0, stream>>>(
            dtt, ut_bf, bmt, cmt, alog + (size_t)i*DI_*DS_, Dv + i*DI_,
            send, xz, ysbb);
        gemm_mfma<true><<<dim3(BLP_/128, DM_/128), 256, 0, stream>>>(
            ysbb, opwb + (size_t)i*DM_*DI_, h, DM_, DI_);
    }
    final_kernel<<<BL_, 256, 0, stream>>>(h, fw, fb, hw, hb, out);
}

// Round 8
// 530.625 us; speedup vs baseline: 4.5810x; 1.1151x over previous
//
#include <hip/hip_runtime.h>
#include <math.h>

#define B_  2
#define L_  2000
#define DM_ 256
#define DI_ 512
#define DS_ 16
#define NL_ 4
#define BL_ (B_*L_)     // 4000
#define BLP_ 4096       // rows padded to multiple of 64
#define NC_ 100         // scan chunks
#define CL_ 20          // chunk length (L_ = NC_*CL_)

typedef unsigned short ushort_t;
typedef __attribute__((ext_vector_type(8))) short bf16x8;
typedef __attribute__((ext_vector_type(4))) float f32x4;

__device__ __forceinline__ float siluf(float x) {
    return x / (1.f + __expf(-x));
}

__device__ __forceinline__ ushort_t f2bf(float x) {
    unsigned int u = __float_as_uint(x);
    unsigned int r = (u + 0x7FFFu + ((u >> 16) & 1u)) >> 16;
    return (ushort_t)r;
}

__device__ __forceinline__ float bf2f(ushort_t v) {
    return __uint_as_float(((unsigned int)v) << 16);
}

// ---------------- fp32 -> bf16 conversion (4 el/thread) ----------------
__global__ __launch_bounds__(256) void f2bf_kernel(
    const float* __restrict__ src, ushort_t* __restrict__ dst, int n4)
{
    int i = (blockIdx.x*256 + threadIdx.x);
    if (i < n4) {
        float4 v = *(const float4*)(src + 4*i);
        ushort_t o[4] = {f2bf(v.x), f2bf(v.y), f2bf(v.z), f2bf(v.w)};
        *(ushort2*)(dst + 4*i)     = *(ushort2*)&o[0];
        *(ushort2*)(dst + 4*i + 2) = *(ushort2*)&o[2];
    }
}

// ---------------- embed: h = x*biw + bib + gene_emb + mod_emb ----------------
__global__ __launch_bounds__(256) void embed_kernel(
    const float* __restrict__ x, const float* __restrict__ biw,
    const float* __restrict__ bib, const float* __restrict__ ge,
    const float* __restrict__ me, float* __restrict__ h)
{
    int bl = blockIdx.x, d = threadIdx.x;
    int l = bl % L_;
    h[(size_t)bl*DM_ + d] = x[bl]*biw[d] + bib[d] + ge[(size_t)l*DM_ + d] + me[d];
}

// ---------------- layernorm over D_MODEL=256 -> bf16 output ----------------
__global__ __launch_bounds__(256) void ln_kernel(
    const float* __restrict__ h, const float* __restrict__ w,
    const float* __restrict__ b, ushort_t* __restrict__ out)
{
    __shared__ float sm[4];
    int row = blockIdx.x, tid = threadIdx.x;
    float v = h[(size_t)row*DM_ + tid];
    float s = v;
    #pragma unroll
    for (int o = 32; o > 0; o >>= 1) s += __shfl_down(s, o);
    if ((tid & 63) == 0) sm[tid >> 6] = s;
    __syncthreads();
    float mu = (sm[0]+sm[1]+sm[2]+sm[3]) * (1.f/DM_);
    __syncthreads();
    float d = v - mu;
    float q = d*d;
    #pragma unroll
    for (int o = 32; o > 0; o >>= 1) q += __shfl_down(q, o);
    if ((tid & 63) == 0) sm[tid >> 6] = q;
    __syncthreads();
    float var = (sm[0]+sm[1]+sm[2]+sm[3]) * (1.f/DM_);
    out[(size_t)row*DM_ + tid] = f2bf(d * rsqrtf(var + 1e-5f) * w[tid] + b[tid]);
}

// ---------------- bf16 MFMA GEMM: C[m,n] (+)= sum_k A[m,k]*W[n,k] ----------------
template<bool ACCUM>
__global__ __launch_bounds__(256) void gemm_mfma(
    const ushort_t* __restrict__ A, const ushort_t* __restrict__ W,
    float* __restrict__ C, int ldc, int K)
{
    __shared__ ushort_t a_s[128*64];
    __shared__ ushort_t b_s[128*64];
    const int r0 = blockIdx.x*128, c0 = blockIdx.y*128;
    const int tid = threadIdx.x;
    const int lane = tid & 63, w = tid >> 6;
    const int wm = (w & 1)*64, wn = (w >> 1)*64;
    const int qd = lane >> 4, l16 = lane & 15;
    f32x4 acc[4][4] = {};
    for (int kc = 0; kc < K; kc += 64) {
        #pragma unroll
        for (int q = 0; q < 4; q++) {
            int ch = tid + 256*q;              // 0..1023
            int row = ch >> 3, col8 = (ch & 7)*8;
            *(bf16x8*)&a_s[row*64 + col8] =
                *(const bf16x8*)(A + (size_t)(r0 + row)*K + kc + col8);
            *(bf16x8*)&b_s[row*64 + col8] =
                *(const bf16x8*)(W + (size_t)(c0 + row)*K + kc + col8);
        }
        __syncthreads();
        #pragma unroll
        for (int ks = 0; ks < 2; ks++) {
            bf16x8 af[4], bf[4];
            #pragma unroll
            for (int i = 0; i < 4; i++)
                af[i] = *(const bf16x8*)&a_s[(wm + i*16 + l16)*64 + ks*32 + qd*8];
            #pragma unroll
            for (int j = 0; j < 4; j++)
                bf[j] = *(const bf16x8*)&b_s[(wn + j*16 + l16)*64 + ks*32 + qd*8];
            #pragma unroll
            for (int i = 0; i < 4; i++) {
                #pragma unroll
                for (int j = 0; j < 4; j++)
                    acc[i][j] = __builtin_amdgcn_mfma_f32_16x16x32_bf16(
                        af[i], bf[j], acc[i][j], 0, 0, 0);
            }
        }
        __syncthreads();
    }
    // C/D layout: col = lane&15, row = (lane>>4)*4 + reg
    #pragma unroll
    for (int i = 0; i < 4; i++) {
        #pragma unroll
        for (int j = 0; j < 4; j++) {
            #pragma unroll
            for (int r = 0; r < 4; r++) {
                int row = r0 + wm + i*16 + qd*4 + r;
                int col = c0 + wn + j*16 + l16;
                size_t idx = (size_t)row*ldc + col;
                if constexpr (ACCUM) C[idx] += acc[i][j][r];
                else                 C[idx]  = acc[i][j][r];
            }
        }
    }
}

// ---------------- conv(4) + silu, tiled; writes u_bf (b,l,c) bf16 ----------------
__global__ __launch_bounds__(256) void conv_silu_kernel(
    const float* __restrict__ xz, const float* __restrict__ cw,
    const float* __restrict__ cb, ushort_t* __restrict__ u_bf)
{
    __shared__ float xs[67][68];
    __shared__ ushort_t us[64][72];
    const int l0 = blockIdx.x * 64, c0 = blockIdx.y * 64, b = blockIdx.z;
    const int tid = threadIdx.x;
    // stage xz tile rows l0-3 .. l0+63
    for (int f = tid; f < 67*16; f += 256) {
        int row = f >> 4, c4 = (f & 15) * 4;
        int l = l0 - 3 + row;
        float4 v = {0.f, 0.f, 0.f, 0.f};
        if (l >= 0 && l < L_)
            v = *(const float4*)(xz + (size_t)(b*L_ + l)*1024 + c0 + c4);
        *(float4*)&xs[row][c4] = v;
    }
    __syncthreads();
    // conv: thread -> fixed c, 16 consecutive l
    const int c_loc = tid & 63, lq = tid >> 6;
    const int c = c0 + c_loc;
    float4 wv = *(const float4*)(cw + c*4);
    float bias = cb[c];
    float x0 = xs[lq*16 + 0][c_loc];
    float x1 = xs[lq*16 + 1][c_loc];
    float x2 = xs[lq*16 + 2][c_loc];
    #pragma unroll
    for (int j = 0; j < 16; j++) {
        float x3 = xs[lq*16 + 3 + j][c_loc];
        float v = fmaf(x0, wv.x, fmaf(x1, wv.y, fmaf(x2, wv.z, fmaf(x3, wv.w, bias))));
        us[lq*16 + j][c_loc] = f2bf(siluf(v));
        x0 = x1; x1 = x2; x2 = x3;
    }
    __syncthreads();
    // u_bf rows (l,c) via LDS transpose, 16B stores
    for (int f = tid; f < 64*8; f += 256) {
        int row = f >> 3, g8 = (f & 7)*8;
        if (l0 + row < L_)
            *(uint4*)(u_bf + (size_t)(b*L_ + l0 + row)*512 + c0 + g8) =
                *(const uint4*)&us[row][g8];
    }
}

// ---------------- x_proj via MFMA + fused dt_proj ----------------
// Outputs in l-major layouts: bn/cn (b,l,n) fp32, dtn (b,l,d) fp32.
__global__ __launch_bounds__(256) void xproj_dt_kernel(
    const ushort_t* __restrict__ U, const ushort_t* __restrict__ XWb,
    const float* __restrict__ DTW, const float* __restrict__ DTB,
    float* __restrict__ bn, float* __restrict__ cn, float* __restrict__ dtn)
{
    __shared__ ushort_t a_s[16*520];
    __shared__ ushort_t w_s[48*520];
    __shared__ float ps[4*16*48];
    __shared__ float dtr_s[16][16];
    const int l0 = blockIdx.x * 16, b = blockIdx.y;
    const int tid = threadIdx.x;
    const int lane = tid & 63, w = tid >> 6;
    const int qd = lane >> 4, l16 = lane & 15;
    // stage A (16x512): 1024 16B-chunks
    #pragma unroll
    for (int q = 0; q < 4; q++) {
        int f = tid + 256*q;
        int row = f >> 6, col8 = (f & 63)*8;
        *(bf16x8*)&a_s[row*520 + col8] =
            *(const bf16x8*)(U + (size_t)(b*L_ + l0 + row)*512 + col8);
    }
    // stage W (48x512): 3072 16B-chunks
    #pragma unroll
    for (int q = 0; q < 12; q++) {
        int f = tid + 256*q;
        int row = f >> 6, col8 = (f & 63)*8;
        *(bf16x8*)&w_s[row*520 + col8] =
            *(const bf16x8*)(XWb + (size_t)row*512 + col8);
    }
    __syncthreads();
    // MFMA: wave w covers K in [128w, 128w+128)
    f32x4 acc[3] = {};
    #pragma unroll
    for (int step = 0; step < 4; step++) {
        int k = w*128 + step*32 + qd*8;
        bf16x8 af = *(const bf16x8*)&a_s[l16*520 + k];
        #pragma unroll
        for (int j = 0; j < 3; j++) {
            bf16x8 bf = *(const bf16x8*)&w_s[(j*16 + l16)*520 + k];
            acc[j] = __builtin_amdgcn_mfma_f32_16x16x32_bf16(af, bf, acc[j], 0, 0, 0);
        }
    }
    // partials -> LDS
    #pragma unroll
    for (int j = 0; j < 3; j++) {
        #pragma unroll
        for (int r = 0; r < 4; r++)
            ps[(w*16 + qd*4 + r)*48 + j*16 + l16] = acc[j][r];
    }
    __syncthreads();
    // reduce 4 partials into ps[0..767]
    #pragma unroll
    for (int e = tid; e < 768; e += 256)
        ps[e] = ps[e] + ps[768 + e] + ps[1536 + e] + ps[2304 + e];
    __syncthreads();
    // scatter: thread = (row = tid>>4, n = tid&15); contiguous 1KB stores
    {
        int row = tid >> 4, n = tid & 15;
        dtr_s[row][n] = ps[row*48 + n];
        size_t base = ((size_t)(b*L_) + l0 + row)*DS_ + n;
        bn[base] = ps[row*48 + 16 + n];
        cn[base] = ps[row*48 + 32 + n];
    }
    __syncthreads();
    // dt_proj: thread -> d = tid, tid+256; 16 rows each; softplus; (l,d) stores
    #pragma unroll
    for (int q = 0; q < 2; q++) {
        int d = tid + q*256;
        float wreg[16];
        const float4* wp = (const float4*)(DTW + (size_t)d*16);
        #pragma unroll
        for (int k4 = 0; k4 < 4; k4++) {
            float4 v = wp[k4];
            wreg[4*k4+0] = v.x; wreg[4*k4+1] = v.y;
            wreg[4*k4+2] = v.z; wreg[4*k4+3] = v.w;
        }
        float bias = DTB[d];
        #pragma unroll
        for (int r = 0; r < 16; r++) {
            float a = bias;
            #pragma unroll
            for (int k = 0; k < 16; k++) a = fmaf(dtr_s[r][k], wreg[k], a);
            float dt = a > 20.f ? a : log1pf(__expf(a));
            dtn[((size_t)(b*L_) + l0 + r)*DI_ + d] = dt;
        }
    }
}

// ---------------- chunked selective scan, thread-per-d (no cross-lane) ----------
// grid(NC_, DI_/128, B_), block 128. Thread owns channel d: 16 n-states in
// registers; 16 exp+2x16 fma per element; dt/u/z loads coalesced (l,d)-major;
// B/C chunk staged in LDS, read as same-address b128 broadcasts (free).
__global__ __launch_bounds__(128) void scan_phase1(
    const float* __restrict__ dtn, const ushort_t* __restrict__ u_bf,
    const float* __restrict__ bn, const float* __restrict__ Alog,
    float* __restrict__ send, float* __restrict__ aprod)
{
    __shared__ float b_sh[CL_*DS_];
    const int c = blockIdx.x, qy = blockIdx.y, b = blockIdx.z;
    const int tid = threadIdx.x;
    const int d = qy*128 + tid;
    const int l0 = c*CL_;
    for (int f = tid; f < CL_*DS_; f += 128)
        b_sh[f] = bn[((size_t)(b*L_) + l0)*DS_ + f];
    float Ac[DS_], s[DS_], ap[DS_];
    const float* ar = Alog + (size_t)d*DS_;
    #pragma unroll
    for (int n = 0; n < DS_; n++) { Ac[n] = -__expf(ar[n]); s[n] = 0.f; ap[n] = 1.f; }
    __syncthreads();
    const float*    dtp = dtn  + ((size_t)(b*L_ + l0))*DI_ + d;
    const ushort_t* up  = u_bf + ((size_t)(b*L_ + l0))*DI_ + d;
    for (int l = 0; l < CL_; l++) {
        float dt = dtp[(size_t)l*DI_];
        float u  = bf2f(up[(size_t)l*DI_]);
        float dtu = dt*u;
        float bv[DS_];
        #pragma unroll
        for (int n4 = 0; n4 < 4; n4++)
            *(float4*)&bv[4*n4] = *(const float4*)&b_sh[l*DS_ + 4*n4];
        #pragma unroll
        for (int n = 0; n < DS_; n++) {
            float e = __expf(dt*Ac[n]);
            s[n] = fmaf(e, s[n], dtu*bv[n]);
            ap[n] *= e;
        }
    }
    size_t base = (((size_t)c*B_ + b)*DI_ + d)*DS_;
    #pragma unroll
    for (int n4 = 0; n4 < 4; n4++) {
        *(float4*)(send  + base + 4*n4) = *(float4*)&s[4*n4];
        *(float4*)(aprod + base + 4*n4) = *(float4*)&ap[4*n4];
    }
}

__global__ __launch_bounds__(256) void scan_phase2(
    float* __restrict__ send, const float* __restrict__ aprod)
{
    int t = blockIdx.x*256 + threadIdx.x;   // B_*DI_*DS_ = 16384 threads
    float s = 0.f;
    for (int c = 0; c < NC_; c++) {
        size_t idx = (size_t)c*(B_*DI_*DS_) + t;         // coalesced per c
        float tmp = send[idx];
        send[idx] = s;
        s = fmaf(aprod[idx], s, tmp);
    }
}

// Phase 3: re-run chunk with incoming state; y complete per-thread; fuse
// (y + u*D)*silu(z), store bf16 (l,d)-major coalesced.
__global__ __launch_bounds__(128) void scan_phase3(
    const float* __restrict__ dtn, const ushort_t* __restrict__ u_bf,
    const float* __restrict__ bn, const float* __restrict__ cn,
    const float* __restrict__ Alog, const float* __restrict__ Dv,
    const float* __restrict__ sin_, const float* __restrict__ xz,
    ushort_t* __restrict__ ysb)
{
    __shared__ float b_sh[CL_*DS_];
    __shared__ float c_sh[CL_*DS_];
    const int c = blockIdx.x, qy = blockIdx.y, b = blockIdx.z;
    const int tid = threadIdx.x;
    const int d = qy*128 + tid;
    const int l0 = c*CL_;
    for (int f = tid; f < CL_*DS_; f += 128) {
        size_t src = ((size_t)(b*L_) + l0)*DS_ + f;
        b_sh[f] = bn[src];
        c_sh[f] = cn[src];
    }
    float Ac[DS_], s[DS_];
    const float* ar = Alog + (size_t)d*DS_;
    #pragma unroll
    for (int n = 0; n < DS_; n++) Ac[n] = -__expf(ar[n]);
    {
        size_t base = (((size_t)c*B_ + b)*DI_ + d)*DS_;
        #pragma unroll
        for (int n4 = 0; n4 < 4; n4++)
            *(float4*)&s[4*n4] = *(const float4*)(sin_ + base + 4*n4);
    }
    const float Dd = Dv[d];
    __syncthreads();
    const float*    dtp = dtn  + ((size_t)(b*L_ + l0))*DI_ + d;
    const ushort_t* up  = u_bf + ((size_t)(b*L_ + l0))*DI_ + d;
    const float*    zp  = xz   + ((size_t)(b*L_ + l0))*1024 + 512 + d;
    ushort_t*       yo  = ysb  + ((size_t)(b*L_ + l0))*DI_ + d;
    for (int l = 0; l < CL_; l++) {
        float dt = dtp[(size_t)l*DI_];
        float u  = bf2f(up[(size_t)l*DI_]);
        float z  = zp[(size_t)l*1024];
        float dtu = dt*u;
        float bv[DS_], cv[DS_];
        #pragma unroll
        for (int n4 = 0; n4 < 4; n4++) {
            *(float4*)&bv[4*n4] = *(const float4*)&b_sh[l*DS_ + 4*n4];
            *(float4*)&cv[4*n4] = *(const float4*)&c_sh[l*DS_ + 4*n4];
        }
        float y = u*Dd;
        #pragma unroll
        for (int n = 0; n < DS_; n++) {
            float e = __expf(dt*Ac[n]);
            s[n] = fmaf(e, s[n], dtu*bv[n]);
            y = fmaf(s[n], cv[n], y);
        }
        yo[(size_t)l*DI_] = f2bf(y * siluf(z));
    }
}

// ---------------- final LN + head dot ----------------
__global__ __launch_bounds__(256) void final_kernel(
    const float* __restrict__ h, const float* __restrict__ fw,
    const float* __restrict__ fb, const float* __restrict__ hw,
    const float* __restrict__ hb, float* __restrict__ out)
{
    __shared__ float sm[4];
    int row = blockIdx.x, tid = threadIdx.x;
    float v = h[(size_t)row*DM_ + tid];
    float s = v;
    #pragma unroll
    for (int o = 32; o > 0; o >>= 1) s += __shfl_down(s, o);
    if ((tid & 63) == 0) sm[tid >> 6] = s;
    __syncthreads();
    float mu = (sm[0]+sm[1]+sm[2]+sm[3]) * (1.f/DM_);
    __syncthreads();
    float dv = v - mu;
    float q = dv*dv;
    #pragma unroll
    for (int o = 32; o > 0; o >>= 1) q += __shfl_down(q, o);
    if ((tid & 63) == 0) sm[tid >> 6] = q;
    __syncthreads();
    float var = (sm[0]+sm[1]+sm[2]+sm[3]) * (1.f/DM_);
    float nv = dv * rsqrtf(var + 1e-5f) * fw[tid] + fb[tid];
    float p = nv * hw[tid];
    __syncthreads();
    #pragma unroll
    for (int o = 32; o > 0; o >>= 1) p += __shfl_down(p, o);
    if ((tid & 63) == 0) sm[tid >> 6] = p;
    __syncthreads();
    if (tid == 0) out[row] = sm[0]+sm[1]+sm[2]+sm[3] + hb[0];
}

extern "C" void kernel_launch(void* const* d_in, const int* in_sizes, int n_in,
                              void* d_out, int out_size, void* d_ws, size_t ws_size,
                              hipStream_t stream)
{
    const float* x    = (const float*)d_in[0];
    const float* biw  = (const float*)d_in[1];
    const float* bib  = (const float*)d_in[2];
    const float* ge   = (const float*)d_in[3];
    const float* me   = (const float*)d_in[4];
    const float* lnw  = (const float*)d_in[5];
    const float* lnb  = (const float*)d_in[6];
    const float* ipw  = (const float*)d_in[7];
    const float* cw   = (const float*)d_in[8];
    const float* cb   = (const float*)d_in[9];
    const float* xpw  = (const float*)d_in[10];
    const float* dtw  = (const float*)d_in[11];
    const float* dtb  = (const float*)d_in[12];
    const float* alog = (const float*)d_in[13];
    const float* Dv   = (const float*)d_in[14];
    const float* opw  = (const float*)d_in[15];
    const float* fw   = (const float*)d_in[16];
    const float* fb   = (const float*)d_in[17];
    const float* hw   = (const float*)d_in[18];
    const float* hb   = (const float*)d_in[19];
    float* out = (float*)d_out;

    // workspace layout (float units; 16B-aligned); ~57.1 MB
    float* ws  = (float*)d_ws;
    float* h     = ws;                                   // 1,048,576 f
    float* scr   = h + (size_t)BLP_*DM_;                 // 655,360 f (hnb)
    float* xz    = scr + 655360;                         // 4,194,304 f
    float* dtn   = xz + (size_t)BLP_*1024;               // 2,048,000 f (b,l,d)
    float* bn    = dtn + (size_t)B_*L_*DI_;              // 64,000 f (b,l,n)
    float* cn    = bn + (size_t)B_*L_*DS_;               // 64,000 f
    float* send  = cn + (size_t)B_*L_*DS_;               // 1,638,400 f
    float* aprod = send + (size_t)B_*DI_*DS_*NC_;        // 1,638,400 f
    ushort_t* u_bf = (ushort_t*)(aprod + (size_t)B_*DI_*DS_*NC_); // BLP_*DI_ us
    ushort_t* ysbb = u_bf + (size_t)BLP_*DI_;            // BLP_*DI_ us
    ushort_t* ipwb = ysbb + (size_t)BLP_*DI_;            // NL_*1024*DM_ us
    ushort_t* opwb = ipwb + (size_t)NL_*1024*DM_;        // NL_*DM_*DI_ us
    ushort_t* xpwb = opwb + (size_t)NL_*DM_*DI_;         // NL_*48*512 us
    ushort_t* hnb  = (ushort_t*)scr;                     // BLP_*DM_ us

    // convert weights to bf16 (every launch; ~1.7M elements)
    f2bf_kernel<<<(NL_*1024*DM_/4 + 255)/256, 256, 0, stream>>>(ipw, ipwb, NL_*1024*DM_/4);
    f2bf_kernel<<<(NL_*DM_*DI_/4 + 255)/256, 256, 0, stream>>>(opw, opwb, NL_*DM_*DI_/4);
    f2bf_kernel<<<(NL_*48*512/4 + 255)/256, 256, 0, stream>>>(xpw, xpwb, NL_*48*512/4);

    embed_kernel<<<BL_, 256, 0, stream>>>(x, biw, bib, ge, me, h);
    for (int i = 0; i < NL_; i++) {
        ln_kernel<<<BL_, 256, 0, stream>>>(h, lnw + i*DM_, lnb + i*DM_, hnb);
        gemm_mfma<false><<<dim3(BLP_/128, 1024/128), 256, 0, stream>>>(
            hnb, ipwb + (size_t)i*1024*DM_, xz, 1024, DM_);
        conv_silu_kernel<<<dim3(32, 8, B_), 256, 0, stream>>>(
            xz, cw + i*DI_*4, cb + i*DI_, u_bf);
        xproj_dt_kernel<<<dim3(125, B_), 256, 0, stream>>>(
            u_bf, xpwb + (size_t)i*48*512, dtw + (size_t)i*DI_*16, dtb + i*DI_,
            bn, cn, dtn);
        scan_phase1<<<dim3(NC_, DI_/128, B_), 128, 0, stream>>>(
            dtn, u_bf, bn, alog + (size_t)i*DI_*DS_, send, aprod);
        scan_phase2<<<B_*DI_*DS_/256, 256, 0, stream>>>(send, aprod);
        scan_phase3<<<dim3(NC_, DI_/128, B_), 128, 0, stream>>>(
            dtn, u_bf, bn, cn, alog + (size_t)i*DI_*DS_, Dv + i*DI_,
            send, xz, ysbb);
        gemm_mfma<true><<<dim3(BLP_/128, DM_/128), 256, 0, stream>>>(
            ysbb, opwb + (size_t)i*DM_*DI_, h, DM_, DI_);
    }
    final_kernel<<<BL_, 256, 0, stream>>>(h, fw, fb, hw, hb, out);
}

// Round 9
// 528.246 us; speedup vs baseline: 4.6017x; 1.0045x over previous
//
#include <hip/hip_runtime.h>
#include <math.h>

#define B_  2
#define L_  2000
#define DM_ 256
#define DI_ 512
#define DS_ 16
#define NL_ 4
#define BL_ (B_*L_)     // 4000
#define BLP_ 4096       // rows padded to multiple of 64
#define NC_ 100         // scan chunks
#define CL_ 20          // chunk length (L_ = NC_*CL_)

typedef unsigned short ushort_t;
typedef __attribute__((ext_vector_type(8))) short bf16x8;
typedef __attribute__((ext_vector_type(4))) float f32x4;

__device__ __forceinline__ float siluf(float x) {
    return x / (1.f + __expf(-x));
}

__device__ __forceinline__ ushort_t f2bf(float x) {
    unsigned int u = __float_as_uint(x);
    unsigned int r = (u + 0x7FFFu + ((u >> 16) & 1u)) >> 16;
    return (ushort_t)r;
}

__device__ __forceinline__ float bf2f(ushort_t v) {
    return __uint_as_float(((unsigned int)v) << 16);
}

// ---------------- fp32 -> bf16 conversion (4 el/thread) ----------------
__global__ __launch_bounds__(256) void f2bf_kernel(
    const float* __restrict__ src, ushort_t* __restrict__ dst, int n4)
{
    int i = (blockIdx.x*256 + threadIdx.x);
    if (i < n4) {
        float4 v = *(const float4*)(src + 4*i);
        ushort_t o[4] = {f2bf(v.x), f2bf(v.y), f2bf(v.z), f2bf(v.w)};
        *(ushort2*)(dst + 4*i)     = *(ushort2*)&o[0];
        *(ushort2*)(dst + 4*i + 2) = *(ushort2*)&o[2];
    }
}

// ---------------- embed: h = x*biw + bib + gene_emb + mod_emb ----------------
__global__ __launch_bounds__(256) void embed_kernel(
    const float* __restrict__ x, const float* __restrict__ biw,
    const float* __restrict__ bib, const float* __restrict__ ge,
    const float* __restrict__ me, float* __restrict__ h)
{
    int bl = blockIdx.x, d = threadIdx.x;
    int l = bl % L_;
    h[(size_t)bl*DM_ + d] = x[bl]*biw[d] + bib[d] + ge[(size_t)l*DM_ + d] + me[d];
}

// ---------------- layernorm over D_MODEL=256 -> bf16 output ----------------
__global__ __launch_bounds__(256) void ln_kernel(
    const float* __restrict__ h, const float* __restrict__ w,
    const float* __restrict__ b, ushort_t* __restrict__ out)
{
    __shared__ float sm[4];
    int row = blockIdx.x, tid = threadIdx.x;
    float v = h[(size_t)row*DM_ + tid];
    float s = v;
    #pragma unroll
    for (int o = 32; o > 0; o >>= 1) s += __shfl_down(s, o);
    if ((tid & 63) == 0) sm[tid >> 6] = s;
    __syncthreads();
    float mu = (sm[0]+sm[1]+sm[2]+sm[3]) * (1.f/DM_);
    __syncthreads();
    float d = v - mu;
    float q = d*d;
    #pragma unroll
    for (int o = 32; o > 0; o >>= 1) q += __shfl_down(q, o);
    if ((tid & 63) == 0) sm[tid >> 6] = q;
    __syncthreads();
    float var = (sm[0]+sm[1]+sm[2]+sm[3]) * (1.f/DM_);
    out[(size_t)row*DM_ + tid] = f2bf(d * rsqrtf(var + 1e-5f) * w[tid] + b[tid]);
}

// ---------------- bf16 MFMA GEMM: C[m,n] (+)= sum_k A[m,k]*W[n,k] ----------------
template<bool ACCUM>
__global__ __launch_bounds__(256) void gemm_mfma(
    const ushort_t* __restrict__ A, const ushort_t* __restrict__ W,
    float* __restrict__ C, int ldc, int K)
{
    __shared__ ushort_t a_s[128*64];
    __shared__ ushort_t b_s[128*64];
    const int r0 = blockIdx.x*128, c0 = blockIdx.y*128;
    const int tid = threadIdx.x;
    const int lane = tid & 63, w = tid >> 6;
    const int wm = (w & 1)*64, wn = (w >> 1)*64;
    const int qd = lane >> 4, l16 = lane & 15;
    f32x4 acc[4][4] = {};
    for (int kc = 0; kc < K; kc += 64) {
        #pragma unroll
        for (int q = 0; q < 4; q++) {
            int ch = tid + 256*q;              // 0..1023
            int row = ch >> 3, col8 = (ch & 7)*8;
            *(bf16x8*)&a_s[row*64 + col8] =
                *(const bf16x8*)(A + (size_t)(r0 + row)*K + kc + col8);
            *(bf16x8*)&b_s[row*64 + col8] =
                *(const bf16x8*)(W + (size_t)(c0 + row)*K + kc + col8);
        }
        __syncthreads();
        #pragma unroll
        for (int ks = 0; ks < 2; ks++) {
            bf16x8 af[4], bf[4];
            #pragma unroll
            for (int i = 0; i < 4; i++)
                af[i] = *(const bf16x8*)&a_s[(wm + i*16 + l16)*64 + ks*32 + qd*8];
            #pragma unroll
            for (int j = 0; j < 4; j++)
                bf[j] = *(const bf16x8*)&b_s[(wn + j*16 + l16)*64 + ks*32 + qd*8];
            #pragma unroll
            for (int i = 0; i < 4; i++) {
                #pragma unroll
                for (int j = 0; j < 4; j++)
                    acc[i][j] = __builtin_amdgcn_mfma_f32_16x16x32_bf16(
                        af[i], bf[j], acc[i][j], 0, 0, 0);
            }
        }
        __syncthreads();
    }
    // C/D layout: col = lane&15, row = (lane>>4)*4 + reg
    #pragma unroll
    for (int i = 0; i < 4; i++) {
        #pragma unroll
        for (int j = 0; j < 4; j++) {
            #pragma unroll
            for (int r = 0; r < 4; r++) {
                int row = r0 + wm + i*16 + qd*4 + r;
                int col = c0 + wn + j*16 + l16;
                size_t idx = (size_t)row*ldc + col;
                if constexpr (ACCUM) C[idx] += acc[i][j][r];
                else                 C[idx]  = acc[i][j][r];
            }
        }
    }
}

// ---------------- conv(4) + silu, tiled; writes u_bf (b,l,c) bf16 ----------------
__global__ __launch_bounds__(256) void conv_silu_kernel(
    const float* __restrict__ xz, const float* __restrict__ cw,
    const float* __restrict__ cb, ushort_t* __restrict__ u_bf)
{
    __shared__ float xs[67][68];
    __shared__ ushort_t us[64][72];
    const int l0 = blockIdx.x * 64, c0 = blockIdx.y * 64, b = blockIdx.z;
    const int tid = threadIdx.x;
    // stage xz tile rows l0-3 .. l0+63
    for (int f = tid; f < 67*16; f += 256) {
        int row = f >> 4, c4 = (f & 15) * 4;
        int l = l0 - 3 + row;
        float4 v = {0.f, 0.f, 0.f, 0.f};
        if (l >= 0 && l < L_)
            v = *(const float4*)(xz + (size_t)(b*L_ + l)*1024 + c0 + c4);
        *(float4*)&xs[row][c4] = v;
    }
    __syncthreads();
    // conv: thread -> fixed c, 16 consecutive l
    const int c_loc = tid & 63, lq = tid >> 6;
    const int c = c0 + c_loc;
    float4 wv = *(const float4*)(cw + c*4);
    float bias = cb[c];
    float x0 = xs[lq*16 + 0][c_loc];
    float x1 = xs[lq*16 + 1][c_loc];
    float x2 = xs[lq*16 + 2][c_loc];
    #pragma unroll
    for (int j = 0; j < 16; j++) {
        float x3 = xs[lq*16 + 3 + j][c_loc];
        float v = fmaf(x0, wv.x, fmaf(x1, wv.y, fmaf(x2, wv.z, fmaf(x3, wv.w, bias))));
        us[lq*16 + j][c_loc] = f2bf(siluf(v));
        x0 = x1; x1 = x2; x2 = x3;
    }
    __syncthreads();
    // u_bf rows (l,c) via LDS transpose, 16B stores
    for (int f = tid; f < 64*8; f += 256) {
        int row = f >> 3, g8 = (f & 7)*8;
        if (l0 + row < L_)
            *(uint4*)(u_bf + (size_t)(b*L_ + l0 + row)*512 + c0 + g8) =
                *(const uint4*)&us[row][g8];
    }
}

// ---------------- x_proj via MFMA (fragments direct from global) + fused dt_proj ----
// grid(125, B_), block 256 = 4 waves splitting K (128 each). No A/W LDS
// staging: A-frag = 16B of the row (each row's 4 quads cover one 64B line,
// read once); B-frag = 16B of W (48KB, L2-resident, 250x reuse). LDS = 13 KB.
__global__ __launch_bounds__(256) void xproj_dt_kernel(
    const ushort_t* __restrict__ U, const ushort_t* __restrict__ XWb,
    const float* __restrict__ DTW, const float* __restrict__ DTB,
    float* __restrict__ bn, float* __restrict__ cn, float* __restrict__ dtn)
{
    __shared__ float ps[4*16*48];
    __shared__ float dtr_s[16][16];
    const int l0 = blockIdx.x * 16, b = blockIdx.y;
    const int tid = threadIdx.x;
    const int lane = tid & 63, w = tid >> 6;
    const int qd = lane >> 4, l16 = lane & 15;
    // MFMA: wave w covers K in [128w, 128w+128); fragments straight from global
    const ushort_t* arow = U + ((size_t)(b*L_) + l0 + l16)*512;
    f32x4 acc[3] = {};
    #pragma unroll
    for (int step = 0; step < 4; step++) {
        int k = w*128 + step*32 + qd*8;
        bf16x8 af = *(const bf16x8*)(arow + k);
        #pragma unroll
        for (int j = 0; j < 3; j++) {
            bf16x8 bf = *(const bf16x8*)(XWb + (size_t)(j*16 + l16)*512 + k);
            acc[j] = __builtin_amdgcn_mfma_f32_16x16x32_bf16(af, bf, acc[j], 0, 0, 0);
        }
    }
    // partials -> LDS
    #pragma unroll
    for (int j = 0; j < 3; j++) {
        #pragma unroll
        for (int r = 0; r < 4; r++)
            ps[(w*16 + qd*4 + r)*48 + j*16 + l16] = acc[j][r];
    }
    __syncthreads();
    // reduce 4 partials into ps[0..767]
    #pragma unroll
    for (int e = tid; e < 768; e += 256)
        ps[e] = ps[e] + ps[768 + e] + ps[1536 + e] + ps[2304 + e];
    __syncthreads();
    // scatter: thread = (row = tid>>4, n = tid&15); contiguous 1KB stores
    {
        int row = tid >> 4, n = tid & 15;
        dtr_s[row][n] = ps[row*48 + n];
        size_t base = ((size_t)(b*L_) + l0 + row)*DS_ + n;
        bn[base] = ps[row*48 + 16 + n];
        cn[base] = ps[row*48 + 32 + n];
    }
    __syncthreads();
    // dt_proj: thread -> d = tid, tid+256; 16 rows each; softplus; (l,d) stores
    #pragma unroll
    for (int q = 0; q < 2; q++) {
        int d = tid + q*256;
        float wreg[16];
        const float4* wp = (const float4*)(DTW + (size_t)d*16);
        #pragma unroll
        for (int k4 = 0; k4 < 4; k4++) {
            float4 v = wp[k4];
            wreg[4*k4+0] = v.x; wreg[4*k4+1] = v.y;
            wreg[4*k4+2] = v.z; wreg[4*k4+3] = v.w;
        }
        float bias = DTB[d];
        #pragma unroll
        for (int r = 0; r < 16; r++) {
            float a = bias;
            #pragma unroll
            for (int k = 0; k < 16; k++) a = fmaf(dtr_s[r][k], wreg[k], a);
            float dt = a > 20.f ? a : log1pf(__expf(a));
            dtn[((size_t)(b*L_) + l0 + r)*DI_ + d] = dt;
        }
    }
}

// ---------------- chunked selective scan, thread-per-d (no cross-lane) ----------
__global__ __launch_bounds__(128) void scan_phase1(
    const float* __restrict__ dtn, const ushort_t* __restrict__ u_bf,
    const float* __restrict__ bn, const float* __restrict__ Alog,
    float* __restrict__ send, float* __restrict__ aprod)
{
    __shared__ float b_sh[CL_*DS_];
    const int c = blockIdx.x, qy = blockIdx.y, b = blockIdx.z;
    const int tid = threadIdx.x;
    const int d = qy*128 + tid;
    const int l0 = c*CL_;
    for (int f = tid; f < CL_*DS_; f += 128)
        b_sh[f] = bn[((size_t)(b*L_) + l0)*DS_ + f];
    float Ac[DS_], s[DS_], ap[DS_];
    const float* ar = Alog + (size_t)d*DS_;
    #pragma unroll
    for (int n = 0; n < DS_; n++) { Ac[n] = -__expf(ar[n]); s[n] = 0.f; ap[n] = 1.f; }
    __syncthreads();
    const float*    dtp = dtn  + ((size_t)(b*L_ + l0))*DI_ + d;
    const ushort_t* up  = u_bf + ((size_t)(b*L_ + l0))*DI_ + d;
    for (int l = 0; l < CL_; l++) {
        float dt = dtp[(size_t)l*DI_];
        float u  = bf2f(up[(size_t)l*DI_]);
        float dtu = dt*u;
        float bv[DS_];
        #pragma unroll
        for (int n4 = 0; n4 < 4; n4++)
            *(float4*)&bv[4*n4] = *(const float4*)&b_sh[l*DS_ + 4*n4];
        #pragma unroll
        for (int n = 0; n < DS_; n++) {
            float e = __expf(dt*Ac[n]);
            s[n] = fmaf(e, s[n], dtu*bv[n]);
            ap[n] *= e;
        }
    }
    size_t base = (((size_t)c*B_ + b)*DI_ + d)*DS_;
    #pragma unroll
    for (int n4 = 0; n4 < 4; n4++) {
        *(float4*)(send  + base + 4*n4) = *(float4*)&s[4*n4];
        *(float4*)(aprod + base + 4*n4) = *(float4*)&ap[4*n4];
    }
}

__global__ __launch_bounds__(256) void scan_phase2(
    float* __restrict__ send, const float* __restrict__ aprod)
{
    int t = blockIdx.x*256 + threadIdx.x;   // B_*DI_*DS_ = 16384 threads
    float s = 0.f;
    for (int c = 0; c < NC_; c++) {
        size_t idx = (size_t)c*(B_*DI_*DS_) + t;         // coalesced per c
        float tmp = send[idx];
        send[idx] = s;
        s = fmaf(aprod[idx], s, tmp);
    }
}

// Phase 3: re-run chunk with incoming state; y complete per-thread; fuse
// (y + u*D)*silu(z), store bf16 (l,d)-major coalesced.
__global__ __launch_bounds__(128) void scan_phase3(
    const float* __restrict__ dtn, const ushort_t* __restrict__ u_bf,
    const float* __restrict__ bn, const float* __restrict__ cn,
    const float* __restrict__ Alog, const float* __restrict__ Dv,
    const float* __restrict__ sin_, const float* __restrict__ xz,
    ushort_t* __restrict__ ysb)
{
    __shared__ float b_sh[CL_*DS_];
    __shared__ float c_sh[CL_*DS_];
    const int c = blockIdx.x, qy = blockIdx.y, b = blockIdx.z;
    const int tid = threadIdx.x;
    const int d = qy*128 + tid;
    const int l0 = c*CL_;
    for (int f = tid; f < CL_*DS_; f += 128) {
        size_t src = ((size_t)(b*L_) + l0)*DS_ + f;
        b_sh[f] = bn[src];
        c_sh[f] = cn[src];
    }
    float Ac[DS_], s[DS_];
    const float* ar = Alog + (size_t)d*DS_;
    #pragma unroll
    for (int n = 0; n < DS_; n++) Ac[n] = -__expf(ar[n]);
    {
        size_t base = (((size_t)c*B_ + b)*DI_ + d)*DS_;
        #pragma unroll
        for (int n4 = 0; n4 < 4; n4++)
            *(float4*)&s[4*n4] = *(const float4*)(sin_ + base + 4*n4);
    }
    const float Dd = Dv[d];
    __syncthreads();
    const float*    dtp = dtn  + ((size_t)(b*L_ + l0))*DI_ + d;
    const ushort_t* up  = u_bf + ((size_t)(b*L_ + l0))*DI_ + d;
    const float*    zp  = xz   + ((size_t)(b*L_ + l0))*1024 + 512 + d;
    ushort_t*       yo  = ysb  + ((size_t)(b*L_ + l0))*DI_ + d;
    for (int l = 0; l < CL_; l++) {
        float dt = dtp[(size_t)l*DI_];
        float u  = bf2f(up[(size_t)l*DI_]);
        float z  = zp[(size_t)l*1024];
        float dtu = dt*u;
        float bv[DS_], cv[DS_];
        #pragma unroll
        for (int n4 = 0; n4 < 4; n4++) {
            *(float4*)&bv[4*n4] = *(const float4*)&b_sh[l*DS_ + 4*n4];
            *(float4*)&cv[4*n4] = *(const float4*)&c_sh[l*DS_ + 4*n4];
        }
        float y = u*Dd;
        #pragma unroll
        for (int n = 0; n < DS_; n++) {
            float e = __expf(dt*Ac[n]);
            s[n] = fmaf(e, s[n], dtu*bv[n]);
            y = fmaf(s[n], cv[n], y);
        }
        yo[(size_t)l*DI_] = f2bf(y * siluf(z));
    }
}

// ---------------- final LN + head dot ----------------
__global__ __launch_bounds__(256) void final_kernel(
    const float* __restrict__ h, const float* __restrict__ fw,
    const float* __restrict__ fb, const float* __restrict__ hw,
    const float* __restrict__ hb, float* __restrict__ out)
{
    __shared__ float sm[4];
    int row = blockIdx.x, tid = threadIdx.x;
    float v = h[(size_t)row*DM_ + tid];
    float s = v;
    #pragma unroll
    for (int o = 32; o > 0; o >>= 1) s += __shfl_down(s, o);
    if ((tid & 63) == 0) sm[tid >> 6] = s;
    __syncthreads();
    float mu = (sm[0]+sm[1]+sm[2]+sm[3]) * (1.f/DM_);
    __syncthreads();
    float dv = v - mu;
    float q = dv*dv;
    #pragma unroll
    for (int o = 32; o > 0; o >>= 1) q += __shfl_down(q, o);
    if ((tid & 63) == 0) sm[tid >> 6] = q;
    __syncthreads();
    float var = (sm[0]+sm[1]+sm[2]+sm[3]) * (1.f/DM_);
    float nv = dv * rsqrtf(var + 1e-5f) * fw[tid] + fb[tid];
    float p = nv * hw[tid];
    __syncthreads();
    #pragma unroll
    for (int o = 32; o > 0; o >>= 1) p += __shfl_down(p, o);
    if ((tid & 63) == 0) sm[tid >> 6] = p;
    __syncthreads();
    if (tid == 0) out[row] = sm[0]+sm[1]+sm[2]+sm[3] + hb[0];
}

extern "C" void kernel_launch(void* const* d_in, const int* in_sizes, int n_in,
                              void* d_out, int out_size, void* d_ws, size_t ws_size,
                              hipStream_t stream)
{
    const float* x    = (const float*)d_in[0];
    const float* biw  = (const float*)d_in[1];
    const float* bib  = (const float*)d_in[2];
    const float* ge   = (const float*)d_in[3];
    const float* me   = (const float*)d_in[4];
    const float* lnw  = (const float*)d_in[5];
    const float* lnb  = (const float*)d_in[6];
    const float* ipw  = (const float*)d_in[7];
    const float* cw   = (const float*)d_in[8];
    const float* cb   = (const float*)d_in[9];
    const float* xpw  = (const float*)d_in[10];
    const float* dtw  = (const float*)d_in[11];
    const float* dtb  = (const float*)d_in[12];
    const float* alog = (const float*)d_in[13];
    const float* Dv   = (const float*)d_in[14];
    const float* opw  = (const float*)d_in[15];
    const float* fw   = (const float*)d_in[16];
    const float* fb   = (const float*)d_in[17];
    const float* hw   = (const float*)d_in[18];
    const float* hb   = (const float*)d_in[19];
    float* out = (float*)d_out;

    // workspace layout (float units; 16B-aligned); ~57.1 MB
    float* ws  = (float*)d_ws;
    float* h     = ws;                                   // 1,048,576 f
    float* scr   = h + (size_t)BLP_*DM_;                 // 655,360 f (hnb)
    float* xz    = scr + 655360;                         // 4,194,304 f
    float* dtn   = xz + (size_t)BLP_*1024;               // 2,048,000 f (b,l,d)
    float* bn    = dtn + (size_t)B_*L_*DI_;              // 64,000 f (b,l,n)
    float* cn    = bn + (size_t)B_*L_*DS_;               // 64,000 f
    float* send  = cn + (size_t)B_*L_*DS_;               // 1,638,400 f
    float* aprod = send + (size_t)B_*DI_*DS_*NC_;        // 1,638,400 f
    ushort_t* u_bf = (ushort_t*)(aprod + (size_t)B_*DI_*DS_*NC_); // BLP_*DI_ us
    ushort_t* ysbb = u_bf + (size_t)BLP_*DI_;            // BLP_*DI_ us
    ushort_t* ipwb = ysbb + (size_t)BLP_*DI_;            // NL_*1024*DM_ us
    ushort_t* opwb = ipwb + (size_t)NL_*1024*DM_;        // NL_*DM_*DI_ us
    ushort_t* xpwb = opwb + (size_t)NL_*DM_*DI_;         // NL_*48*512 us
    ushort_t* hnb  = (ushort_t*)scr;                     // BLP_*DM_ us

    // convert weights to bf16 (every launch; ~1.7M elements)
    f2bf_kernel<<<(NL_*1024*DM_/4 + 255)/256, 256, 0, stream>>>(ipw, ipwb, NL_*1024*DM_/4);
    f2bf_kernel<<<(NL_*DM_*DI_/4 + 255)/256, 256, 0, stream>>>(opw, opwb, NL_*DM_*DI_/4);
    f2bf_kernel<<<(NL_*48*512/4 + 255)/256, 256, 0, stream>>>(xpw, xpwb, NL_*48*512/4);

    embed_kernel<<<BL_, 256, 0, stream>>>(x, biw, bib, ge, me, h);
    for (int i = 0; i < NL_; i++) {
        ln_kernel<<<BL_, 256, 0, stream>>>(h, lnw + i*DM_, lnb + i*DM_, hnb);
        gemm_mfma<false><<<dim3(BLP_/128, 1024/128), 256, 0, stream>>>(
            hnb, ipwb + (size_t)i*1024*DM_, xz, 1024, DM_);
        conv_silu_kernel<<<dim3(32, 8, B_), 256, 0, stream>>>(
            xz, cw + i*DI_*4, cb + i*DI_, u_bf);
        xproj_dt_kernel<<<dim3(125, B_), 256, 0, stream>>>(
            u_bf, xpwb + (size_t)i*48*512, dtw + (size_t)i*DI_*16, dtb + i*DI_,
            bn, cn, dtn);
        scan_phase1<<<dim3(NC_, DI_/128, B_), 128, 0, stream>>>(
            dtn, u_bf, bn, alog + (size_t)i*DI_*DS_, send, aprod);
        scan_phase2<<<B_*DI_*DS_/256, 256, 0, stream>>>(send, aprod);
        scan_phase3<<<dim3(NC_, DI_/128, B_), 128, 0, stream>>>(
            dtn, u_bf, bn, cn, alog + (size_t)i*DI_*DS_, Dv + i*DI_,
            send, xz, ysbb);
        gemm_mfma<true><<<dim3(BLP_/128, DM_/128), 256, 0, stream>>>(
            ysbb, opwb + (size_t)i*DM_*DI_, h, DM_, DI_);
    }
    final_kernel<<<BL_, 256, 0, stream>>>(h, fw, fb, hw, hb, out);
}